// Round 2
// baseline (1501.266 us; speedup 1.0000x reference)
//
#include <hip/hip_runtime.h>
#include <hip/hip_bf16.h>

// Problem constants (FoundationalTimeSeriesModel)
#define B_   16
#define L_   512
#define M_   32
#define P_   64
#define D_   128
#define NH_  8
#define DH_  16
#define NL_  2
#define E_   16
#define EH_  512
#define O_   128

// TCN chunking
#define CH    128   // valid outputs per chunk
#define HALO  60    // total receptive field of the 4-level TCN
#define WW    192   // working width (CH+HALO=188, padded to 192)
#define PADF  16    // front pad (max lookback 2*8=16)

// ---------------------------------------------------------------------------
// Kernel 1: per-(sequence,chunk) TCN encoder + layernorm + masked mean-pool
// ---------------------------------------------------------------------------
__device__ __forceinline__ void stage_w(float* WT, const float* __restrict__ wsrc) {
  // global layout [o][c][k] (o*192 + c*3 + k) -> LDS layout [c][o*3+k]
  for (int idx = threadIdx.x; idx < 64 * 192; idx += 256) {
    int c = idx / 192;
    int j = idx - c * 192;     // j = o*3+k
    int o = j / 3;
    int k = j - o * 3;
    WT[idx] = wsrc[o * 192 + c * 3 + k];
  }
}

template <int DIL, bool RES>
__device__ __forceinline__ void conv_one(const float* __restrict__ IN, float* __restrict__ OUT,
                                         const float* __restrict__ WT, const float* __restrict__ bias,
                                         bool zh) {
  const int og = threadIdx.x >> 5;   // 0..7  -> 8 output channels each
  const int lg = threadIdx.x & 31;   // 0..31 -> 6 positions each
  const int l0 = lg * 6;
  const int o0 = og * 8;
  float acc[8][6];
#pragma unroll
  for (int i = 0; i < 8; ++i) {
    float bv = bias[o0 + i];
#pragma unroll
    for (int j = 0; j < 6; ++j) acc[i][j] = bv;
  }
  for (int c = 0; c < 64; ++c) {
    float xv[6 + 2 * DIL];
    const float* ar = IN + PADF + c * WW + l0 - 2 * DIL;
#pragma unroll
    for (int j = 0; j < 3 + DIL; ++j) {
      float2 t2 = *(const float2*)(ar + 2 * j);
      xv[2 * j] = t2.x; xv[2 * j + 1] = t2.y;
    }
    const float* wr = WT + c * WW + o0 * 3;
    float wv[24];
#pragma unroll
    for (int q = 0; q < 6; ++q) {
      float4 t4 = *(const float4*)(wr + 4 * q);
      wv[4 * q] = t4.x; wv[4 * q + 1] = t4.y; wv[4 * q + 2] = t4.z; wv[4 * q + 3] = t4.w;
    }
#pragma unroll
    for (int i = 0; i < 8; ++i) {
#pragma unroll
      for (int j = 0; j < 6; ++j) {
        acc[i][j] = fmaf(wv[i * 3 + 0], xv[j], acc[i][j]);
        acc[i][j] = fmaf(wv[i * 3 + 1], xv[j + DIL], acc[i][j]);
        acc[i][j] = fmaf(wv[i * 3 + 2], xv[j + 2 * DIL], acc[i][j]);
      }
    }
  }
#pragma unroll
  for (int i = 0; i < 8; ++i) {
#pragma unroll
    for (int j = 0; j < 6; ++j) {
      float v = fmaxf(acc[i][j], 0.0f);
      int off = PADF + (o0 + i) * WW + l0 + j;
      if (RES) v = fmaxf(v + OUT[off], 0.0f);
      // chunk 0: positions w<HALO correspond to l<0; reference zero-pads each
      // conv, so force them to 0 (race-free: each thread owns its outputs).
      if (zh && (l0 + j) < HALO) v = 0.0f;
      OUT[off] = v;
    }
  }
}

template <int DILV>
__device__ __forceinline__ void tcn_level(float* A, float* Bf, float* WT,
                                          const float* w1, const float* b1,
                                          const float* w2, const float* b2, bool zh) {
  stage_w(WT, w1);
  __syncthreads();
  conv_one<DILV, false>(A, Bf, WT, b1, zh);
  __syncthreads();
  stage_w(WT, w2);
  __syncthreads();
  conv_one<DILV, true>(Bf, A, WT, b2, zh);
  __syncthreads();
}

__global__ __launch_bounds__(256) void tcn_kernel(
    const float* __restrict__ x, const float* __restrict__ mask,
    const float* __restrict__ pw, const float* __restrict__ pb,
    const float* __restrict__ w1, const float* __restrict__ b1,
    const float* __restrict__ w2, const float* __restrict__ b2,
    const float* __restrict__ lng, const float* __restrict__ lnb,
    float* __restrict__ psum) {
  extern __shared__ float sm[];
  float* A  = sm;                    // PADF + 64*WW = 12304 floats
  float* Bf = A + PADF + 64 * WW;    // 12304
  float* WT = Bf + PADF + 64 * WW;   // 64*192 = 12288  (total 147584 B)

  const int bx = blockIdx.x;
  const int seq = bx >> 2;
  const int chunk = bx & 3;
  const int b = seq >> 5;
  const int m = seq & 31;
  if (mask[b * M_ + m] == 0.0f) return;   // masked sensor: output provably unused
  const int tid = threadIdx.x;
  const bool zh = (chunk == 0);

  if (tid < PADF) { A[tid] = 0.0f; Bf[tid] = 0.0f; }
  const int lbase = chunk * CH - HALO;
  for (int idx = tid; idx < 64 * WW; idx += 256) {
    int c = idx / WW;
    int w = idx - c * WW;
    int l = lbase + w;
    float v = 0.0f;
    if (l >= 0 && l < L_ && w < CH + HALO) {
      float xv = x[(b * L_ + l) * M_ + m];
      float dv = expf(-0.14391157f * (float)(c & ~1));  // ln(1e4)/64
      float ang = (float)l * dv;
      float pe = (c & 1) ? cosf(ang) : sinf(ang);
      v = fmaf(xv, pw[c], pb[c]) + pe;
    }
    A[PADF + idx] = v;
  }
  __syncthreads();

  tcn_level<1>(A, Bf, WT, w1 + 0 * 12288, b1 + 0 * 64, w2 + 0 * 12288, b2 + 0 * 64, zh);
  tcn_level<2>(A, Bf, WT, w1 + 1 * 12288, b1 + 1 * 64, w2 + 1 * 12288, b2 + 1 * 64, zh);
  tcn_level<4>(A, Bf, WT, w1 + 2 * 12288, b1 + 2 * 64, w2 + 2 * 12288, b2 + 2 * 64, zh);
  tcn_level<8>(A, Bf, WT, w1 + 3 * 12288, b1 + 3 * 64, w2 + 3 * 12288, b2 + 3 * 64, zh);

  // LayerNorm over channels at each valid position, then partial mean-pool over L
  float* mst = WT;  // reuse: [0..127]=mean, [128..255]=rstd
  if (tid < CH) {
    int w = HALO + tid;
    float s = 0.f, ss = 0.f;
    for (int c = 0; c < 64; ++c) {
      float v = A[PADF + c * WW + w];
      s += v; ss += v * v;
    }
    float mu = s * 0.015625f;
    float var = fmaxf(ss * 0.015625f - mu * mu, 0.0f);
    mst[tid] = mu;
    mst[CH + tid] = rsqrtf(var + 1e-5f);
  }
  __syncthreads();
  {
    int p = tid & 63, q = tid >> 6;
    float accp = 0.f;
    int w0 = HALO + q * 32;
    for (int w = w0; w < w0 + 32; ++w)
      accp += (A[PADF + p * WW + w] - mst[w - HALO]) * mst[CH + w - HALO];
    atomicAdd(&psum[seq * 64 + p], lng[p] * accp + 32.0f * lnb[p]);
  }
}

// ---------------------------------------------------------------------------
// Kernel 2: per-batch transformer (2 layers) + ctx / g computation
// ---------------------------------------------------------------------------
template <int KD, int NJ, int MODE>  // MODE 0: store, 1: +=, 2: relu-store
__device__ __forceinline__ void gemm_lds(const float* __restrict__ In, int ldin,
                                         const float* __restrict__ W, const float* __restrict__ bias,
                                         float* __restrict__ Out, int ldout) {
  constexpr int NG = 32 * NJ / 4;
  for (int g = threadIdx.x; g < NG; g += 256) {
    int mm = g / (NJ / 4);
    int j0 = (g - mm * (NJ / 4)) * 4;
    float a0 = bias[j0], a1 = bias[j0 + 1], a2 = bias[j0 + 2], a3 = bias[j0 + 3];
    const float* ip = In + mm * ldin;
#pragma unroll 4
    for (int p = 0; p < KD; ++p) {
      float s = ip[p];
      float4 w4 = *(const float4*)(W + p * NJ + j0);
      a0 = fmaf(s, w4.x, a0); a1 = fmaf(s, w4.y, a1);
      a2 = fmaf(s, w4.z, a2); a3 = fmaf(s, w4.w, a3);
    }
    float* op = Out + mm * ldout + j0;
    if (MODE == 0)      { op[0] = a0; op[1] = a1; op[2] = a2; op[3] = a3; }
    else if (MODE == 1) { op[0] += a0; op[1] += a1; op[2] += a2; op[3] += a3; }
    else                { op[0] = fmaxf(a0, 0.f); op[1] = fmaxf(a1, 0.f);
                          op[2] = fmaxf(a2, 0.f); op[3] = fmaxf(a3, 0.f); }
  }
}

__device__ __forceinline__ void ln_rows(const float* __restrict__ In, float* __restrict__ Out,
                                        const float* __restrict__ g, const float* __restrict__ b,
                                        float* mst) {
  if (threadIdx.x < 32) {
    const float* ip = In + threadIdx.x * 132;
    float s = 0, ss = 0;
    for (int j = 0; j < 128; ++j) { float v = ip[j]; s += v; ss += v * v; }
    float mu = s * 0.0078125f;
    float var = fmaxf(ss * 0.0078125f - mu * mu, 0.f);
    mst[threadIdx.x] = mu;
    mst[32 + threadIdx.x] = rsqrtf(var + 1e-5f);
  }
  __syncthreads();
  for (int idx = threadIdx.x; idx < 4096; idx += 256) {
    int mm = idx >> 7, j = idx & 127;
    Out[mm * 132 + j] = (In[mm * 132 + j] - mst[mm]) * mst[32 + mm] * g[j] + b[j];
  }
  __syncthreads();
}

__global__ __launch_bounds__(256) void xf_kernel(
    const float* __restrict__ psum, const float* __restrict__ mask,
    const float* __restrict__ ppw, const float* __restrict__ ppb, const float* __restrict__ pos,
    const float* __restrict__ wq, const float* __restrict__ bq,
    const float* __restrict__ wk, const float* __restrict__ bk,
    const float* __restrict__ wv, const float* __restrict__ bv,
    const float* __restrict__ wo, const float* __restrict__ bo,
    const float* __restrict__ l1g, const float* __restrict__ l1b,
    const float* __restrict__ l2g, const float* __restrict__ l2b,
    const float* __restrict__ f1w, const float* __restrict__ f1b,
    const float* __restrict__ f2w, const float* __restrict__ f2b,
    const float* __restrict__ og_, const float* __restrict__ ob_,
    float* __restrict__ pooledws, float* __restrict__ ctxws, float* __restrict__ gws) {
  extern __shared__ float sm[];
  float* T   = sm;            // 32*132
  float* Y   = T + 4224;
  float* Q   = Y + 4224;
  float* Kb  = Q + 4224;
  float* V   = Kb + 4224;
  float* FF  = V + 4224;      // 32*260 (also reused as 32x33 score buffer)
  float* Pl  = FF + 8320;     // 32*68
  float* mst = Pl + 2176;     // 64
  float* mkv = mst + 64;      // 32     total = 31712 floats = 126848 B
  const int b = blockIdx.x;
  const int tid = threadIdx.x;

  if (tid < 32) mkv[tid] = mask[b * 32 + tid];
  for (int idx = tid; idx < 2048; idx += 256) {
    int mm = idx >> 6, p = idx & 63;
    float v = mask[b * 32 + mm] * psum[(b * 32 + mm) * 64 + p] * (1.0f / 512.0f);
    Pl[mm * 68 + p] = v;
    pooledws[(b * 32 + mm) * 64 + p] = v;
  }
  __syncthreads();

  // t0 = pooled @ pool_proj + b + pos_inter
  for (int g = tid; g < 1024; g += 256) {
    int mm = g >> 5, j0 = (g & 31) * 4;
    float4 pv = *(const float4*)(pos + mm * 128 + j0);
    float a0 = ppb[j0] + pv.x, a1 = ppb[j0 + 1] + pv.y;
    float a2 = ppb[j0 + 2] + pv.z, a3 = ppb[j0 + 3] + pv.w;
    const float* ip = Pl + mm * 68;
#pragma unroll 4
    for (int p = 0; p < 64; ++p) {
      float s = ip[p];
      float4 w4 = *(const float4*)(ppw + p * 128 + j0);
      a0 = fmaf(s, w4.x, a0); a1 = fmaf(s, w4.y, a1);
      a2 = fmaf(s, w4.z, a2); a3 = fmaf(s, w4.w, a3);
    }
    float* op = T + mm * 132 + j0;
    op[0] = a0; op[1] = a1; op[2] = a2; op[3] = a3;
  }
  __syncthreads();

  for (int l = 0; l < NL_; ++l) {
    ln_rows(T, Y, l1g + l * 128, l1b + l * 128, mst);
    gemm_lds<128, 128, 0>(Y, 132, wq + l * 16384, bq + l * 128, Q, 132);  __syncthreads();
    gemm_lds<128, 128, 0>(Y, 132, wk + l * 16384, bk + l * 128, Kb, 132); __syncthreads();
    gemm_lds<128, 128, 0>(Y, 132, wv + l * 16384, bv + l * 128, V, 132);  __syncthreads();

    float* S = FF;  // 32x33
    for (int h = 0; h < NH_; ++h) {
      int hb = h * 16;
      for (int idx = tid; idx < 1024; idx += 256) {
        int mm = idx >> 5, n = idx & 31;
        float a = 0;
#pragma unroll
        for (int d = 0; d < 16; ++d) a = fmaf(Q[mm * 132 + hb + d], Kb[n * 132 + hb + d], a);
        a *= 0.25f;
        if (mkv[n] == 0.0f) a -= 1e9f;
        S[mm * 33 + n] = a;
      }
      __syncthreads();
      if (tid < 32) {
        float* sr = S + tid * 33;
        float mx = sr[0];
        for (int n = 1; n < 32; ++n) mx = fmaxf(mx, sr[n]);
        float sum = 0;
        for (int n = 0; n < 32; ++n) { float e = __expf(sr[n] - mx); sr[n] = e; sum += e; }
        float inv = 1.0f / sum;
        for (int n = 0; n < 32; ++n) sr[n] *= inv;
      }
      __syncthreads();
      for (int idx = tid; idx < 512; idx += 256) {
        int mm = idx >> 4, d = idx & 15;
        float a = 0;
#pragma unroll 4
        for (int n = 0; n < 32; ++n) a = fmaf(S[mm * 33 + n], V[n * 132 + hb + d], a);
        Y[mm * 132 + hb + d] = a;  // Y reused as attention-output buffer
      }
      __syncthreads();
    }
    gemm_lds<128, 128, 1>(Y, 132, wo + l * 16384, bo + l * 128, T, 132); __syncthreads();
    ln_rows(T, Q, l2g + l * 128, l2b + l * 128, mst);
    gemm_lds<128, 256, 2>(Q, 132, f1w + l * 32768, f1b + l * 256, FF, 260); __syncthreads();
    gemm_lds<256, 128, 1>(FF, 260, f2w + l * 32768, f2b + l * 128, T, 132); __syncthreads();
  }

  // ctx = LN(t) * mask ; g = [mean_ctx | max_ctx]
  ln_rows(T, Y, og_, ob_, mst);
  for (int idx = tid; idx < 4096; idx += 256) {
    int mm = idx >> 7, j = idx & 127;
    float c = Y[mm * 132 + j] * mkv[mm];
    Y[mm * 132 + j] = c;
    ctxws[(b * 32 + mm) * 128 + j] = c;
  }
  __syncthreads();
  if (tid < 128) {
    float cnt = 0;
    for (int mm = 0; mm < 32; ++mm) cnt += mkv[mm];
    cnt = fmaxf(cnt, 1.0f);
    float s = 0, mx = -1e9f;
    for (int mm = 0; mm < 32; ++mm) {
      float v = Y[mm * 132 + tid];
      s += v;
      if (mkv[mm] > 0.0f) mx = fmaxf(mx, v);
    }
    gws[b * 256 + tid] = s / cnt;
    gws[b * 256 + 128 + tid] = mx;
  }
}

// ---------------------------------------------------------------------------
// Kernel 3: MoE gates (top-2 + softmax weights) for 16+16+512 rows
// ---------------------------------------------------------------------------
__global__ __launch_bounds__(64) void gates_kernel(
    const float* __restrict__ gws, const float* __restrict__ ctxws,
    const float* __restrict__ gfw, const float* __restrict__ gfb,
    const float* __restrict__ glw, const float* __restrict__ glb,
    const float* __restrict__ grw, const float* __restrict__ grb,
    int* __restrict__ gidx, float* __restrict__ gwt) {
  __shared__ float lg[16];
  int r = blockIdx.x;
  const float* in; const float* W; const float* Bb; int dl;
  if (r < 16)      { in = gws + r * 256;          W = gfw; Bb = gfb; dl = 256; }
  else if (r < 32) { in = gws + (r - 16) * 256;   W = glw; Bb = glb; dl = 256; }
  else             { in = ctxws + (r - 32) * 128; W = grw; Bb = grb; dl = 128; }
  if (threadIdx.x < 16) {
    float a = Bb[threadIdx.x];
    for (int d = 0; d < dl; ++d) a = fmaf(in[d], W[d * 16 + threadIdx.x], a);
    lg[threadIdx.x] = a;
  }
  __syncthreads();
  if (threadIdx.x == 0) {
    int i0 = 0; float v0 = lg[0];
    for (int e = 1; e < 16; ++e) if (lg[e] > v0) { v0 = lg[e]; i0 = e; }
    int i1 = (i0 == 0) ? 1 : 0; float v1 = lg[i1];
    for (int e = 0; e < 16; ++e) if (e != i0 && lg[e] > v1) { v1 = lg[e]; i1 = e; }
    float e1 = __expf(v1 - v0);
    float w0 = 1.0f / (1.0f + e1);
    gidx[2 * r] = i0; gidx[2 * r + 1] = i1;
    gwt[2 * r] = w0;  gwt[2 * r + 1] = 1.0f - w0;
  }
}

// ---------------------------------------------------------------------------
// Kernel 4: MoE experts — one block per row, both selected experts
// ---------------------------------------------------------------------------
__global__ __launch_bounds__(256) void moe_kernel(
    const float* __restrict__ gws, const float* __restrict__ ctxws,
    const float* __restrict__ ew1, const float* __restrict__ eb1,
    const float* __restrict__ ew2, const float* __restrict__ eb2,
    const int* __restrict__ gidx, const float* __restrict__ gwt,
    float* __restrict__ yf, float* __restrict__ yfail, float* __restrict__ yrca) {
  __shared__ float xin[256];
  __shared__ float H[512];
  int r = blockIdx.x;
  int tid = threadIdx.x;
  if (r < 32) {
    int rr = (r < 16) ? r : r - 16;
    xin[tid] = gws[rr * 256 + tid];
  } else {
    int rr = r - 32;
    int bb = rr >> 5;
    if (tid < 128) xin[tid] = ctxws[rr * 128 + tid];
    else           xin[tid] = gws[bb * 256 + (tid - 128)];  // mean_ctx
  }
  float yacc = 0.f;
  for (int tk = 0; tk < 2; ++tk) {
    int e = gidx[2 * r + tk];
    float wgt = gwt[2 * r + tk];
    __syncthreads();
    const float* W1 = ew1 + (size_t)e * (256 * 512);
    for (int h = tid; h < 512; h += 256) {
      float a = eb1[e * 512 + h];
#pragma unroll 4
      for (int d = 0; d < 256; ++d) a = fmaf(xin[d], W1[d * 512 + h], a);
      H[h] = fmaxf(a, 0.f);
    }
    __syncthreads();
    if (tid < 128) {
      const float* W2 = ew2 + (size_t)e * (512 * 128);
      float a = eb2[e * 128 + tid];
#pragma unroll 4
      for (int h = 0; h < 512; ++h) a = fmaf(H[h], W2[h * 128 + tid], a);
      yacc += wgt * a;
    }
  }
  if (tid < 128) {
    float* dst = (r < 16) ? (yf + r * 128) : (r < 32) ? (yfail + (r - 16) * 128)
                                                      : (yrca + (r - 32) * 128);
    dst[tid] = yacc;
  }
}

// ---------------------------------------------------------------------------
// Kernel 5: output heads (pred / fail / rca) -> fp32 output
// ---------------------------------------------------------------------------
__global__ __launch_bounds__(192) void heads_kernel(
    const float* __restrict__ x, const float* __restrict__ mask,
    const float* __restrict__ pooledws, const float* __restrict__ ctxws,
    const float* __restrict__ yf, const float* __restrict__ yfail, const float* __restrict__ yrca,
    const float* __restrict__ pw, const float* __restrict__ pb,
    const float* __restrict__ fw, const float* __restrict__ fb,
    const float* __restrict__ rw, const float* __restrict__ rb,
    float* __restrict__ out) {
  __shared__ float yfb[128];
  int b = blockIdx.x, t = threadIdx.x;
  if (t < 128) yfb[t] = yf[b * 128 + t];
  __syncthreads();
  if (t < 96) {
    int mm = t / 3, o = t - mm * 3;
    int s = b * 32 + mm;
    float a = pb[o];
    const float* pl = pooledws + s * 64;
    for (int i = 0; i < 64; ++i) a = fmaf(pl[i], pw[i * 3 + o], a);
    const float* cx = ctxws + s * 128;
    for (int i = 0; i < 128; ++i) a = fmaf(cx[i], pw[(64 + i) * 3 + o], a);
    for (int i = 0; i < 128; ++i) a = fmaf(yfb[i], pw[(192 + i) * 3 + o], a);
    a += x[(b * 512 + 511) * 32 + mm] * mask[b * 32 + mm];
    out[b * 131 + t] = a;
  } else if (t < 99) {
    int o = t - 96;
    float a = fb[o];
    const float* yl = yfail + b * 128;
    for (int i = 0; i < 128; ++i) a = fmaf(yl[i], fw[i * 3 + o], a);
    out[b * 131 + 96 + o] = a;
  } else if (t < 131) {
    int mm = t - 99;
    int s = b * 32 + mm;
    float a = rb[0];
    const float* pl = pooledws + s * 64;
    for (int i = 0; i < 64; ++i) a = fmaf(pl[i], rw[i], a);
    const float* cx = ctxws + s * 128;
    for (int i = 0; i < 128; ++i) a = fmaf(cx[i], rw[64 + i], a);
    const float* yr = yrca + s * 128;
    for (int i = 0; i < 128; ++i) a = fmaf(yr[i], rw[192 + i], a);
    out[b * 131 + 99 + mm] = a;
  }
}

// ---------------------------------------------------------------------------
extern "C" void kernel_launch(void* const* d_in, const int* in_sizes, int n_in,
                              void* d_out, int out_size, void* d_ws, size_t ws_size,
                              hipStream_t stream) {
  (void)in_sizes; (void)n_in; (void)out_size; (void)ws_size;
  const float* x    = (const float*)d_in[0];
  const float* msk  = (const float*)d_in[1];
  const float* epw  = (const float*)d_in[2];
  const float* epb  = (const float*)d_in[3];
  const float* tw1  = (const float*)d_in[4];
  const float* tb1  = (const float*)d_in[5];
  const float* tw2  = (const float*)d_in[6];
  const float* tb2  = (const float*)d_in[7];
  const float* eng  = (const float*)d_in[8];
  const float* enb  = (const float*)d_in[9];
  const float* ppw  = (const float*)d_in[10];
  const float* ppb  = (const float*)d_in[11];
  const float* pos  = (const float*)d_in[12];
  const float* twq  = (const float*)d_in[13];
  const float* tbq  = (const float*)d_in[14];
  const float* twk  = (const float*)d_in[15];
  const float* tbk  = (const float*)d_in[16];
  const float* twv  = (const float*)d_in[17];
  const float* tbv  = (const float*)d_in[18];
  const float* two  = (const float*)d_in[19];
  const float* tbo  = (const float*)d_in[20];
  const float* l1g  = (const float*)d_in[21];
  const float* l1b  = (const float*)d_in[22];
  const float* l2g  = (const float*)d_in[23];
  const float* l2b  = (const float*)d_in[24];
  const float* f1w  = (const float*)d_in[25];
  const float* f1b  = (const float*)d_in[26];
  const float* f2w  = (const float*)d_in[27];
  const float* f2b  = (const float*)d_in[28];
  const float* tog  = (const float*)d_in[29];
  const float* tob  = (const float*)d_in[30];
  const float* ew1  = (const float*)d_in[31];
  const float* eb1  = (const float*)d_in[32];
  const float* ew2  = (const float*)d_in[33];
  const float* eb2  = (const float*)d_in[34];
  const float* gfw  = (const float*)d_in[35];
  const float* gfb  = (const float*)d_in[36];
  const float* glw  = (const float*)d_in[37];
  const float* glb  = (const float*)d_in[38];
  const float* grw  = (const float*)d_in[39];
  const float* grb  = (const float*)d_in[40];
  const float* prw  = (const float*)d_in[41];
  const float* prb  = (const float*)d_in[42];
  const float* fw   = (const float*)d_in[43];
  const float* fb   = (const float*)d_in[44];
  const float* rw   = (const float*)d_in[45];
  const float* rb   = (const float*)d_in[46];

  float* ws      = (float*)d_ws;
  float* psum    = ws;                 // 512*64
  float* pooledw = psum + 32768;       // 512*64
  float* ctxw    = pooledw + 32768;    // 512*128
  float* gwsb    = ctxw + 65536;       // 16*256
  float* yf      = gwsb + 4096;        // 16*128
  float* yfail   = yf + 2048;          // 16*128
  float* yrca    = yfail + 2048;       // 512*128
  int*   gidx    = (int*)(yrca + 65536);   // 544*2
  float* gwt     = (float*)(gidx + 1088);  // 544*2

  hipFuncSetAttribute((const void*)tcn_kernel, hipFuncAttributeMaxDynamicSharedMemorySize, 147584);
  hipFuncSetAttribute((const void*)xf_kernel,  hipFuncAttributeMaxDynamicSharedMemorySize, 126848);

  hipMemsetAsync(psum, 0, 32768 * sizeof(float), stream);
  tcn_kernel<<<2048, 256, 147584, stream>>>(x, msk, epw, epb, tw1, tb1, tw2, tb2, eng, enb, psum);
  xf_kernel<<<16, 256, 126848, stream>>>(psum, msk, ppw, ppb, pos,
                                         twq, tbq, twk, tbk, twv, tbv, two, tbo,
                                         l1g, l1b, l2g, l2b, f1w, f1b, f2w, f2b,
                                         tog, tob, pooledw, ctxw, gwsb);
  gates_kernel<<<544, 64, 0, stream>>>(gwsb, ctxw, gfw, gfb, glw, glb, grw, grb, gidx, gwt);
  moe_kernel<<<544, 256, 0, stream>>>(gwsb, ctxw, ew1, eb1, ew2, eb2, gidx, gwt, yf, yfail, yrca);
  heads_kernel<<<16, 192, 0, stream>>>(x, msk, pooledw, ctxw, yf, yfail, yrca,
                                       prw, prb, fw, fb, rw, rb, (float*)d_out);
}

// Round 3
// 880.564 us; speedup vs baseline: 1.7049x; 1.7049x over previous
//
#include <hip/hip_runtime.h>
#include <hip/hip_bf16.h>

// Problem constants (FoundationalTimeSeriesModel)
#define B_   16
#define L_   512
#define M_   32
#define P_   64
#define D_   128
#define NH_  8
#define DH_  16
#define NL_  2
#define E_   16
#define EH_  512
#define O_   128

// TCN chunking (MFMA version)
#define CH    128   // valid outputs per chunk
#define HALO  60    // receptive field of the 4-level TCN
#define PADF  16    // front pad rows (max tap lookback 2*8=16)
#define ROWS_ 208   // PADF + 192 (12 n-tiles of 16)
#define LDA_  72    // bf16 leading dim (stride 144B -> 2-way-free banks, 16B aligned)

typedef short  bf16x8 __attribute__((ext_vector_type(8)));
typedef float  f32x4  __attribute__((ext_vector_type(4)));
typedef unsigned short us4 __attribute__((ext_vector_type(4)));

__device__ __forceinline__ float bf2f(unsigned short h) {
  unsigned u = ((unsigned)h) << 16; float f; __builtin_memcpy(&f, &u, 4); return f;
}
__device__ __forceinline__ unsigned short f2bf(float f) {
  unsigned u; __builtin_memcpy(&u, &f, 4);
  u += 0x7fffu + ((u >> 16) & 1);            // RNE (finite inputs only)
  return (unsigned short)(u >> 16);
}

// ---------------------------------------------------------------------------
// Kernel 1: per-(sequence,chunk) MFMA TCN encoder + layernorm + mean-pool
// Activations: bf16 LDS [row=position][ch], LDA_=72. Weights: bf16 [tap][o][c].
// ---------------------------------------------------------------------------
__device__ __forceinline__ void stage_wb(unsigned short* Wt, float* Bs,
                                         const float* __restrict__ w,
                                         const float* __restrict__ b) {
  // global [o][c][k] (o*192+c*3+k) -> LDS [k][o][c] bf16, pack c-pairs
  for (int idx = threadIdx.x; idx < 6144; idx += 256) {
    int t   = idx >> 11;        // tap
    int rem = idx & 2047;
    int o   = rem >> 5;
    int c0  = (rem & 31) * 2;
    float a0 = w[o * 192 + c0 * 3 + t];
    float a1 = w[o * 192 + (c0 + 1) * 3 + t];
    unsigned v = (unsigned)f2bf(a0) | ((unsigned)f2bf(a1) << 16);
    *(unsigned*)(Wt + (t * 64 + o) * LDA_ + c0) = v;
  }
  if (threadIdx.x < 64) Bs[threadIdx.x] = b[threadIdx.x];
}

template <int DIL, bool RES>
__device__ __forceinline__ void conv_mfma(const unsigned short* __restrict__ IN,
                                          unsigned short* __restrict__ OUT,
                                          const unsigned short* __restrict__ Wt,
                                          const float* __restrict__ Bs, bool zh) {
  const int tid  = threadIdx.x;
  const int wid  = tid >> 6;      // 4 waves: wave owns n-tiles {3w..3w+2}, all 4 o-tiles
  const int lane = tid & 63;
  const int fr   = lane & 15;
  const int g    = lane >> 4;

  // A fragments (weights), reused across the wave's 3 n-tiles
  bf16x8 Af[4][6];
#pragma unroll
  for (int ot = 0; ot < 4; ++ot)
#pragma unroll
    for (int t = 0; t < 3; ++t)
#pragma unroll
      for (int kh = 0; kh < 2; ++kh)
        Af[ot][t * 2 + kh] =
            *(const bf16x8*)(Wt + (t * 64 + ot * 16 + fr) * LDA_ + kh * 32 + g * 8);
  float bv[4][4];
#pragma unroll
  for (int ot = 0; ot < 4; ++ot)
#pragma unroll
    for (int j = 0; j < 4; ++j) bv[ot][j] = Bs[ot * 16 + g * 4 + j];

  for (int ntl = 0; ntl < 3; ++ntl) {
    const int nt = wid * 3 + ntl;
    const int rb = PADF + nt * 16 + fr;       // output row for this lane
    bf16x8 Bf[6];
#pragma unroll
    for (int t = 0; t < 3; ++t) {
      int r = rb + (t - 2) * DIL;             // causal taps at l-2d, l-d, l
#pragma unroll
      for (int kh = 0; kh < 2; ++kh)
        Bf[t * 2 + kh] = *(const bf16x8*)(IN + r * LDA_ + kh * 32 + g * 8);
    }
    f32x4 acc[4];
#pragma unroll
    for (int ot = 0; ot < 4; ++ot) {
      f32x4 a; a[0] = bv[ot][0]; a[1] = bv[ot][1]; a[2] = bv[ot][2]; a[3] = bv[ot][3];
      acc[ot] = a;
    }
#pragma unroll
    for (int f = 0; f < 6; ++f)
#pragma unroll
      for (int ot = 0; ot < 4; ++ot)
        acc[ot] = __builtin_amdgcn_mfma_f32_16x16x32_bf16(Af[ot][f], Bf[f], acc[ot], 0, 0, 0);

    // epilogue: relu (+residual relu), chunk-0 zero-pad emulation, store bf16
    const float zm = (zh && rb < PADF + HALO) ? 0.f : 1.f;
#pragma unroll
    for (int ot = 0; ot < 4; ++ot) {
      unsigned short* op = OUT + rb * LDA_ + ot * 16 + g * 4;
      us4 old;
      if (RES) old = *(const us4*)op;
      us4 st;
#pragma unroll
      for (int j = 0; j < 4; ++j) {
        float v = fmaxf(acc[ot][j], 0.f);
        if (RES) v = fmaxf(v + bf2f(old[j]), 0.f);
        st[j] = f2bf(v * zm);
      }
      *(us4*)op = st;
    }
  }
}

__global__ __launch_bounds__(256) void tcn_kernel(
    const float* __restrict__ x, const float* __restrict__ mask,
    const float* __restrict__ pw, const float* __restrict__ pb,
    const float* __restrict__ w1, const float* __restrict__ b1,
    const float* __restrict__ w2, const float* __restrict__ b2,
    const float* __restrict__ lng, const float* __restrict__ lnb,
    float* __restrict__ psum) {
  extern __shared__ unsigned short smu[];
  unsigned short* A  = smu;                    // 208*72 bf16
  unsigned short* Bq = A + ROWS_ * LDA_;       // 208*72 bf16
  unsigned short* Wt = Bq + ROWS_ * LDA_;      // 3*64*72 bf16
  float* Bs  = (float*)(Wt + 3 * 64 * LDA_);   // 64 f32 bias
  float* mst = Bs + 64;                        // 256 f32 LN stats

  const int bx = blockIdx.x;
  const int seq = bx >> 2;
  const int chunk = bx & 3;
  const int b = seq >> 5;
  const int m = seq & 31;
  if (mask[b * M_ + m] == 0.0f) return;        // masked sensor: output unused
  const int tid = threadIdx.x;
  const bool zh = (chunk == 0);

  // stage input: proj + positional encoding, f32 -> bf16, layout [row][ch]
  const int lbase = chunk * CH - HALO;
  for (int idx = tid; idx < ROWS_ * 64; idx += 256) {
    int r = idx >> 6, c = idx & 63;
    int w = r - PADF, l = lbase + w;
    float v = 0.f;
    if (w >= 0 && w < CH + HALO && l >= 0 && l < L_) {
      float xv = x[(b * L_ + l) * M_ + m];
      float dv = expf(-0.14391157f * (float)(c & ~1));  // ln(1e4)/64
      float ang = (float)l * dv;
      float pe = (c & 1) ? cosf(ang) : sinf(ang);
      v = fmaf(xv, pw[c], pb[c]) + pe;
    }
    A[r * LDA_ + c] = f2bf(v);
  }
  for (int idx = tid; idx < PADF * LDA_; idx += 256) Bq[idx] = 0;  // front rows of ping buffer
  __syncthreads();

#define LEVEL(DILV, li)                                                     \
  stage_wb(Wt, Bs, w1 + (li) * 12288, b1 + (li) * 64); __syncthreads();     \
  conv_mfma<DILV, false>(A, Bq, Wt, Bs, zh); __syncthreads();               \
  stage_wb(Wt, Bs, w2 + (li) * 12288, b2 + (li) * 64); __syncthreads();     \
  conv_mfma<DILV, true>(Bq, A, Wt, Bs, zh); __syncthreads();
  LEVEL(1, 0) LEVEL(2, 1) LEVEL(4, 2) LEVEL(8, 3)
#undef LEVEL

  // LayerNorm over channels (contiguous!) at each valid position
  if (tid < CH) {
    int r = PADF + HALO + tid;
    float s = 0.f, ss = 0.f;
    for (int c = 0; c < 64; ++c) { float v = bf2f(A[r * LDA_ + c]); s += v; ss += v * v; }
    float mu = s * 0.015625f;
    float var = fmaxf(ss * 0.015625f - mu * mu, 0.0f);
    mst[tid] = mu;
    mst[CH + tid] = rsqrtf(var + 1e-5f);
  }
  __syncthreads();
  {
    int p = tid & 63, q = tid >> 6;
    float accp = 0.f;
    int r0 = PADF + HALO + q * 32;
    for (int r = r0; r < r0 + 32; ++r)
      accp += (bf2f(A[r * LDA_ + p]) - mst[r - PADF - HALO]) * mst[CH + r - PADF - HALO];
    atomicAdd(&psum[seq * 64 + p], lng[p] * accp + 32.0f * lnb[p]);
  }
}

// ---------------------------------------------------------------------------
// Kernel 2: per-batch transformer (2 layers) + ctx / g computation
// ---------------------------------------------------------------------------
template <int KD, int NJ, int MODE>  // MODE 0: store, 1: +=, 2: relu-store
__device__ __forceinline__ void gemm_lds(const float* __restrict__ In, int ldin,
                                         const float* __restrict__ W, const float* __restrict__ bias,
                                         float* __restrict__ Out, int ldout) {
  constexpr int NG = 32 * NJ / 4;
  for (int g = threadIdx.x; g < NG; g += 256) {
    int mm = g / (NJ / 4);
    int j0 = (g - mm * (NJ / 4)) * 4;
    float a0 = bias[j0], a1 = bias[j0 + 1], a2 = bias[j0 + 2], a3 = bias[j0 + 3];
    const float* ip = In + mm * ldin;
#pragma unroll 4
    for (int p = 0; p < KD; ++p) {
      float s = ip[p];
      float4 w4 = *(const float4*)(W + p * NJ + j0);
      a0 = fmaf(s, w4.x, a0); a1 = fmaf(s, w4.y, a1);
      a2 = fmaf(s, w4.z, a2); a3 = fmaf(s, w4.w, a3);
    }
    float* op = Out + mm * ldout + j0;
    if (MODE == 0)      { op[0] = a0; op[1] = a1; op[2] = a2; op[3] = a3; }
    else if (MODE == 1) { op[0] += a0; op[1] += a1; op[2] += a2; op[3] += a3; }
    else                { op[0] = fmaxf(a0, 0.f); op[1] = fmaxf(a1, 0.f);
                          op[2] = fmaxf(a2, 0.f); op[3] = fmaxf(a3, 0.f); }
  }
}

__device__ __forceinline__ void ln_rows(const float* __restrict__ In, float* __restrict__ Out,
                                        const float* __restrict__ g, const float* __restrict__ b,
                                        float* mst) {
  if (threadIdx.x < 32) {
    const float* ip = In + threadIdx.x * 132;
    float s = 0, ss = 0;
    for (int j = 0; j < 128; ++j) { float v = ip[j]; s += v; ss += v * v; }
    float mu = s * 0.0078125f;
    float var = fmaxf(ss * 0.0078125f - mu * mu, 0.f);
    mst[threadIdx.x] = mu;
    mst[32 + threadIdx.x] = rsqrtf(var + 1e-5f);
  }
  __syncthreads();
  for (int idx = threadIdx.x; idx < 4096; idx += 256) {
    int mm = idx >> 7, j = idx & 127;
    Out[mm * 132 + j] = (In[mm * 132 + j] - mst[mm]) * mst[32 + mm] * g[j] + b[j];
  }
  __syncthreads();
}

__global__ __launch_bounds__(256) void xf_kernel(
    const float* __restrict__ psum, const float* __restrict__ mask,
    const float* __restrict__ ppw, const float* __restrict__ ppb, const float* __restrict__ pos,
    const float* __restrict__ wq, const float* __restrict__ bq,
    const float* __restrict__ wk, const float* __restrict__ bk,
    const float* __restrict__ wv, const float* __restrict__ bv,
    const float* __restrict__ wo, const float* __restrict__ bo,
    const float* __restrict__ l1g, const float* __restrict__ l1b,
    const float* __restrict__ l2g, const float* __restrict__ l2b,
    const float* __restrict__ f1w, const float* __restrict__ f1b,
    const float* __restrict__ f2w, const float* __restrict__ f2b,
    const float* __restrict__ og_, const float* __restrict__ ob_,
    float* __restrict__ pooledws, float* __restrict__ ctxws, float* __restrict__ gws) {
  extern __shared__ float sm[];
  float* T   = sm;            // 32*132
  float* Y   = T + 4224;
  float* Q   = Y + 4224;
  float* Kb  = Q + 4224;
  float* V   = Kb + 4224;
  float* FF  = V + 4224;      // 32*260 (also reused as 32x33 score buffer)
  float* Pl  = FF + 8320;     // 32*68
  float* mst = Pl + 2176;     // 64
  float* mkv = mst + 64;      // 32     total = 31712 floats = 126848 B
  const int b = blockIdx.x;
  const int tid = threadIdx.x;

  if (tid < 32) mkv[tid] = mask[b * 32 + tid];
  for (int idx = tid; idx < 2048; idx += 256) {
    int mm = idx >> 6, p = idx & 63;
    float v = mask[b * 32 + mm] * psum[(b * 32 + mm) * 64 + p] * (1.0f / 512.0f);
    Pl[mm * 68 + p] = v;
    pooledws[(b * 32 + mm) * 64 + p] = v;
  }
  __syncthreads();

  // t0 = pooled @ pool_proj + b + pos_inter
  for (int g = tid; g < 1024; g += 256) {
    int mm = g >> 5, j0 = (g & 31) * 4;
    float4 pv = *(const float4*)(pos + mm * 128 + j0);
    float a0 = ppb[j0] + pv.x, a1 = ppb[j0 + 1] + pv.y;
    float a2 = ppb[j0 + 2] + pv.z, a3 = ppb[j0 + 3] + pv.w;
    const float* ip = Pl + mm * 68;
#pragma unroll 4
    for (int p = 0; p < 64; ++p) {
      float s = ip[p];
      float4 w4 = *(const float4*)(ppw + p * 128 + j0);
      a0 = fmaf(s, w4.x, a0); a1 = fmaf(s, w4.y, a1);
      a2 = fmaf(s, w4.z, a2); a3 = fmaf(s, w4.w, a3);
    }
    float* op = T + mm * 132 + j0;
    op[0] = a0; op[1] = a1; op[2] = a2; op[3] = a3;
  }
  __syncthreads();

  for (int l = 0; l < NL_; ++l) {
    ln_rows(T, Y, l1g + l * 128, l1b + l * 128, mst);
    gemm_lds<128, 128, 0>(Y, 132, wq + l * 16384, bq + l * 128, Q, 132);  __syncthreads();
    gemm_lds<128, 128, 0>(Y, 132, wk + l * 16384, bk + l * 128, Kb, 132); __syncthreads();
    gemm_lds<128, 128, 0>(Y, 132, wv + l * 16384, bv + l * 128, V, 132);  __syncthreads();

    float* S = FF;  // 32x33
    for (int h = 0; h < NH_; ++h) {
      int hb = h * 16;
      for (int idx = tid; idx < 1024; idx += 256) {
        int mm = idx >> 5, n = idx & 31;
        float a = 0;
#pragma unroll
        for (int d = 0; d < 16; ++d) a = fmaf(Q[mm * 132 + hb + d], Kb[n * 132 + hb + d], a);
        a *= 0.25f;
        if (mkv[n] == 0.0f) a -= 1e9f;
        S[mm * 33 + n] = a;
      }
      __syncthreads();
      if (tid < 32) {
        float* sr = S + tid * 33;
        float mx = sr[0];
        for (int n = 1; n < 32; ++n) mx = fmaxf(mx, sr[n]);
        float sum = 0;
        for (int n = 0; n < 32; ++n) { float e = __expf(sr[n] - mx); sr[n] = e; sum += e; }
        float inv = 1.0f / sum;
        for (int n = 0; n < 32; ++n) sr[n] *= inv;
      }
      __syncthreads();
      for (int idx = tid; idx < 512; idx += 256) {
        int mm = idx >> 4, d = idx & 15;
        float a = 0;
#pragma unroll 4
        for (int n = 0; n < 32; ++n) a = fmaf(S[mm * 33 + n], V[n * 132 + hb + d], a);
        Y[mm * 132 + hb + d] = a;  // Y reused as attention-output buffer
      }
      __syncthreads();
    }
    gemm_lds<128, 128, 1>(Y, 132, wo + l * 16384, bo + l * 128, T, 132); __syncthreads();
    ln_rows(T, Q, l2g + l * 128, l2b + l * 128, mst);
    gemm_lds<128, 256, 2>(Q, 132, f1w + l * 32768, f1b + l * 256, FF, 260); __syncthreads();
    gemm_lds<256, 128, 1>(FF, 260, f2w + l * 32768, f2b + l * 128, T, 132); __syncthreads();
  }

  // ctx = LN(t) * mask ; g = [mean_ctx | max_ctx]
  ln_rows(T, Y, og_, ob_, mst);
  for (int idx = tid; idx < 4096; idx += 256) {
    int mm = idx >> 7, j = idx & 127;
    float c = Y[mm * 132 + j] * mkv[mm];
    Y[mm * 132 + j] = c;
    ctxws[(b * 32 + mm) * 128 + j] = c;
  }
  __syncthreads();
  if (tid < 128) {
    float cnt = 0;
    for (int mm = 0; mm < 32; ++mm) cnt += mkv[mm];
    cnt = fmaxf(cnt, 1.0f);
    float s = 0, mx = -1e9f;
    for (int mm = 0; mm < 32; ++mm) {
      float v = Y[mm * 132 + tid];
      s += v;
      if (mkv[mm] > 0.0f) mx = fmaxf(mx, v);
    }
    gws[b * 256 + tid] = s / cnt;
    gws[b * 256 + 128 + tid] = mx;
  }
}

// ---------------------------------------------------------------------------
// Kernel 3: MoE gates (top-2 + softmax weights) for 16+16+512 rows
// ---------------------------------------------------------------------------
__global__ __launch_bounds__(64) void gates_kernel(
    const float* __restrict__ gws, const float* __restrict__ ctxws,
    const float* __restrict__ gfw, const float* __restrict__ gfb,
    const float* __restrict__ glw, const float* __restrict__ glb,
    const float* __restrict__ grw, const float* __restrict__ grb,
    int* __restrict__ gidx, float* __restrict__ gwt) {
  __shared__ float lg[16];
  int r = blockIdx.x;
  const float* in; const float* W; const float* Bb; int dl;
  if (r < 16)      { in = gws + r * 256;          W = gfw; Bb = gfb; dl = 256; }
  else if (r < 32) { in = gws + (r - 16) * 256;   W = glw; Bb = glb; dl = 256; }
  else             { in = ctxws + (r - 32) * 128; W = grw; Bb = grb; dl = 128; }
  if (threadIdx.x < 16) {
    float a = Bb[threadIdx.x];
    for (int d = 0; d < dl; ++d) a = fmaf(in[d], W[d * 16 + threadIdx.x], a);
    lg[threadIdx.x] = a;
  }
  __syncthreads();
  if (threadIdx.x == 0) {
    int i0 = 0; float v0 = lg[0];
    for (int e = 1; e < 16; ++e) if (lg[e] > v0) { v0 = lg[e]; i0 = e; }
    int i1 = (i0 == 0) ? 1 : 0; float v1 = lg[i1];
    for (int e = 0; e < 16; ++e) if (e != i0 && lg[e] > v1) { v1 = lg[e]; i1 = e; }
    float e1 = __expf(v1 - v0);
    float w0 = 1.0f / (1.0f + e1);
    gidx[2 * r] = i0; gidx[2 * r + 1] = i1;
    gwt[2 * r] = w0;  gwt[2 * r + 1] = 1.0f - w0;
  }
}

// ---------------------------------------------------------------------------
// Kernel 4: MoE experts — one block per row, both selected experts
// ---------------------------------------------------------------------------
__global__ __launch_bounds__(256) void moe_kernel(
    const float* __restrict__ gws, const float* __restrict__ ctxws,
    const float* __restrict__ ew1, const float* __restrict__ eb1,
    const float* __restrict__ ew2, const float* __restrict__ eb2,
    const int* __restrict__ gidx, const float* __restrict__ gwt,
    float* __restrict__ yf, float* __restrict__ yfail, float* __restrict__ yrca) {
  __shared__ float xin[256];
  __shared__ float H[512];
  int r = blockIdx.x;
  int tid = threadIdx.x;
  if (r < 32) {
    int rr = (r < 16) ? r : r - 16;
    xin[tid] = gws[rr * 256 + tid];
  } else {
    int rr = r - 32;
    int bb = rr >> 5;
    if (tid < 128) xin[tid] = ctxws[rr * 128 + tid];
    else           xin[tid] = gws[bb * 256 + (tid - 128)];  // mean_ctx
  }
  float yacc = 0.f;
  for (int tk = 0; tk < 2; ++tk) {
    int e = gidx[2 * r + tk];
    float wgt = gwt[2 * r + tk];
    __syncthreads();
    const float* W1 = ew1 + (size_t)e * (256 * 512);
    for (int h = tid; h < 512; h += 256) {
      float a = eb1[e * 512 + h];
#pragma unroll 4
      for (int d = 0; d < 256; ++d) a = fmaf(xin[d], W1[d * 512 + h], a);
      H[h] = fmaxf(a, 0.f);
    }
    __syncthreads();
    if (tid < 128) {
      const float* W2 = ew2 + (size_t)e * (512 * 128);
      float a = eb2[e * 128 + tid];
#pragma unroll 4
      for (int h = 0; h < 512; ++h) a = fmaf(H[h], W2[h * 128 + tid], a);
      yacc += wgt * a;
    }
  }
  if (tid < 128) {
    float* dst = (r < 16) ? (yf + r * 128) : (r < 32) ? (yfail + (r - 16) * 128)
                                                      : (yrca + (r - 32) * 128);
    dst[tid] = yacc;
  }
}

// ---------------------------------------------------------------------------
// Kernel 5: output heads (pred / fail / rca) -> fp32 output
// ---------------------------------------------------------------------------
__global__ __launch_bounds__(192) void heads_kernel(
    const float* __restrict__ x, const float* __restrict__ mask,
    const float* __restrict__ pooledws, const float* __restrict__ ctxws,
    const float* __restrict__ yf, const float* __restrict__ yfail, const float* __restrict__ yrca,
    const float* __restrict__ pw, const float* __restrict__ pb,
    const float* __restrict__ fw, const float* __restrict__ fb,
    const float* __restrict__ rw, const float* __restrict__ rb,
    float* __restrict__ out) {
  __shared__ float yfb[128];
  int b = blockIdx.x, t = threadIdx.x;
  if (t < 128) yfb[t] = yf[b * 128 + t];
  __syncthreads();
  if (t < 96) {
    int mm = t / 3, o = t - mm * 3;
    int s = b * 32 + mm;
    float a = pb[o];
    const float* pl = pooledws + s * 64;
    for (int i = 0; i < 64; ++i) a = fmaf(pl[i], pw[i * 3 + o], a);
    const float* cx = ctxws + s * 128;
    for (int i = 0; i < 128; ++i) a = fmaf(cx[i], pw[(64 + i) * 3 + o], a);
    for (int i = 0; i < 128; ++i) a = fmaf(yfb[i], pw[(192 + i) * 3 + o], a);
    a += x[(b * 512 + 511) * 32 + mm] * mask[b * 32 + mm];
    out[b * 131 + t] = a;
  } else if (t < 99) {
    int o = t - 96;
    float a = fb[o];
    const float* yl = yfail + b * 128;
    for (int i = 0; i < 128; ++i) a = fmaf(yl[i], fw[i * 3 + o], a);
    out[b * 131 + 96 + o] = a;
  } else if (t < 131) {
    int mm = t - 99;
    int s = b * 32 + mm;
    float a = rb[0];
    const float* pl = pooledws + s * 64;
    for (int i = 0; i < 64; ++i) a = fmaf(pl[i], rw[i], a);
    const float* cx = ctxws + s * 128;
    for (int i = 0; i < 128; ++i) a = fmaf(cx[i], rw[64 + i], a);
    const float* yr = yrca + s * 128;
    for (int i = 0; i < 128; ++i) a = fmaf(yr[i], rw[192 + i], a);
    out[b * 131 + 99 + mm] = a;
  }
}

// ---------------------------------------------------------------------------
extern "C" void kernel_launch(void* const* d_in, const int* in_sizes, int n_in,
                              void* d_out, int out_size, void* d_ws, size_t ws_size,
                              hipStream_t stream) {
  (void)in_sizes; (void)n_in; (void)out_size; (void)ws_size;
  const float* x    = (const float*)d_in[0];
  const float* msk  = (const float*)d_in[1];
  const float* epw  = (const float*)d_in[2];
  const float* epb  = (const float*)d_in[3];
  const float* tw1  = (const float*)d_in[4];
  const float* tb1  = (const float*)d_in[5];
  const float* tw2  = (const float*)d_in[6];
  const float* tb2  = (const float*)d_in[7];
  const float* eng  = (const float*)d_in[8];
  const float* enb  = (const float*)d_in[9];
  const float* ppw  = (const float*)d_in[10];
  const float* ppb  = (const float*)d_in[11];
  const float* pos  = (const float*)d_in[12];
  const float* twq  = (const float*)d_in[13];
  const float* tbq  = (const float*)d_in[14];
  const float* twk  = (const float*)d_in[15];
  const float* tbk  = (const float*)d_in[16];
  const float* twv  = (const float*)d_in[17];
  const float* tbv  = (const float*)d_in[18];
  const float* two  = (const float*)d_in[19];
  const float* tbo  = (const float*)d_in[20];
  const float* l1g  = (const float*)d_in[21];
  const float* l1b  = (const float*)d_in[22];
  const float* l2g  = (const float*)d_in[23];
  const float* l2b  = (const float*)d_in[24];
  const float* f1w  = (const float*)d_in[25];
  const float* f1b  = (const float*)d_in[26];
  const float* f2w  = (const float*)d_in[27];
  const float* f2b  = (const float*)d_in[28];
  const float* tog  = (const float*)d_in[29];
  const float* tob  = (const float*)d_in[30];
  const float* ew1  = (const float*)d_in[31];
  const float* eb1  = (const float*)d_in[32];
  const float* ew2  = (const float*)d_in[33];
  const float* eb2  = (const float*)d_in[34];
  const float* gfw  = (const float*)d_in[35];
  const float* gfb  = (const float*)d_in[36];
  const float* glw  = (const float*)d_in[37];
  const float* glb  = (const float*)d_in[38];
  const float* grw  = (const float*)d_in[39];
  const float* grb  = (const float*)d_in[40];
  const float* prw  = (const float*)d_in[41];
  const float* prb  = (const float*)d_in[42];
  const float* fw   = (const float*)d_in[43];
  const float* fb   = (const float*)d_in[44];
  const float* rw   = (const float*)d_in[45];
  const float* rb   = (const float*)d_in[46];

  float* ws      = (float*)d_ws;
  float* psum    = ws;                 // 512*64
  float* pooledw = psum + 32768;       // 512*64
  float* ctxw    = pooledw + 32768;    // 512*128
  float* gwsb    = ctxw + 65536;       // 16*256
  float* yf      = gwsb + 4096;        // 16*128
  float* yfail   = yf + 2048;          // 16*128
  float* yrca    = yfail + 2048;       // 512*128
  int*   gidx    = (int*)(yrca + 65536);   // 544*2
  float* gwt     = (float*)(gidx + 1088);  // 544*2

  const int tcn_lds = (2 * ROWS_ * LDA_ + 3 * 64 * LDA_) * 2 + (64 + 256) * 4;  // 88832 B
  hipFuncSetAttribute((const void*)tcn_kernel, hipFuncAttributeMaxDynamicSharedMemorySize, tcn_lds);
  hipFuncSetAttribute((const void*)xf_kernel,  hipFuncAttributeMaxDynamicSharedMemorySize, 126848);

  hipMemsetAsync(psum, 0, 32768 * sizeof(float), stream);
  tcn_kernel<<<2048, 256, tcn_lds, stream>>>(x, msk, epw, epb, tw1, tb1, tw2, tb2, eng, enb, psum);
  xf_kernel<<<16, 256, 126848, stream>>>(psum, msk, ppw, ppb, pos,
                                         twq, tbq, twk, tbk, twv, tbv, two, tbo,
                                         l1g, l1b, l2g, l2b, f1w, f1b, f2w, f2b,
                                         tog, tob, pooledw, ctxw, gwsb);
  gates_kernel<<<544, 64, 0, stream>>>(gwsb, ctxw, gfw, gfb, glw, glb, grw, grb, gidx, gwt);
  moe_kernel<<<544, 256, 0, stream>>>(gwsb, ctxw, ew1, eb1, ew2, eb2, gidx, gwt, yf, yfail, yrca);
  heads_kernel<<<16, 192, 0, stream>>>(x, msk, pooledw, ctxw, yf, yfail, yrca,
                                       prw, prb, fw, fb, rw, rb, (float*)d_out);
}

// Round 4
// 633.279 us; speedup vs baseline: 2.3706x; 1.3905x over previous
//
#include <hip/hip_runtime.h>
#include <hip/hip_bf16.h>

// Problem constants (FoundationalTimeSeriesModel)
#define B_   16
#define L_   512
#define M_   32
#define P_   64
#define D_   128
#define NH_  8
#define DH_  16
#define NL_  2
#define E_   16
#define EH_  512
#define O_   128

// TCN chunking (MFMA version)
#define CH    128   // valid outputs per chunk
#define HALO  60    // receptive field of the 4-level TCN
#define PADF  16    // front pad rows (max tap lookback 2*8=16)
#define ROWS_ 208   // PADF + 192 (12 n-tiles of 16)
#define LDA_  72    // bf16 leading dim (stride 144B -> 2-way-free banks, 16B aligned)

typedef short  bf16x8 __attribute__((ext_vector_type(8)));
typedef float  f32x4  __attribute__((ext_vector_type(4)));
typedef unsigned short us4 __attribute__((ext_vector_type(4)));

__device__ __forceinline__ float bf2f(unsigned short h) {
  unsigned u = ((unsigned)h) << 16; float f; __builtin_memcpy(&f, &u, 4); return f;
}
__device__ __forceinline__ unsigned short f2bf(float f) {
  unsigned u; __builtin_memcpy(&u, &f, 4);
  u += 0x7fffu + ((u >> 16) & 1);            // RNE (finite inputs only)
  return (unsigned short)(u >> 16);
}

// ---------------------------------------------------------------------------
// Kernel 1: per-(sequence,chunk) MFMA TCN encoder + layernorm + mean-pool
// ---------------------------------------------------------------------------
__device__ __forceinline__ void stage_wb(unsigned short* Wt, float* Bs,
                                         const float* __restrict__ w,
                                         const float* __restrict__ b) {
  for (int idx = threadIdx.x; idx < 6144; idx += 256) {
    int t   = idx >> 11;
    int rem = idx & 2047;
    int o   = rem >> 5;
    int c0  = (rem & 31) * 2;
    float a0 = w[o * 192 + c0 * 3 + t];
    float a1 = w[o * 192 + (c0 + 1) * 3 + t];
    unsigned v = (unsigned)f2bf(a0) | ((unsigned)f2bf(a1) << 16);
    *(unsigned*)(Wt + (t * 64 + o) * LDA_ + c0) = v;
  }
  if (threadIdx.x < 64) Bs[threadIdx.x] = b[threadIdx.x];
}

template <int DIL, bool RES>
__device__ __forceinline__ void conv_mfma(const unsigned short* __restrict__ IN,
                                          unsigned short* __restrict__ OUT,
                                          const unsigned short* __restrict__ Wt,
                                          const float* __restrict__ Bs, bool zh) {
  const int tid  = threadIdx.x;
  const int wid  = tid >> 6;
  const int lane = tid & 63;
  const int fr   = lane & 15;
  const int g    = lane >> 4;

  bf16x8 Af[4][6];
#pragma unroll
  for (int ot = 0; ot < 4; ++ot)
#pragma unroll
    for (int t = 0; t < 3; ++t)
#pragma unroll
      for (int kh = 0; kh < 2; ++kh)
        Af[ot][t * 2 + kh] =
            *(const bf16x8*)(Wt + (t * 64 + ot * 16 + fr) * LDA_ + kh * 32 + g * 8);
  float bv[4][4];
#pragma unroll
  for (int ot = 0; ot < 4; ++ot)
#pragma unroll
    for (int j = 0; j < 4; ++j) bv[ot][j] = Bs[ot * 16 + g * 4 + j];

  for (int ntl = 0; ntl < 3; ++ntl) {
    const int nt = wid * 3 + ntl;
    const int rb = PADF + nt * 16 + fr;
    bf16x8 Bf[6];
#pragma unroll
    for (int t = 0; t < 3; ++t) {
      int r = rb + (t - 2) * DIL;
#pragma unroll
      for (int kh = 0; kh < 2; ++kh)
        Bf[t * 2 + kh] = *(const bf16x8*)(IN + r * LDA_ + kh * 32 + g * 8);
    }
    f32x4 acc[4];
#pragma unroll
    for (int ot = 0; ot < 4; ++ot) {
      f32x4 a; a[0] = bv[ot][0]; a[1] = bv[ot][1]; a[2] = bv[ot][2]; a[3] = bv[ot][3];
      acc[ot] = a;
    }
#pragma unroll
    for (int f = 0; f < 6; ++f)
#pragma unroll
      for (int ot = 0; ot < 4; ++ot)
        acc[ot] = __builtin_amdgcn_mfma_f32_16x16x32_bf16(Af[ot][f], Bf[f], acc[ot], 0, 0, 0);

    const float zm = (zh && rb < PADF + HALO) ? 0.f : 1.f;
#pragma unroll
    for (int ot = 0; ot < 4; ++ot) {
      unsigned short* op = OUT + rb * LDA_ + ot * 16 + g * 4;
      us4 old;
      if (RES) old = *(const us4*)op;
      us4 st;
#pragma unroll
      for (int j = 0; j < 4; ++j) {
        float v = fmaxf(acc[ot][j], 0.f);
        if (RES) v = fmaxf(v + bf2f(old[j]), 0.f);
        st[j] = f2bf(v * zm);
      }
      *(us4*)op = st;
    }
  }
}

__global__ __launch_bounds__(256) void tcn_kernel(
    const float* __restrict__ x, const float* __restrict__ mask,
    const float* __restrict__ pw, const float* __restrict__ pb,
    const float* __restrict__ w1, const float* __restrict__ b1,
    const float* __restrict__ w2, const float* __restrict__ b2,
    const float* __restrict__ lng, const float* __restrict__ lnb,
    float* __restrict__ psum) {
  extern __shared__ unsigned short smu[];
  unsigned short* A  = smu;
  unsigned short* Bq = A + ROWS_ * LDA_;
  unsigned short* Wt = Bq + ROWS_ * LDA_;
  float* Bs  = (float*)(Wt + 3 * 64 * LDA_);
  float* mst = Bs + 64;

  const int bx = blockIdx.x;
  const int seq = bx >> 2;
  const int chunk = bx & 3;
  const int b = seq >> 5;
  const int m = seq & 31;
  if (mask[b * M_ + m] == 0.0f) return;
  const int tid = threadIdx.x;
  const bool zh = (chunk == 0);

  const int lbase = chunk * CH - HALO;
  for (int idx = tid; idx < ROWS_ * 64; idx += 256) {
    int r = idx >> 6, c = idx & 63;
    int w = r - PADF, l = lbase + w;
    float v = 0.f;
    if (w >= 0 && w < CH + HALO && l >= 0 && l < L_) {
      float xv = x[(b * L_ + l) * M_ + m];
      float dv = expf(-0.14391157f * (float)(c & ~1));
      float ang = (float)l * dv;
      float pe = (c & 1) ? cosf(ang) : sinf(ang);
      v = fmaf(xv, pw[c], pb[c]) + pe;
    }
    A[r * LDA_ + c] = f2bf(v);
  }
  for (int idx = tid; idx < PADF * LDA_; idx += 256) Bq[idx] = 0;
  __syncthreads();

#define LEVEL(DILV, li)                                                     \
  stage_wb(Wt, Bs, w1 + (li) * 12288, b1 + (li) * 64); __syncthreads();     \
  conv_mfma<DILV, false>(A, Bq, Wt, Bs, zh); __syncthreads();               \
  stage_wb(Wt, Bs, w2 + (li) * 12288, b2 + (li) * 64); __syncthreads();     \
  conv_mfma<DILV, true>(Bq, A, Wt, Bs, zh); __syncthreads();
  LEVEL(1, 0) LEVEL(2, 1) LEVEL(4, 2) LEVEL(8, 3)
#undef LEVEL

  if (tid < CH) {
    int r = PADF + HALO + tid;
    float s = 0.f, ss = 0.f;
    for (int c = 0; c < 64; ++c) { float v = bf2f(A[r * LDA_ + c]); s += v; ss += v * v; }
    float mu = s * 0.015625f;
    float var = fmaxf(ss * 0.015625f - mu * mu, 0.0f);
    mst[tid] = mu;
    mst[CH + tid] = rsqrtf(var + 1e-5f);
  }
  __syncthreads();
  {
    int p = tid & 63, q = tid >> 6;
    float accp = 0.f;
    int r0 = PADF + HALO + q * 32;
    for (int r = r0; r < r0 + 32; ++r)
      accp += (bf2f(A[r * LDA_ + p]) - mst[r - PADF - HALO]) * mst[CH + r - PADF - HALO];
    atomicAdd(&psum[seq * 64 + p], lng[p] * accp + 32.0f * lnb[p]);
  }
}

// ---------------------------------------------------------------------------
// Kernel 2: per-batch transformer — 512 threads, LDS-staged weights
// ---------------------------------------------------------------------------
__device__ __forceinline__ void stage_w512(float* dst, const float* __restrict__ src) {
  for (int i = threadIdx.x; i < 4096; i += 512)
    ((float4*)dst)[i] = ((const float4*)src)[i];
}
__device__ __forceinline__ void stage_cols512(float* dst, const float* __restrict__ src, int srcld) {
  for (int idx = threadIdx.x; idx < 4096; idx += 512) {
    int p = idx >> 5, j = (idx & 31) * 4;
    *(float4*)(dst + p * 128 + j) = *(const float4*)(src + p * srcld + j);
  }
}

// W is [128][128] in LDS. MODE 0: store, 1: +=, 2: relu-store
template <int MODE>
__device__ __forceinline__ void gemm_w(const float* __restrict__ In, int ldin,
                                       const float* __restrict__ W,
                                       const float* __restrict__ bias,
                                       float* __restrict__ Out, int ldout) {
  for (int g = threadIdx.x; g < 1024; g += 512) {
    int mm = g >> 5, j0 = (g & 31) * 4;
    float a0 = 0, a1 = 0, a2 = 0, a3 = 0;
    if (bias) { a0 = bias[j0]; a1 = bias[j0 + 1]; a2 = bias[j0 + 2]; a3 = bias[j0 + 3]; }
    const float* ip = In + mm * ldin;
#pragma unroll 4
    for (int p = 0; p < 128; ++p) {
      float s = ip[p];
      float4 w4 = *(const float4*)(W + p * 128 + j0);
      a0 = fmaf(s, w4.x, a0); a1 = fmaf(s, w4.y, a1);
      a2 = fmaf(s, w4.z, a2); a3 = fmaf(s, w4.w, a3);
    }
    float* op = Out + mm * ldout + j0;
    if (MODE == 0)      { op[0] = a0; op[1] = a1; op[2] = a2; op[3] = a3; }
    else if (MODE == 1) { op[0] += a0; op[1] += a1; op[2] += a2; op[3] += a3; }
    else                { op[0] = fmaxf(a0, 0.f); op[1] = fmaxf(a1, 0.f);
                          op[2] = fmaxf(a2, 0.f); op[3] = fmaxf(a3, 0.f); }
  }
}

__device__ __forceinline__ void ln512(const float* __restrict__ In, float* __restrict__ Out,
                                      const float* __restrict__ g, const float* __restrict__ b,
                                      float* mst, float* scr) {
  const int t = threadIdx.x;
  if (t < 256) {
    int mm = t >> 3, sg = t & 7;
    const float* ip = In + mm * 132 + sg * 16;
    float s = 0, ss = 0;
#pragma unroll
    for (int j = 0; j < 16; ++j) { float v = ip[j]; s += v; ss += v * v; }
    scr[t] = s; scr[256 + t] = ss;
  }
  __syncthreads();
  if (t < 32) {
    float s = 0, ss = 0;
#pragma unroll
    for (int k = 0; k < 8; ++k) { s += scr[t * 8 + k]; ss += scr[256 + t * 8 + k]; }
    float mu = s * 0.0078125f;
    float var = fmaxf(ss * 0.0078125f - mu * mu, 0.f);
    mst[t] = mu;
    mst[32 + t] = rsqrtf(var + 1e-5f);
  }
  __syncthreads();
  for (int idx = t; idx < 4096; idx += 512) {
    int mm = idx >> 7, j = idx & 127;
    Out[mm * 132 + j] = (In[mm * 132 + j] - mst[mm]) * mst[32 + mm] * g[j] + b[j];
  }
  __syncthreads();
}

__global__ __launch_bounds__(512) void xf_kernel(
    const float* __restrict__ psum, const float* __restrict__ mask,
    const float* __restrict__ ppw, const float* __restrict__ ppb, const float* __restrict__ pos,
    const float* __restrict__ wq, const float* __restrict__ bq,
    const float* __restrict__ wk, const float* __restrict__ bk,
    const float* __restrict__ wv, const float* __restrict__ bv,
    const float* __restrict__ wo, const float* __restrict__ bo,
    const float* __restrict__ l1g, const float* __restrict__ l1b,
    const float* __restrict__ l2g, const float* __restrict__ l2b,
    const float* __restrict__ f1w, const float* __restrict__ f1b,
    const float* __restrict__ f2w, const float* __restrict__ f2b,
    const float* __restrict__ og_, const float* __restrict__ ob_,
    float* __restrict__ pooledws, float* __restrict__ ctxws, float* __restrict__ gws) {
  extern __shared__ float sm[];
  float* T    = sm;            // 32*132 = 4224
  float* Y    = T + 4224;      // 4224   (LN out / attn out / ff in; Pl in prologue)
  float* QKV  = Y + 4224;      // 32*396 = 12672 (Q|K|V, ld 396; FF hidden ld 264)
  float* WS   = QKV + 12672;   // 16384  (weight stage; scores S 8*32*33=8448; LN scratch)
  float* mst  = WS + 16384;    // 64
  float* mkv  = mst + 64;      // 32     total 37600 f = 150400 B
  float* S    = WS;
  float* scr  = WS + 12000;    // LN scratch (512 f), beyond S region
  const int b = blockIdx.x;
  const int tid = threadIdx.x;

  if (tid < 32) mkv[tid] = mask[b * 32 + tid];
  // pooled -> Pl (Y region, ld 68) + pooledws
  for (int idx = tid; idx < 2048; idx += 512) {
    int mm = idx >> 6, p = idx & 63;
    float v = mask[b * 32 + mm] * psum[(b * 32 + mm) * 64 + p] * (1.0f / 512.0f);
    Y[mm * 68 + p] = v;
    pooledws[(b * 32 + mm) * 64 + p] = v;
  }
  for (int i = tid; i < 2048; i += 512)   // stage ppw (64x128)
    ((float4*)WS)[i] = ((const float4*)ppw)[i];
  __syncthreads();

  // t0 = pooled @ pool_proj + ppb + pos
  for (int g = tid; g < 1024; g += 512) {
    int mm = g >> 5, j0 = (g & 31) * 4;
    float4 pv = *(const float4*)(pos + mm * 128 + j0);
    float a0 = ppb[j0] + pv.x, a1 = ppb[j0 + 1] + pv.y;
    float a2 = ppb[j0 + 2] + pv.z, a3 = ppb[j0 + 3] + pv.w;
    const float* ip = Y + mm * 68;
#pragma unroll 4
    for (int p = 0; p < 64; ++p) {
      float s = ip[p];
      float4 w4 = *(const float4*)(WS + p * 128 + j0);
      a0 = fmaf(s, w4.x, a0); a1 = fmaf(s, w4.y, a1);
      a2 = fmaf(s, w4.z, a2); a3 = fmaf(s, w4.w, a3);
    }
    float* op = T + mm * 132 + j0;
    op[0] = a0; op[1] = a1; op[2] = a2; op[3] = a3;
  }
  __syncthreads();

  for (int l = 0; l < NL_; ++l) {
    ln512(T, Y, l1g + l * 128, l1b + l * 128, mst, scr);
    stage_w512(WS, wq + l * 16384); __syncthreads();
    gemm_w<0>(Y, 132, WS, bq + l * 128, QKV + 0, 396); __syncthreads();
    stage_w512(WS, wk + l * 16384); __syncthreads();
    gemm_w<0>(Y, 132, WS, bk + l * 128, QKV + 132, 396); __syncthreads();
    stage_w512(WS, wv + l * 16384); __syncthreads();
    gemm_w<0>(Y, 132, WS, bv + l * 128, QKV + 264, 396); __syncthreads();

    // scores, all heads: S[h][mm][n]
    for (int idx = tid; idx < 8192; idx += 512) {
      int h = idx >> 10, rem = idx & 1023, mm = rem >> 5, n = rem & 31;
      const float* qp = QKV + mm * 396 + h * 16;
      const float* kp = QKV + n * 396 + 132 + h * 16;
      float a = 0;
#pragma unroll
      for (int d = 0; d < 16; ++d) a = fmaf(qp[d], kp[d], a);
      a *= 0.25f;
      if (mkv[n] == 0.0f) a -= 1e9f;
      S[h * 1056 + mm * 33 + n] = a;
    }
    __syncthreads();
    if (tid < 256) {
      float* sr = S + (tid >> 5) * 1056 + (tid & 31) * 33;
      float mx = sr[0];
      for (int n = 1; n < 32; ++n) mx = fmaxf(mx, sr[n]);
      float sum = 0;
      for (int n = 0; n < 32; ++n) { float e = __expf(sr[n] - mx); sr[n] = e; sum += e; }
      float inv = 1.0f / sum;
      for (int n = 0; n < 32; ++n) sr[n] *= inv;
    }
    __syncthreads();
    // AV -> Y
    for (int idx = tid; idx < 4096; idx += 512) {
      int mm = idx >> 7, jd = idx & 127, h = jd >> 4, d = jd & 15;
      const float* sp = S + h * 1056 + mm * 33;
      const float* vp = QKV + 264 + h * 16 + d;
      float a = 0;
#pragma unroll 8
      for (int n = 0; n < 32; ++n) a = fmaf(sp[n], vp[n * 396], a);
      Y[mm * 132 + jd] = a;
    }
    __syncthreads();
    stage_w512(WS, wo + l * 16384); __syncthreads();
    gemm_w<1>(Y, 132, WS, bo + l * 128, T, 132); __syncthreads();

    ln512(T, Y, l2g + l * 128, l2b + l * 128, mst, scr);
    float* FFH = QKV;  // 32 x 264
    for (int half = 0; half < 2; ++half) {
      stage_cols512(WS, f1w + l * 32768 + half * 128, 256); __syncthreads();
      gemm_w<2>(Y, 132, WS, f1b + l * 256 + half * 128, FFH + half * 128, 264); __syncthreads();
    }
    for (int half = 0; half < 2; ++half) {
      stage_w512(WS, f2w + l * 32768 + half * 16384); __syncthreads();
      gemm_w<1>(FFH + half * 128, 264, WS, half == 0 ? (f2b + l * 128) : nullptr, T, 132);
      __syncthreads();
    }
  }

  // ctx = LN(t) * mask ; g = [mean_ctx | max_ctx]
  ln512(T, Y, og_, ob_, mst, scr);
  for (int idx = tid; idx < 4096; idx += 512) {
    int mm = idx >> 7, j = idx & 127;
    float c = Y[mm * 132 + j] * mkv[mm];
    Y[mm * 132 + j] = c;
    ctxws[(b * 32 + mm) * 128 + j] = c;
  }
  __syncthreads();
  if (tid < 128) {
    float cnt = 0;
    for (int mm = 0; mm < 32; ++mm) cnt += mkv[mm];
    cnt = fmaxf(cnt, 1.0f);
    float s = 0, mx = -1e9f;
    for (int mm = 0; mm < 32; ++mm) {
      float v = Y[mm * 132 + tid];
      s += v;
      if (mkv[mm] > 0.0f) mx = fmaxf(mx, v);
    }
    gws[b * 256 + tid] = s / cnt;
    gws[b * 256 + 128 + tid] = mx;
  }
}

// ---------------------------------------------------------------------------
// Kernel 3: MoE gates (top-2 + softmax weights) for 16+16+512 rows
// ---------------------------------------------------------------------------
__global__ __launch_bounds__(64) void gates_kernel(
    const float* __restrict__ gws, const float* __restrict__ ctxws,
    const float* __restrict__ gfw, const float* __restrict__ gfb,
    const float* __restrict__ glw, const float* __restrict__ glb,
    const float* __restrict__ grw, const float* __restrict__ grb,
    int* __restrict__ gidx, float* __restrict__ gwt) {
  __shared__ float lg[16];
  int r = blockIdx.x;
  const float* in; const float* W; const float* Bb; int dl;
  if (r < 16)      { in = gws + r * 256;          W = gfw; Bb = gfb; dl = 256; }
  else if (r < 32) { in = gws + (r - 16) * 256;   W = glw; Bb = glb; dl = 256; }
  else             { in = ctxws + (r - 32) * 128; W = grw; Bb = grb; dl = 128; }
  if (threadIdx.x < 16) {
    float a = Bb[threadIdx.x];
    for (int d = 0; d < dl; ++d) a = fmaf(in[d], W[d * 16 + threadIdx.x], a);
    lg[threadIdx.x] = a;
  }
  __syncthreads();
  if (threadIdx.x == 0) {
    int i0 = 0; float v0 = lg[0];
    for (int e = 1; e < 16; ++e) if (lg[e] > v0) { v0 = lg[e]; i0 = e; }
    int i1 = (i0 == 0) ? 1 : 0; float v1 = lg[i1];
    for (int e = 0; e < 16; ++e) if (e != i0 && lg[e] > v1) { v1 = lg[e]; i1 = e; }
    float e1 = __expf(v1 - v0);
    float w0 = 1.0f / (1.0f + e1);
    gidx[2 * r] = i0; gidx[2 * r + 1] = i1;
    gwt[2 * r] = w0;  gwt[2 * r + 1] = 1.0f - w0;
  }
}

// ---------------------------------------------------------------------------
// Kernel 4: MoE experts — one block per row, both selected experts
// ---------------------------------------------------------------------------
__global__ __launch_bounds__(256) void moe_kernel(
    const float* __restrict__ gws, const float* __restrict__ ctxws,
    const float* __restrict__ ew1, const float* __restrict__ eb1,
    const float* __restrict__ ew2, const float* __restrict__ eb2,
    const int* __restrict__ gidx, const float* __restrict__ gwt,
    float* __restrict__ yf, float* __restrict__ yfail, float* __restrict__ yrca) {
  __shared__ float xin[256];
  __shared__ float H[512];
  int r = blockIdx.x;
  int tid = threadIdx.x;
  if (r < 32) {
    int rr = (r < 16) ? r : r - 16;
    xin[tid] = gws[rr * 256 + tid];
  } else {
    int rr = r - 32;
    int bb = rr >> 5;
    if (tid < 128) xin[tid] = ctxws[rr * 128 + tid];
    else           xin[tid] = gws[bb * 256 + (tid - 128)];  // mean_ctx
  }
  float yacc = 0.f;
  for (int tk = 0; tk < 2; ++tk) {
    int e = gidx[2 * r + tk];
    float wgt = gwt[2 * r + tk];
    __syncthreads();
    const float* W1 = ew1 + (size_t)e * (256 * 512);
    for (int h = tid; h < 512; h += 256) {
      float a = eb1[e * 512 + h];
#pragma unroll 4
      for (int d = 0; d < 256; ++d) a = fmaf(xin[d], W1[d * 512 + h], a);
      H[h] = fmaxf(a, 0.f);
    }
    __syncthreads();
    if (tid < 128) {
      const float* W2 = ew2 + (size_t)e * (512 * 128);
      float a = eb2[e * 128 + tid];
#pragma unroll 4
      for (int h = 0; h < 512; ++h) a = fmaf(H[h], W2[h * 128 + tid], a);
      yacc += wgt * a;
    }
  }
  if (tid < 128) {
    float* dst = (r < 16) ? (yf + r * 128) : (r < 32) ? (yfail + (r - 16) * 128)
                                                      : (yrca + (r - 32) * 128);
    dst[tid] = yacc;
  }
}

// ---------------------------------------------------------------------------
// Kernel 5: output heads (pred / fail / rca) -> fp32 output
// ---------------------------------------------------------------------------
__global__ __launch_bounds__(192) void heads_kernel(
    const float* __restrict__ x, const float* __restrict__ mask,
    const float* __restrict__ pooledws, const float* __restrict__ ctxws,
    const float* __restrict__ yf, const float* __restrict__ yfail, const float* __restrict__ yrca,
    const float* __restrict__ pw, const float* __restrict__ pb,
    const float* __restrict__ fw, const float* __restrict__ fb,
    const float* __restrict__ rw, const float* __restrict__ rb,
    float* __restrict__ out) {
  __shared__ float yfb[128];
  int b = blockIdx.x, t = threadIdx.x;
  if (t < 128) yfb[t] = yf[b * 128 + t];
  __syncthreads();
  if (t < 96) {
    int mm = t / 3, o = t - mm * 3;
    int s = b * 32 + mm;
    float a = pb[o];
    const float* pl = pooledws + s * 64;
    for (int i = 0; i < 64; ++i) a = fmaf(pl[i], pw[i * 3 + o], a);
    const float* cx = ctxws + s * 128;
    for (int i = 0; i < 128; ++i) a = fmaf(cx[i], pw[(64 + i) * 3 + o], a);
    for (int i = 0; i < 128; ++i) a = fmaf(yfb[i], pw[(192 + i) * 3 + o], a);
    a += x[(b * 512 + 511) * 32 + mm] * mask[b * 32 + mm];
    out[b * 131 + t] = a;
  } else if (t < 99) {
    int o = t - 96;
    float a = fb[o];
    const float* yl = yfail + b * 128;
    for (int i = 0; i < 128; ++i) a = fmaf(yl[i], fw[i * 3 + o], a);
    out[b * 131 + 96 + o] = a;
  } else if (t < 131) {
    int mm = t - 99;
    int s = b * 32 + mm;
    float a = rb[0];
    const float* pl = pooledws + s * 64;
    for (int i = 0; i < 64; ++i) a = fmaf(pl[i], rw[i], a);
    const float* cx = ctxws + s * 128;
    for (int i = 0; i < 128; ++i) a = fmaf(cx[i], rw[64 + i], a);
    const float* yr = yrca + s * 128;
    for (int i = 0; i < 128; ++i) a = fmaf(yr[i], rw[192 + i], a);
    out[b * 131 + 99 + mm] = a;
  }
}

// ---------------------------------------------------------------------------
extern "C" void kernel_launch(void* const* d_in, const int* in_sizes, int n_in,
                              void* d_out, int out_size, void* d_ws, size_t ws_size,
                              hipStream_t stream) {
  (void)in_sizes; (void)n_in; (void)out_size; (void)ws_size;
  const float* x    = (const float*)d_in[0];
  const float* msk  = (const float*)d_in[1];
  const float* epw  = (const float*)d_in[2];
  const float* epb  = (const float*)d_in[3];
  const float* tw1  = (const float*)d_in[4];
  const float* tb1  = (const float*)d_in[5];
  const float* tw2  = (const float*)d_in[6];
  const float* tb2  = (const float*)d_in[7];
  const float* eng  = (const float*)d_in[8];
  const float* enb  = (const float*)d_in[9];
  const float* ppw  = (const float*)d_in[10];
  const float* ppb  = (const float*)d_in[11];
  const float* pos  = (const float*)d_in[12];
  const float* twq  = (const float*)d_in[13];
  const float* tbq  = (const float*)d_in[14];
  const float* twk  = (const float*)d_in[15];
  const float* tbk  = (const float*)d_in[16];
  const float* twv  = (const float*)d_in[17];
  const float* tbv  = (const float*)d_in[18];
  const float* two  = (const float*)d_in[19];
  const float* tbo  = (const float*)d_in[20];
  const float* l1g  = (const float*)d_in[21];
  const float* l1b  = (const float*)d_in[22];
  const float* l2g  = (const float*)d_in[23];
  const float* l2b  = (const float*)d_in[24];
  const float* f1w  = (const float*)d_in[25];
  const float* f1b  = (const float*)d_in[26];
  const float* f2w  = (const float*)d_in[27];
  const float* f2b  = (const float*)d_in[28];
  const float* tog  = (const float*)d_in[29];
  const float* tob  = (const float*)d_in[30];
  const float* ew1  = (const float*)d_in[31];
  const float* eb1  = (const float*)d_in[32];
  const float* ew2  = (const float*)d_in[33];
  const float* eb2  = (const float*)d_in[34];
  const float* gfw  = (const float*)d_in[35];
  const float* gfb  = (const float*)d_in[36];
  const float* glw  = (const float*)d_in[37];
  const float* glb  = (const float*)d_in[38];
  const float* grw  = (const float*)d_in[39];
  const float* grb  = (const float*)d_in[40];
  const float* prw  = (const float*)d_in[41];
  const float* prb  = (const float*)d_in[42];
  const float* fw   = (const float*)d_in[43];
  const float* fb   = (const float*)d_in[44];
  const float* rw   = (const float*)d_in[45];
  const float* rb   = (const float*)d_in[46];

  float* ws      = (float*)d_ws;
  float* psum    = ws;                 // 512*64
  float* pooledw = psum + 32768;       // 512*64
  float* ctxw    = pooledw + 32768;    // 512*128
  float* gwsb    = ctxw + 65536;       // 16*256
  float* yf      = gwsb + 4096;        // 16*128
  float* yfail   = yf + 2048;          // 16*128
  float* yrca    = yfail + 2048;       // 512*128
  int*   gidx    = (int*)(yrca + 65536);   // 544*2
  float* gwt     = (float*)(gidx + 1088);  // 544*2

  const int tcn_lds = (2 * ROWS_ * LDA_ + 3 * 64 * LDA_) * 2 + (64 + 256) * 4;  // 88832 B
  const int xf_lds  = 37600 * 4;  // 150400 B
  hipFuncSetAttribute((const void*)tcn_kernel, hipFuncAttributeMaxDynamicSharedMemorySize, tcn_lds);
  hipFuncSetAttribute((const void*)xf_kernel,  hipFuncAttributeMaxDynamicSharedMemorySize, xf_lds);

  hipMemsetAsync(psum, 0, 32768 * sizeof(float), stream);
  tcn_kernel<<<2048, 256, tcn_lds, stream>>>(x, msk, epw, epb, tw1, tb1, tw2, tb2, eng, enb, psum);
  xf_kernel<<<16, 512, xf_lds, stream>>>(psum, msk, ppw, ppb, pos,
                                         twq, tbq, twk, tbk, twv, tbv, two, tbo,
                                         l1g, l1b, l2g, l2b, f1w, f1b, f2w, f2b,
                                         tog, tob, pooledw, ctxw, gwsb);
  gates_kernel<<<544, 64, 0, stream>>>(gwsb, ctxw, gfw, gfb, glw, glb, grw, grb, gidx, gwt);
  moe_kernel<<<544, 256, 0, stream>>>(gwsb, ctxw, ew1, eb1, ew2, eb2, gidx, gwt, yf, yfail, yrca);
  heads_kernel<<<16, 192, 0, stream>>>(x, msk, pooledw, ctxw, yf, yfail, yrca,
                                       prw, prb, fw, fb, rw, rb, (float*)d_out);
}

// Round 5
// 531.122 us; speedup vs baseline: 2.8266x; 1.1923x over previous
//
#include <hip/hip_runtime.h>
#include <hip/hip_bf16.h>

// Problem constants (FoundationalTimeSeriesModel)
#define B_   16
#define L_   512
#define M_   32
#define P_   64
#define D_   128
#define NH_  8
#define DH_  16
#define NL_  2
#define E_   16
#define EH_  512
#define O_   128

// TCN chunking (MFMA version)
#define CH    128   // valid outputs per chunk
#define HALO  60    // receptive field of the 4-level TCN
#define PADF  16    // front pad rows (max tap lookback 2*8=16)
#define ROWS_ 208   // PADF + 192 (12 n-tiles of 16)
#define LDA_  72    // bf16 leading dim (stride 144B -> 2-way-free banks, 16B aligned)

typedef short  bf16x8 __attribute__((ext_vector_type(8)));
typedef float  f32x4  __attribute__((ext_vector_type(4)));
typedef unsigned short us4 __attribute__((ext_vector_type(4)));

__device__ __forceinline__ float bf2f(unsigned short h) {
  unsigned u = ((unsigned)h) << 16; float f; __builtin_memcpy(&f, &u, 4); return f;
}
__device__ __forceinline__ unsigned short f2bf(float f) {
  unsigned u; __builtin_memcpy(&u, &f, 4);
  u += 0x7fffu + ((u >> 16) & 1);            // RNE (finite inputs only)
  return (unsigned short)(u >> 16);
}

// ---------------------------------------------------------------------------
// Kernel 0: prep — pack conv weights to bf16 [lc][tap][o][c], PE table f32
// ---------------------------------------------------------------------------
__global__ __launch_bounds__(256) void prep_kernel(
    const float* __restrict__ w1, const float* __restrict__ w2,
    unsigned short* __restrict__ wpack, float* __restrict__ peT) {
  int i = blockIdx.x * 256 + threadIdx.x;
  if (i < 98304) {
    int c = i & 63, o = (i >> 6) & 63, tlc = i >> 12;   // tlc = lc*3 + t
    int t = tlc % 3, lc = tlc / 3;
    int lvl = lc >> 1;
    const float* src = (lc & 1) ? w2 : w1;
    wpack[i] = f2bf(src[lvl * 12288 + o * 192 + c * 3 + t]);
  } else {
    int j = i - 98304;
    if (j < 32768) {
      int l = j >> 6, c = j & 63;
      float dv = expf(-0.14391157f * (float)(c & ~1));  // ln(1e4)/64
      float ang = (float)l * dv;
      peT[j] = (c & 1) ? cosf(ang) : sinf(ang);
    }
  }
}

// ---------------------------------------------------------------------------
// Kernel 1: per-(sequence,chunk) MFMA TCN encoder + layernorm + mean-pool
// 512 threads, weights in registers from packed global, activations bf16 LDS
// ---------------------------------------------------------------------------
template <int DIL, bool RES>
__device__ __forceinline__ void conv_mfma(const unsigned short* __restrict__ IN,
                                          unsigned short* __restrict__ OUT,
                                          const unsigned short* __restrict__ wp,
                                          const float* __restrict__ bias, bool zh) {
  const int tid  = threadIdx.x;
  const int wid  = tid >> 6;          // 8 waves
  const int lane = tid & 63;
  const int fr   = lane & 15;
  const int g    = lane >> 4;
  const int ot0  = (wid & 1) * 2;     // 2 o-tiles per wave
  const int ntg  = wid >> 1;          // 3 n-tiles per wave

  bf16x8 Af[2][6];
#pragma unroll
  for (int oo = 0; oo < 2; ++oo)
#pragma unroll
    for (int t = 0; t < 3; ++t)
#pragma unroll
      for (int kh = 0; kh < 2; ++kh)
        Af[oo][t * 2 + kh] =
            *(const bf16x8*)(wp + (t * 64 + (ot0 + oo) * 16 + fr) * 64 + kh * 32 + g * 8);
  float bv[2][4];
#pragma unroll
  for (int oo = 0; oo < 2; ++oo)
#pragma unroll
    for (int j = 0; j < 4; ++j) bv[oo][j] = bias[(ot0 + oo) * 16 + g * 4 + j];

#pragma unroll
  for (int ntl = 0; ntl < 3; ++ntl) {
    const int nt = ntg * 3 + ntl;
    const int rb = PADF + nt * 16 + fr;
    bf16x8 Bf[6];
#pragma unroll
    for (int t = 0; t < 3; ++t) {
      int r = rb + (t - 2) * DIL;               // causal taps at l-2d, l-d, l
#pragma unroll
      for (int kh = 0; kh < 2; ++kh)
        Bf[t * 2 + kh] = *(const bf16x8*)(IN + r * LDA_ + kh * 32 + g * 8);
    }
    f32x4 acc[2];
#pragma unroll
    for (int oo = 0; oo < 2; ++oo) {
      f32x4 a; a[0] = bv[oo][0]; a[1] = bv[oo][1]; a[2] = bv[oo][2]; a[3] = bv[oo][3];
      acc[oo] = a;
    }
#pragma unroll
    for (int f = 0; f < 6; ++f)
#pragma unroll
      for (int oo = 0; oo < 2; ++oo)
        acc[oo] = __builtin_amdgcn_mfma_f32_16x16x32_bf16(Af[oo][f], Bf[f], acc[oo], 0, 0, 0);

    const float zm = (zh && rb < PADF + HALO) ? 0.f : 1.f;
#pragma unroll
    for (int oo = 0; oo < 2; ++oo) {
      unsigned short* op = OUT + rb * LDA_ + (ot0 + oo) * 16 + g * 4;
      us4 old;
      if (RES) old = *(const us4*)op;
      us4 st;
#pragma unroll
      for (int j = 0; j < 4; ++j) {
        float v = fmaxf(acc[oo][j], 0.f);
        if (RES) v = fmaxf(v + bf2f(old[j]), 0.f);
        st[j] = f2bf(v * zm);
      }
      *(us4*)op = st;
    }
  }
}

__global__ __launch_bounds__(512) void tcn_kernel(
    const float* __restrict__ x, const float* __restrict__ mask,
    const float* __restrict__ pw, const float* __restrict__ pb,
    const unsigned short* __restrict__ wpack,
    const float* __restrict__ b1, const float* __restrict__ b2,
    const float* __restrict__ peT,
    const float* __restrict__ lng, const float* __restrict__ lnb,
    float* __restrict__ psum) {
  extern __shared__ unsigned short smu[];
  unsigned short* A  = smu;                    // 208*72 bf16
  unsigned short* Bq = A + ROWS_ * LDA_;       // 208*72 bf16
  float* xr  = (float*)(Bq + ROWS_ * LDA_);    // 208 f32
  float* mst = xr + ROWS_;                     // 256 f32   total 61760 B

  const int bx = blockIdx.x;
  const int seq = bx >> 2;
  const int chunk = bx & 3;
  const int b = seq >> 5;
  const int m = seq & 31;
  if (mask[b * M_ + m] == 0.0f) return;        // masked sensor: output unused
  const int tid = threadIdx.x;
  const bool zh = (chunk == 0);

  const int lbase = chunk * CH - HALO;
  for (int r = tid; r < ROWS_; r += 512) {
    int w = r - PADF, l = lbase + w;
    float xv = 0.f;
    if (w >= 0 && w < CH + HALO && l >= 0 && l < L_) xv = x[(b * L_ + l) * M_ + m];
    xr[r] = xv;
  }
  __syncthreads();
  for (int idx = tid; idx < ROWS_ * 64; idx += 512) {
    int r = idx >> 6, c = idx & 63;
    int w = r - PADF, l = lbase + w;
    float v = 0.f;
    if (w >= 0 && w < CH + HALO && l >= 0 && l < L_)
      v = fmaf(xr[r], pw[c], pb[c]) + peT[l * 64 + c];
    A[r * LDA_ + c] = f2bf(v);
  }
  for (int idx = tid; idx < PADF * LDA_; idx += 512) Bq[idx] = 0;
  __syncthreads();

#define LEVEL(DILV, li)                                                              \
  conv_mfma<DILV, false>(A, Bq, wpack + ((li) * 2 + 0) * 12288, b1 + (li) * 64, zh); \
  __syncthreads();                                                                   \
  conv_mfma<DILV, true >(Bq, A, wpack + ((li) * 2 + 1) * 12288, b2 + (li) * 64, zh); \
  __syncthreads();
  LEVEL(1, 0) LEVEL(2, 1) LEVEL(4, 2) LEVEL(8, 3)
#undef LEVEL

  // LayerNorm over channels (contiguous) at each valid position
  if (tid < CH) {
    int r = PADF + HALO + tid;
    float s = 0.f, ss = 0.f;
    const bf16x8* ap = (const bf16x8*)(A + r * LDA_);
#pragma unroll
    for (int c8 = 0; c8 < 8; ++c8) {
      bf16x8 vv = ap[c8];
#pragma unroll
      for (int j = 0; j < 8; ++j) { float v = bf2f((unsigned short)vv[j]); s += v; ss += v * v; }
    }
    float mu = s * 0.015625f;
    float var = fmaxf(ss * 0.015625f - mu * mu, 0.0f);
    mst[tid] = mu;
    mst[CH + tid] = rsqrtf(var + 1e-5f);
  }
  __syncthreads();
  {
    int p = tid & 63, q = tid >> 6;            // 8 row-groups of 16
    float accp = 0.f;
    int r0 = PADF + HALO + q * 16;
    for (int r = r0; r < r0 + 16; ++r)
      accp += (bf2f(A[r * LDA_ + p]) - mst[r - PADF - HALO]) * mst[CH + r - PADF - HALO];
    atomicAdd(&psum[seq * 64 + p], lng[p] * accp + 16.0f * lnb[p]);
  }
}

// ---------------------------------------------------------------------------
// Kernel 2: per-batch transformer — 512 threads, LDS-staged weights
// ---------------------------------------------------------------------------
__device__ __forceinline__ void stage_w512(float* dst, const float* __restrict__ src) {
  for (int i = threadIdx.x; i < 4096; i += 512)
    ((float4*)dst)[i] = ((const float4*)src)[i];
}
__device__ __forceinline__ void stage_cols512(float* dst, const float* __restrict__ src, int srcld) {
  for (int idx = threadIdx.x; idx < 4096; idx += 512) {
    int p = idx >> 5, j = (idx & 31) * 4;
    *(float4*)(dst + p * 128 + j) = *(const float4*)(src + p * srcld + j);
  }
}

// W is [128][128] in LDS. MODE 0: store, 1: +=, 2: relu-store
template <int MODE>
__device__ __forceinline__ void gemm_w(const float* __restrict__ In, int ldin,
                                       const float* __restrict__ W,
                                       const float* __restrict__ bias,
                                       float* __restrict__ Out, int ldout) {
  for (int g = threadIdx.x; g < 1024; g += 512) {
    int mm = g >> 5, j0 = (g & 31) * 4;
    float a0 = 0, a1 = 0, a2 = 0, a3 = 0;
    if (bias) { a0 = bias[j0]; a1 = bias[j0 + 1]; a2 = bias[j0 + 2]; a3 = bias[j0 + 3]; }
    const float* ip = In + mm * ldin;
#pragma unroll 4
    for (int p = 0; p < 128; ++p) {
      float s = ip[p];
      float4 w4 = *(const float4*)(W + p * 128 + j0);
      a0 = fmaf(s, w4.x, a0); a1 = fmaf(s, w4.y, a1);
      a2 = fmaf(s, w4.z, a2); a3 = fmaf(s, w4.w, a3);
    }
    float* op = Out + mm * ldout + j0;
    if (MODE == 0)      { op[0] = a0; op[1] = a1; op[2] = a2; op[3] = a3; }
    else if (MODE == 1) { op[0] += a0; op[1] += a1; op[2] += a2; op[3] += a3; }
    else                { op[0] = fmaxf(a0, 0.f); op[1] = fmaxf(a1, 0.f);
                          op[2] = fmaxf(a2, 0.f); op[3] = fmaxf(a3, 0.f); }
  }
}

__device__ __forceinline__ void ln512(const float* __restrict__ In, float* __restrict__ Out,
                                      const float* __restrict__ g, const float* __restrict__ b,
                                      float* mst, float* scr) {
  const int t = threadIdx.x;
  if (t < 256) {
    int mm = t >> 3, sg = t & 7;
    const float* ip = In + mm * 132 + sg * 16;
    float s = 0, ss = 0;
#pragma unroll
    for (int j = 0; j < 16; ++j) { float v = ip[j]; s += v; ss += v * v; }
    scr[t] = s; scr[256 + t] = ss;
  }
  __syncthreads();
  if (t < 32) {
    float s = 0, ss = 0;
#pragma unroll
    for (int k = 0; k < 8; ++k) { s += scr[t * 8 + k]; ss += scr[256 + t * 8 + k]; }
    float mu = s * 0.0078125f;
    float var = fmaxf(ss * 0.0078125f - mu * mu, 0.f);
    mst[t] = mu;
    mst[32 + t] = rsqrtf(var + 1e-5f);
  }
  __syncthreads();
  for (int idx = t; idx < 4096; idx += 512) {
    int mm = idx >> 7, j = idx & 127;
    Out[mm * 132 + j] = (In[mm * 132 + j] - mst[mm]) * mst[32 + mm] * g[j] + b[j];
  }
  __syncthreads();
}

__global__ __launch_bounds__(512) void xf_kernel(
    const float* __restrict__ psum, const float* __restrict__ mask,
    const float* __restrict__ ppw, const float* __restrict__ ppb, const float* __restrict__ pos,
    const float* __restrict__ wq, const float* __restrict__ bq,
    const float* __restrict__ wk, const float* __restrict__ bk,
    const float* __restrict__ wv, const float* __restrict__ bv,
    const float* __restrict__ wo, const float* __restrict__ bo,
    const float* __restrict__ l1g, const float* __restrict__ l1b,
    const float* __restrict__ l2g, const float* __restrict__ l2b,
    const float* __restrict__ f1w, const float* __restrict__ f1b,
    const float* __restrict__ f2w, const float* __restrict__ f2b,
    const float* __restrict__ og_, const float* __restrict__ ob_,
    float* __restrict__ pooledws, float* __restrict__ ctxws, float* __restrict__ gws) {
  extern __shared__ float sm[];
  float* T    = sm;            // 32*132 = 4224
  float* Y    = T + 4224;      // 4224
  float* QKV  = Y + 4224;      // 32*396 = 12672
  float* WS   = QKV + 12672;   // 16384
  float* mst  = WS + 16384;    // 64
  float* mkv  = mst + 64;      // 32
  float* S    = WS;
  float* scr  = WS + 12000;
  const int b = blockIdx.x;
  const int tid = threadIdx.x;

  if (tid < 32) mkv[tid] = mask[b * 32 + tid];
  for (int idx = tid; idx < 2048; idx += 512) {
    int mm = idx >> 6, p = idx & 63;
    float v = mask[b * 32 + mm] * psum[(b * 32 + mm) * 64 + p] * (1.0f / 512.0f);
    Y[mm * 68 + p] = v;
    pooledws[(b * 32 + mm) * 64 + p] = v;
  }
  for (int i = tid; i < 2048; i += 512)
    ((float4*)WS)[i] = ((const float4*)ppw)[i];
  __syncthreads();

  for (int g = tid; g < 1024; g += 512) {
    int mm = g >> 5, j0 = (g & 31) * 4;
    float4 pv = *(const float4*)(pos + mm * 128 + j0);
    float a0 = ppb[j0] + pv.x, a1 = ppb[j0 + 1] + pv.y;
    float a2 = ppb[j0 + 2] + pv.z, a3 = ppb[j0 + 3] + pv.w;
    const float* ip = Y + mm * 68;
#pragma unroll 4
    for (int p = 0; p < 64; ++p) {
      float s = ip[p];
      float4 w4 = *(const float4*)(WS + p * 128 + j0);
      a0 = fmaf(s, w4.x, a0); a1 = fmaf(s, w4.y, a1);
      a2 = fmaf(s, w4.z, a2); a3 = fmaf(s, w4.w, a3);
    }
    float* op = T + mm * 132 + j0;
    op[0] = a0; op[1] = a1; op[2] = a2; op[3] = a3;
  }
  __syncthreads();

  for (int l = 0; l < NL_; ++l) {
    ln512(T, Y, l1g + l * 128, l1b + l * 128, mst, scr);
    stage_w512(WS, wq + l * 16384); __syncthreads();
    gemm_w<0>(Y, 132, WS, bq + l * 128, QKV + 0, 396); __syncthreads();
    stage_w512(WS, wk + l * 16384); __syncthreads();
    gemm_w<0>(Y, 132, WS, bk + l * 128, QKV + 132, 396); __syncthreads();
    stage_w512(WS, wv + l * 16384); __syncthreads();
    gemm_w<0>(Y, 132, WS, bv + l * 128, QKV + 264, 396); __syncthreads();

    for (int idx = tid; idx < 8192; idx += 512) {
      int h = idx >> 10, rem = idx & 1023, mm = rem >> 5, n = rem & 31;
      const float* qp = QKV + mm * 396 + h * 16;
      const float* kp = QKV + n * 396 + 132 + h * 16;
      float a = 0;
#pragma unroll
      for (int d = 0; d < 16; ++d) a = fmaf(qp[d], kp[d], a);
      a *= 0.25f;
      if (mkv[n] == 0.0f) a -= 1e9f;
      S[h * 1056 + mm * 33 + n] = a;
    }
    __syncthreads();
    if (tid < 256) {
      float* sr = S + (tid >> 5) * 1056 + (tid & 31) * 33;
      float mx = sr[0];
      for (int n = 1; n < 32; ++n) mx = fmaxf(mx, sr[n]);
      float sum = 0;
      for (int n = 0; n < 32; ++n) { float e = __expf(sr[n] - mx); sr[n] = e; sum += e; }
      float inv = 1.0f / sum;
      for (int n = 0; n < 32; ++n) sr[n] *= inv;
    }
    __syncthreads();
    for (int idx = tid; idx < 4096; idx += 512) {
      int mm = idx >> 7, jd = idx & 127, h = jd >> 4, d = jd & 15;
      const float* sp = S + h * 1056 + mm * 33;
      const float* vp = QKV + 264 + h * 16 + d;
      float a = 0;
#pragma unroll 8
      for (int n = 0; n < 32; ++n) a = fmaf(sp[n], vp[n * 396], a);
      Y[mm * 132 + jd] = a;
    }
    __syncthreads();
    stage_w512(WS, wo + l * 16384); __syncthreads();
    gemm_w<1>(Y, 132, WS, bo + l * 128, T, 132); __syncthreads();

    ln512(T, Y, l2g + l * 128, l2b + l * 128, mst, scr);
    float* FFH = QKV;  // 32 x 264
    for (int half = 0; half < 2; ++half) {
      stage_cols512(WS, f1w + l * 32768 + half * 128, 256); __syncthreads();
      gemm_w<2>(Y, 132, WS, f1b + l * 256 + half * 128, FFH + half * 128, 264); __syncthreads();
    }
    for (int half = 0; half < 2; ++half) {
      stage_w512(WS, f2w + l * 32768 + half * 16384); __syncthreads();
      gemm_w<1>(FFH + half * 128, 264, WS, half == 0 ? (f2b + l * 128) : nullptr, T, 132);
      __syncthreads();
    }
  }

  ln512(T, Y, og_, ob_, mst, scr);
  for (int idx = tid; idx < 4096; idx += 512) {
    int mm = idx >> 7, j = idx & 127;
    float c = Y[mm * 132 + j] * mkv[mm];
    Y[mm * 132 + j] = c;
    ctxws[(b * 32 + mm) * 128 + j] = c;
  }
  __syncthreads();
  if (tid < 128) {
    float cnt = 0;
    for (int mm = 0; mm < 32; ++mm) cnt += mkv[mm];
    cnt = fmaxf(cnt, 1.0f);
    float s = 0, mx = -1e9f;
    for (int mm = 0; mm < 32; ++mm) {
      float v = Y[mm * 132 + tid];
      s += v;
      if (mkv[mm] > 0.0f) mx = fmaxf(mx, v);
    }
    gws[b * 256 + tid] = s / cnt;
    gws[b * 256 + 128 + tid] = mx;
  }
}

// ---------------------------------------------------------------------------
// Kernel 3: MoE gates (top-2 + softmax weights) for 16+16+512 rows
// ---------------------------------------------------------------------------
__global__ __launch_bounds__(64) void gates_kernel(
    const float* __restrict__ gws, const float* __restrict__ ctxws,
    const float* __restrict__ gfw, const float* __restrict__ gfb,
    const float* __restrict__ glw, const float* __restrict__ glb,
    const float* __restrict__ grw, const float* __restrict__ grb,
    int* __restrict__ gidx, float* __restrict__ gwt) {
  __shared__ float lg[16];
  int r = blockIdx.x;
  const float* in; const float* W; const float* Bb; int dl;
  if (r < 16)      { in = gws + r * 256;          W = gfw; Bb = gfb; dl = 256; }
  else if (r < 32) { in = gws + (r - 16) * 256;   W = glw; Bb = glb; dl = 256; }
  else             { in = ctxws + (r - 32) * 128; W = grw; Bb = grb; dl = 128; }
  if (threadIdx.x < 16) {
    float a = Bb[threadIdx.x];
    for (int d = 0; d < dl; ++d) a = fmaf(in[d], W[d * 16 + threadIdx.x], a);
    lg[threadIdx.x] = a;
  }
  __syncthreads();
  if (threadIdx.x == 0) {
    int i0 = 0; float v0 = lg[0];
    for (int e = 1; e < 16; ++e) if (lg[e] > v0) { v0 = lg[e]; i0 = e; }
    int i1 = (i0 == 0) ? 1 : 0; float v1 = lg[i1];
    for (int e = 0; e < 16; ++e) if (e != i0 && lg[e] > v1) { v1 = lg[e]; i1 = e; }
    float e1 = __expf(v1 - v0);
    float w0 = 1.0f / (1.0f + e1);
    gidx[2 * r] = i0; gidx[2 * r + 1] = i1;
    gwt[2 * r] = w0;  gwt[2 * r + 1] = 1.0f - w0;
  }
}

// ---------------------------------------------------------------------------
// Kernel 4: MoE experts — one block per row, both selected experts
// ---------------------------------------------------------------------------
__global__ __launch_bounds__(256) void moe_kernel(
    const float* __restrict__ gws, const float* __restrict__ ctxws,
    const float* __restrict__ ew1, const float* __restrict__ eb1,
    const float* __restrict__ ew2, const float* __restrict__ eb2,
    const int* __restrict__ gidx, const float* __restrict__ gwt,
    float* __restrict__ yf, float* __restrict__ yfail, float* __restrict__ yrca) {
  __shared__ float xin[256];
  __shared__ float H[512];
  int r = blockIdx.x;
  int tid = threadIdx.x;
  if (r < 32) {
    int rr = (r < 16) ? r : r - 16;
    xin[tid] = gws[rr * 256 + tid];
  } else {
    int rr = r - 32;
    int bb = rr >> 5;
    if (tid < 128) xin[tid] = ctxws[rr * 128 + tid];
    else           xin[tid] = gws[bb * 256 + (tid - 128)];  // mean_ctx
  }
  float yacc = 0.f;
  for (int tk = 0; tk < 2; ++tk) {
    int e = gidx[2 * r + tk];
    float wgt = gwt[2 * r + tk];
    __syncthreads();
    const float* W1 = ew1 + (size_t)e * (256 * 512);
    for (int h = tid; h < 512; h += 256) {
      float a = eb1[e * 512 + h];
#pragma unroll 4
      for (int d = 0; d < 256; ++d) a = fmaf(xin[d], W1[d * 512 + h], a);
      H[h] = fmaxf(a, 0.f);
    }
    __syncthreads();
    if (tid < 128) {
      const float* W2 = ew2 + (size_t)e * (512 * 128);
      float a = eb2[e * 128 + tid];
#pragma unroll 4
      for (int h = 0; h < 512; ++h) a = fmaf(H[h], W2[h * 128 + tid], a);
      yacc += wgt * a;
    }
  }
  if (tid < 128) {
    float* dst = (r < 16) ? (yf + r * 128) : (r < 32) ? (yfail + (r - 16) * 128)
                                                      : (yrca + (r - 32) * 128);
    dst[tid] = yacc;
  }
}

// ---------------------------------------------------------------------------
// Kernel 5: output heads (pred / fail / rca) -> fp32 output
// ---------------------------------------------------------------------------
__global__ __launch_bounds__(192) void heads_kernel(
    const float* __restrict__ x, const float* __restrict__ mask,
    const float* __restrict__ pooledws, const float* __restrict__ ctxws,
    const float* __restrict__ yf, const float* __restrict__ yfail, const float* __restrict__ yrca,
    const float* __restrict__ pw, const float* __restrict__ pb,
    const float* __restrict__ fw, const float* __restrict__ fb,
    const float* __restrict__ rw, const float* __restrict__ rb,
    float* __restrict__ out) {
  __shared__ float yfb[128];
  int b = blockIdx.x, t = threadIdx.x;
  if (t < 128) yfb[t] = yf[b * 128 + t];
  __syncthreads();
  if (t < 96) {
    int mm = t / 3, o = t - mm * 3;
    int s = b * 32 + mm;
    float a = pb[o];
    const float* pl = pooledws + s * 64;
    for (int i = 0; i < 64; ++i) a = fmaf(pl[i], pw[i * 3 + o], a);
    const float* cx = ctxws + s * 128;
    for (int i = 0; i < 128; ++i) a = fmaf(cx[i], pw[(64 + i) * 3 + o], a);
    for (int i = 0; i < 128; ++i) a = fmaf(yfb[i], pw[(192 + i) * 3 + o], a);
    a += x[(b * 512 + 511) * 32 + mm] * mask[b * 32 + mm];
    out[b * 131 + t] = a;
  } else if (t < 99) {
    int o = t - 96;
    float a = fb[o];
    const float* yl = yfail + b * 128;
    for (int i = 0; i < 128; ++i) a = fmaf(yl[i], fw[i * 3 + o], a);
    out[b * 131 + 96 + o] = a;
  } else if (t < 131) {
    int mm = t - 99;
    int s = b * 32 + mm;
    float a = rb[0];
    const float* pl = pooledws + s * 64;
    for (int i = 0; i < 64; ++i) a = fmaf(pl[i], rw[i], a);
    const float* cx = ctxws + s * 128;
    for (int i = 0; i < 128; ++i) a = fmaf(cx[i], rw[64 + i], a);
    const float* yr = yrca + s * 128;
    for (int i = 0; i < 128; ++i) a = fmaf(yr[i], rw[192 + i], a);
    out[b * 131 + 99 + mm] = a;
  }
}

// ---------------------------------------------------------------------------
extern "C" void kernel_launch(void* const* d_in, const int* in_sizes, int n_in,
                              void* d_out, int out_size, void* d_ws, size_t ws_size,
                              hipStream_t stream) {
  (void)in_sizes; (void)n_in; (void)out_size; (void)ws_size;
  const float* x    = (const float*)d_in[0];
  const float* msk  = (const float*)d_in[1];
  const float* epw  = (const float*)d_in[2];
  const float* epb  = (const float*)d_in[3];
  const float* tw1  = (const float*)d_in[4];
  const float* tb1  = (const float*)d_in[5];
  const float* tw2  = (const float*)d_in[6];
  const float* tb2  = (const float*)d_in[7];
  const float* eng  = (const float*)d_in[8];
  const float* enb  = (const float*)d_in[9];
  const float* ppw  = (const float*)d_in[10];
  const float* ppb  = (const float*)d_in[11];
  const float* pos  = (const float*)d_in[12];
  const float* twq  = (const float*)d_in[13];
  const float* tbq  = (const float*)d_in[14];
  const float* twk  = (const float*)d_in[15];
  const float* tbk  = (const float*)d_in[16];
  const float* twv  = (const float*)d_in[17];
  const float* tbv  = (const float*)d_in[18];
  const float* two  = (const float*)d_in[19];
  const float* tbo  = (const float*)d_in[20];
  const float* l1g  = (const float*)d_in[21];
  const float* l1b  = (const float*)d_in[22];
  const float* l2g  = (const float*)d_in[23];
  const float* l2b  = (const float*)d_in[24];
  const float* f1w  = (const float*)d_in[25];
  const float* f1b  = (const float*)d_in[26];
  const float* f2w  = (const float*)d_in[27];
  const float* f2b  = (const float*)d_in[28];
  const float* tog  = (const float*)d_in[29];
  const float* tob  = (const float*)d_in[30];
  const float* ew1  = (const float*)d_in[31];
  const float* eb1  = (const float*)d_in[32];
  const float* ew2  = (const float*)d_in[33];
  const float* eb2  = (const float*)d_in[34];
  const float* gfw  = (const float*)d_in[35];
  const float* gfb  = (const float*)d_in[36];
  const float* glw  = (const float*)d_in[37];
  const float* glb  = (const float*)d_in[38];
  const float* grw  = (const float*)d_in[39];
  const float* grb  = (const float*)d_in[40];
  const float* prw  = (const float*)d_in[41];
  const float* prb  = (const float*)d_in[42];
  const float* fw   = (const float*)d_in[43];
  const float* fb   = (const float*)d_in[44];
  const float* rw   = (const float*)d_in[45];
  const float* rb   = (const float*)d_in[46];

  float* ws      = (float*)d_ws;
  float* psum    = ws;                 // 512*64
  float* pooledw = psum + 32768;       // 512*64
  float* ctxw    = pooledw + 32768;    // 512*128
  float* gwsb    = ctxw + 65536;       // 16*256
  float* yf      = gwsb + 4096;        // 16*128
  float* yfail   = yf + 2048;          // 16*128
  float* yrca    = yfail + 2048;       // 512*128
  int*   gidx    = (int*)(yrca + 65536);   // 544*2
  float* gwt     = (float*)(gidx + 1088);  // 544*2
  float* peT     = gwt + 1088;             // 512*64 f32
  unsigned short* wpack = (unsigned short*)(peT + 32768);  // 98304 bf16

  const int tcn_lds = 2 * ROWS_ * LDA_ * 2 + (ROWS_ + 256) * 4;  // 61760 B
  const int xf_lds  = 37600 * 4;  // 150400 B
  hipFuncSetAttribute((const void*)tcn_kernel, hipFuncAttributeMaxDynamicSharedMemorySize, tcn_lds);
  hipFuncSetAttribute((const void*)xf_kernel,  hipFuncAttributeMaxDynamicSharedMemorySize, xf_lds);

  hipMemsetAsync(psum, 0, 32768 * sizeof(float), stream);
  prep_kernel<<<512, 256, 0, stream>>>(tw1, tw2, wpack, peT);
  tcn_kernel<<<2048, 512, tcn_lds, stream>>>(x, msk, epw, epb, wpack, tb1, tb2, peT,
                                             eng, enb, psum);
  xf_kernel<<<16, 512, xf_lds, stream>>>(psum, msk, ppw, ppb, pos,
                                         twq, tbq, twk, tbk, twv, tbv, two, tbo,
                                         l1g, l1b, l2g, l2b, f1w, f1b, f2w, f2b,
                                         tog, tob, pooledw, ctxw, gwsb);
  gates_kernel<<<544, 64, 0, stream>>>(gwsb, ctxw, gfw, gfb, glw, glb, grw, grb, gidx, gwt);
  moe_kernel<<<544, 256, 0, stream>>>(gwsb, ctxw, ew1, eb1, ew2, eb2, gidx, gwt, yf, yfail, yrca);
  heads_kernel<<<16, 192, 0, stream>>>(x, msk, pooledw, ctxw, yf, yfail, yrca,
                                       prw, prb, fw, fb, rw, rb, (float*)d_out);
}

// Round 6
// 355.890 us; speedup vs baseline: 4.2183x; 1.4924x over previous
//
#include <hip/hip_runtime.h>
#include <hip/hip_bf16.h>

// Problem constants
#define B_   16
#define L_   512
#define M_   32
#define P_   64
#define D_   128
#define NH_  8
#define NL_  2
#define E_   16
#define EH_  512
#define O_   128

// TCN chunking
#define CH    128
#define HALO  60
#define PADF  16
#define ROWS_ 208
#define LDA_  72

typedef short  bf16x8 __attribute__((ext_vector_type(8)));
typedef float  f32x4  __attribute__((ext_vector_type(4)));
typedef unsigned short us4 __attribute__((ext_vector_type(4)));

__device__ __forceinline__ float bf2f(unsigned short h) {
  unsigned u = ((unsigned)h) << 16; float f; __builtin_memcpy(&f, &u, 4); return f;
}
__device__ __forceinline__ unsigned short f2bf(float f) {
  unsigned u; __builtin_memcpy(&u, &f, 4);
  u += 0x7fffu + ((u >> 16) & 1);
  return (unsigned short)(u >> 16);
}

// xfw packed-buffer offsets (bf16 elements)
#define XFW_PPW   0
#define XFW_QKVO  8192      // + l*65536 + gem*16384   [128n][128k]
#define XFW_F1    139264    // + l*32768               [256n][128k]
#define XFW_F2    204800    // + l*32768               [128n][256k]

// ---------------------------------------------------------------------------
// Kernel 0: prep — tiled transposes f32->bf16 + conv wpack + PE table
// ---------------------------------------------------------------------------
__global__ __launch_bounds__(256) void prep_kernel(
    const float* __restrict__ ppw,
    const float* __restrict__ twq, const float* __restrict__ twk,
    const float* __restrict__ twv, const float* __restrict__ two,
    const float* __restrict__ f1w, const float* __restrict__ f2w,
    const float* __restrict__ ew1, const float* __restrict__ ew2,
    const float* __restrict__ tw1, const float* __restrict__ tw2,
    unsigned short* __restrict__ xfw, unsigned short* __restrict__ w1t,
    unsigned short* __restrict__ w2t, unsigned short* __restrict__ wpack,
    float* __restrict__ peT) {
  const int b = blockIdx.x;
  const int tid = threadIdx.x;
  if (b < 834) {
    __shared__ float tl[64][65];
    const float* src; unsigned short* dst; int R, C, tr, tc;
    if (b < 2) {
      src = ppw; dst = xfw + XFW_PPW; R = 64; C = 128; tr = 0; tc = b;
    } else if (b < 34) {
      int t = b - 2; int lg = t >> 2; int l = lg >> 2, gem = lg & 3;
      int tt = t & 3; tr = tt >> 1; tc = tt & 1;
      const float* s4 = (gem == 0) ? twq : (gem == 1) ? twk : (gem == 2) ? twv : two;
      src = s4 + l * 16384; dst = xfw + XFW_QKVO + l * 65536 + gem * 16384; R = 128; C = 128;
    } else if (b < 50) {
      int t = b - 34; int l = t >> 3; int tt = t & 7; tr = tt >> 2; tc = tt & 3;
      src = f1w + l * 32768; dst = xfw + XFW_F1 + l * 32768; R = 128; C = 256;
    } else if (b < 66) {
      int t = b - 50; int l = t >> 3; int tt = t & 7; tr = tt >> 1; tc = tt & 1;
      src = f2w + l * 32768; dst = xfw + XFW_F2 + l * 32768; R = 256; C = 128;
    } else if (b < 578) {
      int t = b - 66; int e = t >> 5; int tt = t & 31; tr = tt >> 3; tc = tt & 7;
      src = ew1 + e * 131072; dst = w1t + e * 131072; R = 256; C = 512;
    } else {
      int t = b - 578; int e = t >> 4; int tt = t & 15; tr = tt >> 1; tc = tt & 1;
      src = ew2 + e * 65536; dst = w2t + e * 65536; R = 512; C = 128;
    }
    for (int i = tid; i < 4096; i += 256) {
      int r = i >> 6, c = i & 63;
      tl[r][c] = src[(tr * 64 + r) * C + tc * 64 + c];
    }
    __syncthreads();
    for (int i = tid; i < 4096; i += 256) {
      int c = i >> 6, r = i & 63;
      dst[(tc * 64 + c) * R + tr * 64 + r] = f2bf(tl[r][c]);
    }
  } else if (b < 840) {
    int base = (b - 834) * 16384;
    for (int q = tid; q < 16384; q += 256) {
      int i = base + q;
      int c = i & 63, o = (i >> 6) & 63, tlc = i >> 12;
      int t = tlc % 3, lc = tlc / 3, lvl = lc >> 1;
      const float* src = (lc & 1) ? tw2 : tw1;
      wpack[i] = f2bf(src[lvl * 12288 + o * 192 + c * 3 + t]);
    }
  } else {
    int base = (b - 840) * 16384;
    for (int q = tid; q < 16384; q += 256) {
      int j = base + q; int ll = j >> 6, c = j & 63;
      float dv = expf(-0.14391157f * (float)(c & ~1));
      float ang = (float)ll * dv;
      peT[j] = (c & 1) ? cosf(ang) : sinf(ang);
    }
  }
}

// ---------------------------------------------------------------------------
// Kernel 1: TCN (unchanged from round 5)
// ---------------------------------------------------------------------------
template <int DIL, bool RES>
__device__ __forceinline__ void conv_mfma(const unsigned short* __restrict__ IN,
                                          unsigned short* __restrict__ OUT,
                                          const unsigned short* __restrict__ wp,
                                          const float* __restrict__ bias, bool zh) {
  const int tid  = threadIdx.x;
  const int wid  = tid >> 6;
  const int lane = tid & 63;
  const int fr   = lane & 15;
  const int g    = lane >> 4;
  const int ot0  = (wid & 1) * 2;
  const int ntg  = wid >> 1;

  bf16x8 Af[2][6];
#pragma unroll
  for (int oo = 0; oo < 2; ++oo)
#pragma unroll
    for (int t = 0; t < 3; ++t)
#pragma unroll
      for (int kh = 0; kh < 2; ++kh)
        Af[oo][t * 2 + kh] =
            *(const bf16x8*)(wp + (t * 64 + (ot0 + oo) * 16 + fr) * 64 + kh * 32 + g * 8);
  float bv[2][4];
#pragma unroll
  for (int oo = 0; oo < 2; ++oo)
#pragma unroll
    for (int j = 0; j < 4; ++j) bv[oo][j] = bias[(ot0 + oo) * 16 + g * 4 + j];

#pragma unroll
  for (int ntl = 0; ntl < 3; ++ntl) {
    const int nt = ntg * 3 + ntl;
    const int rb = PADF + nt * 16 + fr;
    bf16x8 Bf[6];
#pragma unroll
    for (int t = 0; t < 3; ++t) {
      int r = rb + (t - 2) * DIL;
#pragma unroll
      for (int kh = 0; kh < 2; ++kh)
        Bf[t * 2 + kh] = *(const bf16x8*)(IN + r * LDA_ + kh * 32 + g * 8);
    }
    f32x4 acc[2];
#pragma unroll
    for (int oo = 0; oo < 2; ++oo) {
      f32x4 a; a[0] = bv[oo][0]; a[1] = bv[oo][1]; a[2] = bv[oo][2]; a[3] = bv[oo][3];
      acc[oo] = a;
    }
#pragma unroll
    for (int f = 0; f < 6; ++f)
#pragma unroll
      for (int oo = 0; oo < 2; ++oo)
        acc[oo] = __builtin_amdgcn_mfma_f32_16x16x32_bf16(Af[oo][f], Bf[f], acc[oo], 0, 0, 0);

    const float zm = (zh && rb < PADF + HALO) ? 0.f : 1.f;
#pragma unroll
    for (int oo = 0; oo < 2; ++oo) {
      unsigned short* op = OUT + rb * LDA_ + (ot0 + oo) * 16 + g * 4;
      us4 old;
      if (RES) old = *(const us4*)op;
      us4 st;
#pragma unroll
      for (int j = 0; j < 4; ++j) {
        float v = fmaxf(acc[oo][j], 0.f);
        if (RES) v = fmaxf(v + bf2f(old[j]), 0.f);
        st[j] = f2bf(v * zm);
      }
      *(us4*)op = st;
    }
  }
}

__global__ __launch_bounds__(512) void tcn_kernel(
    const float* __restrict__ x, const float* __restrict__ mask,
    const float* __restrict__ pw, const float* __restrict__ pb,
    const unsigned short* __restrict__ wpack,
    const float* __restrict__ b1, const float* __restrict__ b2,
    const float* __restrict__ peT,
    const float* __restrict__ lng, const float* __restrict__ lnb,
    float* __restrict__ psum) {
  extern __shared__ unsigned short smu[];
  unsigned short* A  = smu;
  unsigned short* Bq = A + ROWS_ * LDA_;
  float* xr  = (float*)(Bq + ROWS_ * LDA_);
  float* mst = xr + ROWS_;

  const int bx = blockIdx.x;
  const int seq = bx >> 2;
  const int chunk = bx & 3;
  const int b = seq >> 5;
  const int m = seq & 31;
  if (mask[b * M_ + m] == 0.0f) return;
  const int tid = threadIdx.x;
  const bool zh = (chunk == 0);

  const int lbase = chunk * CH - HALO;
  for (int r = tid; r < ROWS_; r += 512) {
    int w = r - PADF, l = lbase + w;
    float xv = 0.f;
    if (w >= 0 && w < CH + HALO && l >= 0 && l < L_) xv = x[(b * L_ + l) * M_ + m];
    xr[r] = xv;
  }
  __syncthreads();
  for (int idx = tid; idx < ROWS_ * 64; idx += 512) {
    int r = idx >> 6, c = idx & 63;
    int w = r - PADF, l = lbase + w;
    float v = 0.f;
    if (w >= 0 && w < CH + HALO && l >= 0 && l < L_)
      v = fmaf(xr[r], pw[c], pb[c]) + peT[l * 64 + c];
    A[r * LDA_ + c] = f2bf(v);
  }
  for (int idx = tid; idx < PADF * LDA_; idx += 512) Bq[idx] = 0;
  __syncthreads();

#define LEVEL(DILV, li)                                                              \
  conv_mfma<DILV, false>(A, Bq, wpack + ((li) * 2 + 0) * 12288, b1 + (li) * 64, zh); \
  __syncthreads();                                                                   \
  conv_mfma<DILV, true >(Bq, A, wpack + ((li) * 2 + 1) * 12288, b2 + (li) * 64, zh); \
  __syncthreads();
  LEVEL(1, 0) LEVEL(2, 1) LEVEL(4, 2) LEVEL(8, 3)
#undef LEVEL

  if (tid < CH) {
    int r = PADF + HALO + tid;
    float s = 0.f, ss = 0.f;
    const bf16x8* ap = (const bf16x8*)(A + r * LDA_);
#pragma unroll
    for (int c8 = 0; c8 < 8; ++c8) {
      bf16x8 vv = ap[c8];
#pragma unroll
      for (int j = 0; j < 8; ++j) { float v = bf2f((unsigned short)vv[j]); s += v; ss += v * v; }
    }
    float mu = s * 0.015625f;
    float var = fmaxf(ss * 0.015625f - mu * mu, 0.0f);
    mst[tid] = mu;
    mst[CH + tid] = rsqrtf(var + 1e-5f);
  }
  __syncthreads();
  {
    int p = tid & 63, q = tid >> 6;
    float accp = 0.f;
    int r0 = PADF + HALO + q * 16;
    for (int r = r0; r < r0 + 16; ++r)
      accp += (bf2f(A[r * LDA_ + p]) - mst[r - PADF - HALO]) * mst[CH + r - PADF - HALO];
    atomicAdd(&psum[seq * 64 + p], lng[p] * accp + 16.0f * lnb[p]);
  }
}

// ---------------------------------------------------------------------------
// Kernel 2: transformer — MFMA GEMMs, B-frags streamed from global bf16
// ---------------------------------------------------------------------------
__device__ __forceinline__ void ln_sums(const float* __restrict__ In, float* mst, float* scr) {
  const int t = threadIdx.x;
  if (t < 256) {
    int mm = t >> 3, sg = t & 7;
    const float* ip = In + mm * 132 + sg * 16;
    float s = 0, ss = 0;
#pragma unroll
    for (int j = 0; j < 16; ++j) { float v = ip[j]; s += v; ss += v * v; }
    scr[t] = s; scr[256 + t] = ss;
  }
  __syncthreads();
  if (t < 32) {
    float s = 0, ss = 0;
#pragma unroll
    for (int k = 0; k < 8; ++k) { s += scr[t * 8 + k]; ss += scr[256 + t * 8 + k]; }
    float mu = s * 0.0078125f;
    float var = fmaxf(ss * 0.0078125f - mu * mu, 0.f);
    mst[t] = mu;
    mst[32 + t] = rsqrtf(var + 1e-5f);
  }
  __syncthreads();
}

__device__ __forceinline__ void ln_bf(const float* __restrict__ In, unsigned short* __restrict__ Out,
                                      const float* __restrict__ g, const float* __restrict__ b,
                                      float* mst, float* scr) {
  ln_sums(In, mst, scr);
  for (int idx = threadIdx.x; idx < 4096; idx += 512) {
    int mm = idx >> 7, j = idx & 127;
    Out[mm * 136 + j] = f2bf((In[mm * 132 + j] - mst[mm]) * mst[32 + mm] * g[j] + b[j]);
  }
  __syncthreads();
}

__device__ __forceinline__ void ln_f32(const float* __restrict__ In, float* __restrict__ Out,
                                       const float* __restrict__ g, const float* __restrict__ b,
                                       float* mst, float* scr) {
  ln_sums(In, mst, scr);
  for (int idx = threadIdx.x; idx < 4096; idx += 512) {
    int mm = idx >> 7, j = idx & 127;
    Out[mm * 132 + j] = (In[mm * 132 + j] - mst[mm]) * mst[32 + mm] * g[j] + b[j];
  }
  __syncthreads();
}

__global__ __launch_bounds__(512) void xf_kernel(
    const float* __restrict__ psum, const float* __restrict__ mask,
    const unsigned short* __restrict__ xfw,
    const float* __restrict__ ppb, const float* __restrict__ pos,
    const float* __restrict__ bq, const float* __restrict__ bk,
    const float* __restrict__ bv, const float* __restrict__ bo,
    const float* __restrict__ l1g, const float* __restrict__ l1b,
    const float* __restrict__ l2g, const float* __restrict__ l2b,
    const float* __restrict__ f1b, const float* __restrict__ f2b,
    const float* __restrict__ og_, const float* __restrict__ ob_,
    float* __restrict__ pooledws, float* __restrict__ ctxws, float* __restrict__ gws) {
  extern __shared__ float sm[];
  float* T    = sm;                 // 32*132
  float* QKV  = T + 4224;           // 32*396
  float* S    = QKV + 12672;        // 8448 (scores; final-LN scratch)
  float* scr  = S + 8448;           // 512
  float* mst  = scr + 512;          // 64
  float* mkv  = mst + 64;           // 32
  unsigned short* Ybf = (unsigned short*)(mkv + 32);   // [32][136] bf16
  unsigned short* Yb2 = Ybf + 32 * 136;                // [32][136] bf16
  unsigned short* FFH = Yb2 + 32 * 136;                // [32][264] bf16
  const int b = blockIdx.x;
  const int tid = threadIdx.x;
  const int wid = tid >> 6;
  const int lane = tid & 63;
  const int fr = lane & 15;
  const int g = lane >> 4;

  if (tid < 32) mkv[tid] = mask[b * 32 + tid];
  for (int idx = tid; idx < 2048; idx += 512) {
    int mm = idx >> 6, p = idx & 63;
    float v = mask[b * 32 + mm] * psum[(b * 32 + mm) * 64 + p] * (1.0f / 512.0f);
    pooledws[(b * 32 + mm) * 64 + p] = v;
    Ybf[mm * 136 + p] = f2bf(v);
  }
  __syncthreads();

  // pool-proj: M=32,K=64,N=128 -> T = pooled@ppw + ppb + pos
  {
    int mt = wid >> 2;
    bf16x8 Af[2];
#pragma unroll
    for (int kf = 0; kf < 2; ++kf)
      Af[kf] = *(const bf16x8*)(Ybf + (mt * 16 + fr) * 136 + kf * 32 + g * 8);
#pragma unroll
    for (int i = 0; i < 2; ++i) {
      int nt = (wid & 3) * 2 + i;
      const unsigned short* bp = xfw + XFW_PPW + (nt * 16 + fr) * 64;
      f32x4 acc = {0.f, 0.f, 0.f, 0.f};
#pragma unroll
      for (int kf = 0; kf < 2; ++kf)
        acc = __builtin_amdgcn_mfma_f32_16x16x32_bf16(Af[kf], *(const bf16x8*)(bp + kf * 32 + g * 8), acc, 0, 0, 0);
      int n = nt * 16 + fr;
      float bb = ppb[n];
#pragma unroll
      for (int j = 0; j < 4; ++j) {
        int m = mt * 16 + g * 4 + j;
        T[m * 132 + n] = acc[j] + bb + pos[m * 128 + n];
      }
    }
  }
  __syncthreads();

  for (int l = 0; l < NL_; ++l) {
    ln_bf(T, Ybf, l1g + l * 128, l1b + l * 128, mst, scr);
    // QKV: 48 tiles (gem,mt,nt), 6 per wave
#pragma unroll
    for (int i = 0; i < 6; ++i) {
      int tt = wid * 6 + i;
      int gem = tt >> 4, r = tt & 15, mt = r >> 3, nt = r & 7;
      const unsigned short* wT = xfw + XFW_QKVO + l * 65536 + gem * 16384;
      const float* bias = (gem == 0) ? bq : (gem == 1) ? bk : bv;
      bf16x8 Afr[4];
#pragma unroll
      for (int kf = 0; kf < 4; ++kf)
        Afr[kf] = *(const bf16x8*)(Ybf + (mt * 16 + fr) * 136 + kf * 32 + g * 8);
      const unsigned short* bp = wT + (nt * 16 + fr) * 128;
      f32x4 acc = {0.f, 0.f, 0.f, 0.f};
#pragma unroll
      for (int kf = 0; kf < 4; ++kf)
        acc = __builtin_amdgcn_mfma_f32_16x16x32_bf16(Afr[kf], *(const bf16x8*)(bp + kf * 32 + g * 8), acc, 0, 0, 0);
      int n = nt * 16 + fr;
      float bb = bias[l * 128 + n];
#pragma unroll
      for (int j = 0; j < 4; ++j)
        QKV[(mt * 16 + g * 4 + j) * 396 + gem * 132 + n] = acc[j] + bb;
    }
    __syncthreads();
    // scores
    for (int idx = tid; idx < 8192; idx += 512) {
      int h = idx >> 10, rem = idx & 1023, mm = rem >> 5, n = rem & 31;
      const float* qp = QKV + mm * 396 + h * 16;
      const float* kp = QKV + n * 396 + 132 + h * 16;
      float a = 0;
#pragma unroll
      for (int d = 0; d < 16; ++d) a = fmaf(qp[d], kp[d], a);
      a *= 0.25f;
      if (mkv[n] == 0.0f) a -= 1e9f;
      S[h * 1056 + mm * 33 + n] = a;
    }
    __syncthreads();
    if (tid < 256) {
      float* sr = S + (tid >> 5) * 1056 + (tid & 31) * 33;
      float mx = sr[0];
      for (int n = 1; n < 32; ++n) mx = fmaxf(mx, sr[n]);
      float sum = 0;
      for (int n = 0; n < 32; ++n) { float e = __expf(sr[n] - mx); sr[n] = e; sum += e; }
      float inv = 1.0f / sum;
      for (int n = 0; n < 32; ++n) sr[n] *= inv;
    }
    __syncthreads();
    // AV -> Yb2 (bf16)
    for (int idx = tid; idx < 4096; idx += 512) {
      int mm = idx >> 7, jd = idx & 127, h = jd >> 4, d = jd & 15;
      const float* sp = S + h * 1056 + mm * 33;
      const float* vp = QKV + 264 + h * 16 + d;
      float a = 0;
#pragma unroll 8
      for (int n = 0; n < 32; ++n) a = fmaf(sp[n], vp[n * 396], a);
      Yb2[mm * 136 + jd] = f2bf(a);
    }
    __syncthreads();
    // wo: T += Yb2 @ woT + bo
    {
      int mt = wid >> 2;
      bf16x8 Aw[4];
#pragma unroll
      for (int kf = 0; kf < 4; ++kf)
        Aw[kf] = *(const bf16x8*)(Yb2 + (mt * 16 + fr) * 136 + kf * 32 + g * 8);
#pragma unroll
      for (int i = 0; i < 2; ++i) {
        int nt = (wid & 3) * 2 + i;
        const unsigned short* bp = xfw + XFW_QKVO + l * 65536 + 3 * 16384 + (nt * 16 + fr) * 128;
        f32x4 acc = {0.f, 0.f, 0.f, 0.f};
#pragma unroll
        for (int kf = 0; kf < 4; ++kf)
          acc = __builtin_amdgcn_mfma_f32_16x16x32_bf16(Aw[kf], *(const bf16x8*)(bp + kf * 32 + g * 8), acc, 0, 0, 0);
        int n = nt * 16 + fr;
        float bb = bo[l * 128 + n];
#pragma unroll
        for (int j = 0; j < 4; ++j)
          T[(mt * 16 + g * 4 + j) * 132 + n] += acc[j] + bb;
      }
    }
    __syncthreads();
    ln_bf(T, Ybf, l2g + l * 128, l2b + l * 128, mst, scr);
    // FF1: FFH = relu(Ybf @ f1T + f1b), N=256
    {
      int mt = wid >> 2;   // (wid*4+i)>>4 == wid>>2 for i<4
      bf16x8 Aff[4];
#pragma unroll
      for (int kf = 0; kf < 4; ++kf)
        Aff[kf] = *(const bf16x8*)(Ybf + (mt * 16 + fr) * 136 + kf * 32 + g * 8);
#pragma unroll
      for (int i = 0; i < 4; ++i) {
        int tt = wid * 4 + i;
        int nt = tt & 15;
        const unsigned short* bp = xfw + XFW_F1 + l * 32768 + (nt * 16 + fr) * 128;
        f32x4 acc = {0.f, 0.f, 0.f, 0.f};
#pragma unroll
        for (int kf = 0; kf < 4; ++kf)
          acc = __builtin_amdgcn_mfma_f32_16x16x32_bf16(Aff[kf], *(const bf16x8*)(bp + kf * 32 + g * 8), acc, 0, 0, 0);
        int n = nt * 16 + fr;
        float bb = f1b[l * 256 + n];
#pragma unroll
        for (int j = 0; j < 4; ++j)
          FFH[(mt * 16 + g * 4 + j) * 264 + n] = f2bf(fmaxf(acc[j] + bb, 0.f));
      }
    }
    __syncthreads();
    // FF2: T += FFH @ f2T + f2b, K=256
    {
      int mt = wid >> 2;
      bf16x8 Af2[8];
#pragma unroll
      for (int kf = 0; kf < 8; ++kf)
        Af2[kf] = *(const bf16x8*)(FFH + (mt * 16 + fr) * 264 + kf * 32 + g * 8);
#pragma unroll
      for (int i = 0; i < 2; ++i) {
        int nt = (wid & 3) * 2 + i;
        const unsigned short* bp = xfw + XFW_F2 + l * 32768 + (nt * 16 + fr) * 256;
        f32x4 acc = {0.f, 0.f, 0.f, 0.f};
#pragma unroll
        for (int kf = 0; kf < 8; ++kf)
          acc = __builtin_amdgcn_mfma_f32_16x16x32_bf16(Af2[kf], *(const bf16x8*)(bp + kf * 32 + g * 8), acc, 0, 0, 0);
        int n = nt * 16 + fr;
        float bb = f2b[l * 128 + n];
#pragma unroll
        for (int j = 0; j < 4; ++j)
          T[(mt * 16 + g * 4 + j) * 132 + n] += acc[j] + bb;
      }
    }
    __syncthreads();
  }

  // ctx = LN(t) * mask -> S scratch ; g = [mean|max]
  ln_f32(T, S, og_, ob_, mst, scr);
  for (int idx = tid; idx < 4096; idx += 512) {
    int mm = idx >> 7, j = idx & 127;
    float c = S[mm * 132 + j] * mkv[mm];
    S[mm * 132 + j] = c;
    ctxws[(b * 32 + mm) * 128 + j] = c;
  }
  __syncthreads();
  if (tid < 128) {
    float cnt = 0;
    for (int mm = 0; mm < 32; ++mm) cnt += mkv[mm];
    cnt = fmaxf(cnt, 1.0f);
    float s = 0, mx = -1e9f;
    for (int mm = 0; mm < 32; ++mm) {
      float v = S[mm * 132 + tid];
      s += v;
      if (mkv[mm] > 0.0f) mx = fmaxf(mx, v);
    }
    gws[b * 256 + tid] = s / cnt;
    gws[b * 256 + 128 + tid] = mx;
  }
}

// ---------------------------------------------------------------------------
// Kernel 3: gates — top-2 + weights + expert lists + bf16 row pack
// ---------------------------------------------------------------------------
__global__ __launch_bounds__(64) void gates_kernel(
    const float* __restrict__ gws, const float* __restrict__ ctxws,
    const float* __restrict__ gfw, const float* __restrict__ gfb,
    const float* __restrict__ glw, const float* __restrict__ glb,
    const float* __restrict__ grw, const float* __restrict__ grb,
    float* __restrict__ gwt, int* __restrict__ ecnt, int* __restrict__ elist,
    unsigned short* __restrict__ xbf) {
  __shared__ float lg[16];
  int r = blockIdx.x;
  const float* in; const float* W; const float* Bb; int dl; int rr = 0;
  if (r < 16)      { rr = r;      in = gws + rr * 256;       W = gfw; Bb = gfb; dl = 256; }
  else if (r < 32) { rr = r - 16; in = gws + rr * 256;       W = glw; Bb = glb; dl = 256; }
  else             { in = ctxws + (r - 32) * 128;            W = grw; Bb = grb; dl = 128; }
  if (threadIdx.x < 16) {
    float a = Bb[threadIdx.x];
    for (int d = 0; d < dl; ++d) a = fmaf(in[d], W[d * 16 + threadIdx.x], a);
    lg[threadIdx.x] = a;
  }
  // pack xbf row (256 bf16)
#pragma unroll
  for (int q = 0; q < 4; ++q) {
    int d = threadIdx.x * 4 + q;
    float v;
    if (r < 32) v = gws[rr * 256 + d];
    else        v = (d < 128) ? ctxws[(r - 32) * 128 + d]
                              : gws[((r - 32) >> 5) * 256 + (d - 128)];
    xbf[r * 256 + d] = f2bf(v);
  }
  __syncthreads();
  if (threadIdx.x == 0) {
    int i0 = 0; float v0 = lg[0];
    for (int e = 1; e < 16; ++e) if (lg[e] > v0) { v0 = lg[e]; i0 = e; }
    int i1 = (i0 == 0) ? 1 : 0; float v1 = lg[i1];
    for (int e = 0; e < 16; ++e) if (e != i0 && lg[e] > v1) { v1 = lg[e]; i1 = e; }
    float e1 = __expf(v1 - v0);
    float w0 = 1.0f / (1.0f + e1);
    gwt[2 * r] = w0;  gwt[2 * r + 1] = 1.0f - w0;
    int p0 = atomicAdd(&ecnt[i0], 1); elist[i0 * 544 + p0] = 2 * r;
    int p1 = atomicAdd(&ecnt[i1], 1); elist[i1 * 544 + p1] = 2 * r + 1;
  }
}

// ---------------------------------------------------------------------------
// Kernel 4: MoE experts — batched MFMA GEMM per expert
// ---------------------------------------------------------------------------
__global__ __launch_bounds__(512) void moe_kernel(
    const unsigned short* __restrict__ xbf, const float* __restrict__ gwt,
    const int* __restrict__ elist, const int* __restrict__ ecnt,
    const unsigned short* __restrict__ w1t, const float* __restrict__ eb1,
    const unsigned short* __restrict__ w2t, const float* __restrict__ eb2,
    float* __restrict__ yall) {
  __shared__ unsigned short Xb[16 * 264];
  __shared__ unsigned short Hb[16 * 520];
  __shared__ float wl[16];
  __shared__ int rowl[16];
  const int e = blockIdx.x >> 3;
  const int slot = blockIdx.x & 7;
  const int n = ecnt[e];
  const int ntiles = (n + 15) >> 4;
  const int tid = threadIdx.x;
  const int wid = tid >> 6;
  const int lane = tid & 63;
  const int fr = lane & 15;
  const int g = lane >> 4;

  for (int t = slot; t < ntiles; t += 8) {
    if (tid < 16) {
      int idx = t * 16 + tid;
      int id = (idx < n) ? elist[e * 544 + idx] : -1;
      rowl[tid] = (id >= 0) ? (id >> 1) : -1;
      wl[tid] = (id >= 0) ? gwt[id] : 0.f;
    }
    __syncthreads();
    for (int i = tid; i < 512; i += 512) {
      int r = i >> 5, c8 = (i & 31) * 8;
      int row = rowl[r];
      bf16x8 v = {0, 0, 0, 0, 0, 0, 0, 0};
      if (row >= 0) v = *(const bf16x8*)(xbf + row * 256 + c8);
      *(bf16x8*)(Xb + r * 264 + c8) = v;
    }
    __syncthreads();
    // GEMM1: H[16][512] = relu(X @ W1 + b1)
    bf16x8 Af[8];
#pragma unroll
    for (int kf = 0; kf < 8; ++kf)
      Af[kf] = *(const bf16x8*)(Xb + fr * 264 + kf * 32 + g * 8);
#pragma unroll
    for (int ntl = 0; ntl < 4; ++ntl) {
      int nt = wid * 4 + ntl;
      const unsigned short* bp = w1t + (e * 512 + nt * 16 + fr) * 256;
      f32x4 acc = {0.f, 0.f, 0.f, 0.f};
#pragma unroll
      for (int kf = 0; kf < 8; ++kf)
        acc = __builtin_amdgcn_mfma_f32_16x16x32_bf16(Af[kf], *(const bf16x8*)(bp + kf * 32 + g * 8), acc, 0, 0, 0);
      int h = nt * 16 + fr;
      float b1v = eb1[e * 512 + h];
#pragma unroll
      for (int j = 0; j < 4; ++j)
        Hb[(g * 4 + j) * 520 + h] = f2bf(fmaxf(acc[j] + b1v, 0.f));
    }
    __syncthreads();
    // GEMM2: Y[16][128] = H @ W2 + b2, scaled atomic scatter
    {
      const unsigned short* bp = w2t + (e * 128 + wid * 16 + fr) * 512;
      f32x4 acc = {0.f, 0.f, 0.f, 0.f};
#pragma unroll
      for (int kf = 0; kf < 16; ++kf) {
        bf16x8 Ah = *(const bf16x8*)(Hb + fr * 520 + kf * 32 + g * 8);
        acc = __builtin_amdgcn_mfma_f32_16x16x32_bf16(Ah, *(const bf16x8*)(bp + kf * 32 + g * 8), acc, 0, 0, 0);
      }
      int o = wid * 16 + fr;
      float b2v = eb2[e * 128 + o];
#pragma unroll
      for (int j = 0; j < 4; ++j) {
        int r = g * 4 + j;
        int row = rowl[r];
        if (row >= 0) atomicAdd(&yall[row * 128 + o], wl[r] * (acc[j] + b2v));
      }
    }
    __syncthreads();
  }
}

// ---------------------------------------------------------------------------
// Kernel 5: output heads -> fp32 output
// ---------------------------------------------------------------------------
__global__ __launch_bounds__(192) void heads_kernel(
    const float* __restrict__ x, const float* __restrict__ mask,
    const float* __restrict__ pooledws, const float* __restrict__ ctxws,
    const float* __restrict__ yf, const float* __restrict__ yfail, const float* __restrict__ yrca,
    const float* __restrict__ pw, const float* __restrict__ pb,
    const float* __restrict__ fw, const float* __restrict__ fb,
    const float* __restrict__ rw, const float* __restrict__ rb,
    float* __restrict__ out) {
  __shared__ float yfb[128];
  int b = blockIdx.x, t = threadIdx.x;
  if (t < 128) yfb[t] = yf[b * 128 + t];
  __syncthreads();
  if (t < 96) {
    int mm = t / 3, o = t - mm * 3;
    int s = b * 32 + mm;
    float a = pb[o];
    const float* pl = pooledws + s * 64;
    for (int i = 0; i < 64; ++i) a = fmaf(pl[i], pw[i * 3 + o], a);
    const float* cx = ctxws + s * 128;
    for (int i = 0; i < 128; ++i) a = fmaf(cx[i], pw[(64 + i) * 3 + o], a);
    for (int i = 0; i < 128; ++i) a = fmaf(yfb[i], pw[(192 + i) * 3 + o], a);
    a += x[(b * 512 + 511) * 32 + mm] * mask[b * 32 + mm];
    out[b * 131 + t] = a;
  } else if (t < 99) {
    int o = t - 96;
    float a = fb[o];
    const float* yl = yfail + b * 128;
    for (int i = 0; i < 128; ++i) a = fmaf(yl[i], fw[i * 3 + o], a);
    out[b * 131 + 96 + o] = a;
  } else if (t < 131) {
    int mm = t - 99;
    int s = b * 32 + mm;
    float a = rb[0];
    const float* pl = pooledws + s * 64;
    for (int i = 0; i < 64; ++i) a = fmaf(pl[i], rw[i], a);
    const float* cx = ctxws + s * 128;
    for (int i = 0; i < 128; ++i) a = fmaf(cx[i], rw[64 + i], a);
    const float* yr = yrca + s * 128;
    for (int i = 0; i < 128; ++i) a = fmaf(yr[i], rw[192 + i], a);
    out[b * 131 + 99 + mm] = a;
  }
}

// ---------------------------------------------------------------------------
extern "C" void kernel_launch(void* const* d_in, const int* in_sizes, int n_in,
                              void* d_out, int out_size, void* d_ws, size_t ws_size,
                              hipStream_t stream) {
  (void)in_sizes; (void)n_in; (void)out_size; (void)ws_size;
  const float* x    = (const float*)d_in[0];
  const float* msk  = (const float*)d_in[1];
  const float* epw  = (const float*)d_in[2];
  const float* epb  = (const float*)d_in[3];
  const float* tw1  = (const float*)d_in[4];
  const float* tb1  = (const float*)d_in[5];
  const float* tw2  = (const float*)d_in[6];
  const float* tb2  = (const float*)d_in[7];
  const float* eng  = (const float*)d_in[8];
  const float* enb  = (const float*)d_in[9];
  const float* ppw  = (const float*)d_in[10];
  const float* ppb  = (const float*)d_in[11];
  const float* pos  = (const float*)d_in[12];
  const float* twq  = (const float*)d_in[13];
  const float* tbq  = (const float*)d_in[14];
  const float* twk  = (const float*)d_in[15];
  const float* tbk  = (const float*)d_in[16];
  const float* twv  = (const float*)d_in[17];
  const float* tbv  = (const float*)d_in[18];
  const float* two  = (const float*)d_in[19];
  const float* tbo  = (const float*)d_in[20];
  const float* l1g  = (const float*)d_in[21];
  const float* l1b  = (const float*)d_in[22];
  const float* l2g  = (const float*)d_in[23];
  const float* l2b  = (const float*)d_in[24];
  const float* f1w  = (const float*)d_in[25];
  const float* f1b  = (const float*)d_in[26];
  const float* f2w  = (const float*)d_in[27];
  const float* f2b  = (const float*)d_in[28];
  const float* tog  = (const float*)d_in[29];
  const float* tob  = (const float*)d_in[30];
  const float* ew1  = (const float*)d_in[31];
  const float* eb1  = (const float*)d_in[32];
  const float* ew2  = (const float*)d_in[33];
  const float* eb2  = (const float*)d_in[34];
  const float* gfw  = (const float*)d_in[35];
  const float* gfb  = (const float*)d_in[36];
  const float* glw  = (const float*)d_in[37];
  const float* glb  = (const float*)d_in[38];
  const float* grw  = (const float*)d_in[39];
  const float* grb  = (const float*)d_in[40];
  const float* prw  = (const float*)d_in[41];
  const float* prb  = (const float*)d_in[42];
  const float* fw   = (const float*)d_in[43];
  const float* fb   = (const float*)d_in[44];
  const float* rw   = (const float*)d_in[45];
  const float* rb   = (const float*)d_in[46];

  float* ws      = (float*)d_ws;
  float* psum    = ws;                     // 32768
  float* pooledw = psum + 32768;           // 32768
  float* ctxw    = pooledw + 32768;        // 65536
  float* gwsb    = ctxw + 65536;           // 4096
  float* yall    = gwsb + 4096;            // 544*128 = 69632
  float* gwt     = yall + 69632;           // 1088
  int*   ecnt    = (int*)(gwt + 1088);     // 16
  int*   elist   = ecnt + 16;              // 16*544 = 8704
  float* peT     = (float*)(elist + 8704); // 32768
  unsigned short* wpack = (unsigned short*)(peT + 32768);  // 98304
  unsigned short* xfw   = wpack + 98304;                   // 270336
  unsigned short* w1t   = xfw + 270336;                    // 2097152
  unsigned short* w2t   = w1t + 2097152;                   // 1048576
  unsigned short* xbf   = w2t + 1048576;                   // 139264

  const int tcn_lds = 2 * ROWS_ * LDA_ * 2 + (ROWS_ + 256) * 4;  // 61760 B
  const int xf_lds  = (4224 + 12672 + 8448 + 512 + 64 + 32 + 2176 + 2176 + 4224) * 4;  // 138112 B
  hipFuncSetAttribute((const void*)tcn_kernel, hipFuncAttributeMaxDynamicSharedMemorySize, tcn_lds);
  hipFuncSetAttribute((const void*)xf_kernel,  hipFuncAttributeMaxDynamicSharedMemorySize, xf_lds);

  hipMemsetAsync(psum, 0, 32768 * sizeof(float), stream);
  hipMemsetAsync(yall, 0, 69632 * sizeof(float), stream);
  hipMemsetAsync(ecnt, 0, 16 * sizeof(int), stream);

  prep_kernel<<<842, 256, 0, stream>>>(ppw, twq, twk, twv, two, f1w, f2w, ew1, ew2,
                                       tw1, tw2, xfw, w1t, w2t, wpack, peT);
  tcn_kernel<<<2048, 512, tcn_lds, stream>>>(x, msk, epw, epb, wpack, tb1, tb2, peT,
                                             eng, enb, psum);
  xf_kernel<<<16, 512, xf_lds, stream>>>(psum, msk, xfw, ppb, pos,
                                         tbq, tbk, tbv, tbo,
                                         l1g, l1b, l2g, l2b, f1b, f2b,
                                         tog, tob, pooledw, ctxw, gwsb);
  gates_kernel<<<544, 64, 0, stream>>>(gwsb, ctxw, gfw, gfb, glw, glb, grw, grb,
                                       gwt, ecnt, elist, xbf);
  moe_kernel<<<128, 512, 0, stream>>>(xbf, gwt, elist, ecnt, w1t, eb1, w2t, eb2, yall);
  heads_kernel<<<16, 192, 0, stream>>>(x, msk, pooledw, ctxw,
                                       yall, yall + 2048, yall + 4096,
                                       prw, prb, fw, fb, rw, rb, (float*)d_out);
}

// Round 7
// 305.083 us; speedup vs baseline: 4.9208x; 1.1665x over previous
//
#include <hip/hip_runtime.h>
#include <hip/hip_bf16.h>

// Problem constants
#define B_   16
#define L_   512
#define M_   32
#define P_   64
#define D_   128
#define NH_  8
#define NL_  2
#define E_   16
#define EH_  512
#define O_   128

// TCN chunking: 2 chunks of 256 per sequence
#define HALO  60
#define PADF  16
#define CH2   256
#define ROWS2 336   // PADF + 20 n-tiles * 16
#define LDA_  72

typedef short  bf16x8 __attribute__((ext_vector_type(8)));
typedef float  f32x4  __attribute__((ext_vector_type(4)));
typedef unsigned short us4 __attribute__((ext_vector_type(4)));

__device__ __forceinline__ float bf2f(unsigned short h) {
  unsigned u = ((unsigned)h) << 16; float f; __builtin_memcpy(&f, &u, 4); return f;
}
__device__ __forceinline__ unsigned short f2bf(float f) {
  unsigned u; __builtin_memcpy(&u, &f, 4);
  u += 0x7fffu + ((u >> 16) & 1);
  return (unsigned short)(u >> 16);
}

// xfw packed-buffer offsets (bf16 elements)
#define XFW_PPW   0
#define XFW_QKVO  8192      // + l*65536 + gem*16384   [128n][128k]
#define XFW_F1    139264    // + l*32768               [256n][128k]
#define XFW_F2    204800    // + l*32768               [128n][256k]

// ---------------------------------------------------------------------------
// Kernel 0: prep — tiled transposes f32->bf16 + conv wpack + PE table
// ---------------------------------------------------------------------------
__global__ __launch_bounds__(256) void prep_kernel(
    const float* __restrict__ ppw,
    const float* __restrict__ twq, const float* __restrict__ twk,
    const float* __restrict__ twv, const float* __restrict__ two,
    const float* __restrict__ f1w, const float* __restrict__ f2w,
    const float* __restrict__ ew1, const float* __restrict__ ew2,
    const float* __restrict__ tw1, const float* __restrict__ tw2,
    unsigned short* __restrict__ xfw, unsigned short* __restrict__ w1t,
    unsigned short* __restrict__ w2t, unsigned short* __restrict__ wpack,
    float* __restrict__ peT) {
  const int b = blockIdx.x;
  const int tid = threadIdx.x;
  if (b < 834) {
    __shared__ float tl[64][65];
    const float* src; unsigned short* dst; int R, C, tr, tc;
    if (b < 2) {
      src = ppw; dst = xfw + XFW_PPW; R = 64; C = 128; tr = 0; tc = b;
    } else if (b < 34) {
      int t = b - 2; int lg = t >> 2; int l = lg >> 2, gem = lg & 3;
      int tt = t & 3; tr = tt >> 1; tc = tt & 1;
      const float* s4 = (gem == 0) ? twq : (gem == 1) ? twk : (gem == 2) ? twv : two;
      src = s4 + l * 16384; dst = xfw + XFW_QKVO + l * 65536 + gem * 16384; R = 128; C = 128;
    } else if (b < 50) {
      int t = b - 34; int l = t >> 3; int tt = t & 7; tr = tt >> 2; tc = tt & 3;
      src = f1w + l * 32768; dst = xfw + XFW_F1 + l * 32768; R = 128; C = 256;
    } else if (b < 66) {
      int t = b - 50; int l = t >> 3; int tt = t & 7; tr = tt >> 1; tc = tt & 1;
      src = f2w + l * 32768; dst = xfw + XFW_F2 + l * 32768; R = 256; C = 128;
    } else if (b < 578) {
      int t = b - 66; int e = t >> 5; int tt = t & 31; tr = tt >> 3; tc = tt & 7;
      src = ew1 + e * 131072; dst = w1t + e * 131072; R = 256; C = 512;
    } else {
      int t = b - 578; int e = t >> 4; int tt = t & 15; tr = tt >> 1; tc = tt & 1;
      src = ew2 + e * 65536; dst = w2t + e * 65536; R = 512; C = 128;
    }
    for (int i = tid; i < 4096; i += 256) {
      int r = i >> 6, c = i & 63;
      tl[r][c] = src[(tr * 64 + r) * C + tc * 64 + c];
    }
    __syncthreads();
    for (int i = tid; i < 4096; i += 256) {
      int c = i >> 6, r = i & 63;
      dst[(tc * 64 + c) * R + tr * 64 + r] = f2bf(tl[r][c]);
    }
  } else if (b < 840) {
    int base = (b - 834) * 16384;
    for (int q = tid; q < 16384; q += 256) {
      int i = base + q;
      int c = i & 63, o = (i >> 6) & 63, tlc = i >> 12;
      int t = tlc % 3, lc = tlc / 3, lvl = lc >> 1;
      const float* src = (lc & 1) ? tw2 : tw1;
      wpack[i] = f2bf(src[lvl * 12288 + o * 192 + c * 3 + t]);
    }
  } else {
    int base = (b - 840) * 16384;
    for (int q = tid; q < 16384; q += 256) {
      int j = base + q; int ll = j >> 6, c = j & 63;
      float dv = expf(-0.14391157f * (float)(c & ~1));
      float ang = (float)ll * dv;
      peT[j] = (c & 1) ? cosf(ang) : sinf(ang);
    }
  }
}

// ---------------------------------------------------------------------------
// Kernel 1: TCN — 2 chunks/seq, LDS-staged dbuf weights, MFMA convs
// ---------------------------------------------------------------------------
template <int DIL, bool RES>
__device__ __forceinline__ void conv_mfma(const unsigned short* __restrict__ IN,
                                          unsigned short* __restrict__ OUT,
                                          const unsigned short* __restrict__ Wt,
                                          const float* __restrict__ bias, bool zh) {
  const int tid  = threadIdx.x;
  const int wid  = tid >> 6;
  const int lane = tid & 63;
  const int fr   = lane & 15;
  const int g    = lane >> 4;
  const int ot0  = (wid & 1) * 2;   // 2 o-tiles per wave
  const int ng   = wid >> 1;        // 4 n-groups, 5 tiles each (stride 4)

  bf16x8 Af[2][6];
#pragma unroll
  for (int oo = 0; oo < 2; ++oo)
#pragma unroll
    for (int t = 0; t < 3; ++t)
#pragma unroll
      for (int kh = 0; kh < 2; ++kh)
        Af[oo][t * 2 + kh] =
            *(const bf16x8*)(Wt + (t * 64 + (ot0 + oo) * 16 + fr) * LDA_ + kh * 32 + g * 8);
  float bv[2][4];
#pragma unroll
  for (int oo = 0; oo < 2; ++oo)
#pragma unroll
    for (int j = 0; j < 4; ++j) bv[oo][j] = bias[(ot0 + oo) * 16 + g * 4 + j];

#pragma unroll
  for (int ni = 0; ni < 5; ++ni) {
    const int nt = ng + ni * 4;
    const int rb = PADF + nt * 16 + fr;
    bf16x8 Bf[6];
#pragma unroll
    for (int t = 0; t < 3; ++t) {
      int r = rb + (t - 2) * DIL;   // causal taps at l-2d, l-d, l
#pragma unroll
      for (int kh = 0; kh < 2; ++kh)
        Bf[t * 2 + kh] = *(const bf16x8*)(IN + r * LDA_ + kh * 32 + g * 8);
    }
    f32x4 acc[2];
#pragma unroll
    for (int oo = 0; oo < 2; ++oo) {
      f32x4 a; a[0] = bv[oo][0]; a[1] = bv[oo][1]; a[2] = bv[oo][2]; a[3] = bv[oo][3];
      acc[oo] = a;
    }
#pragma unroll
    for (int f = 0; f < 6; ++f)
#pragma unroll
      for (int oo = 0; oo < 2; ++oo)
        acc[oo] = __builtin_amdgcn_mfma_f32_16x16x32_bf16(Af[oo][f], Bf[f], acc[oo], 0, 0, 0);

    const float zm = (zh && rb < PADF + HALO) ? 0.f : 1.f;
#pragma unroll
    for (int oo = 0; oo < 2; ++oo) {
      unsigned short* op = OUT + rb * LDA_ + (ot0 + oo) * 16 + g * 4;
      us4 old;
      if (RES) old = *(const us4*)op;
      us4 st;
#pragma unroll
      for (int j = 0; j < 4; ++j) {
        float v = fmaxf(acc[oo][j], 0.f);
        if (RES) v = fmaxf(v + bf2f(old[j]), 0.f);
        st[j] = f2bf(v * zm);
      }
      *(us4*)op = st;
    }
  }
}

__global__ __launch_bounds__(512) void tcn_kernel(
    const float* __restrict__ x, const float* __restrict__ mask,
    const float* __restrict__ pw, const float* __restrict__ pb,
    const unsigned short* __restrict__ wpack,
    const float* __restrict__ b1, const float* __restrict__ b2,
    const float* __restrict__ peT,
    const float* __restrict__ lng, const float* __restrict__ lnb,
    float* __restrict__ psum) {
  extern __shared__ unsigned short smu[];
  unsigned short* A  = smu;                     // 336*72 bf16
  unsigned short* Bq = A + ROWS2 * LDA_;        // 336*72
  unsigned short* W0 = Bq + ROWS2 * LDA_;       // 192*72
  unsigned short* W1 = W0 + 192 * LDA_;         // 192*72
  float* xr  = (float*)(W1 + 192 * LDA_);       // 336 f32
  float* mst = xr + ROWS2;                      // 512 f32   total 155456 B

  const int bx = blockIdx.x;
  const int seq = bx & 511;
  const int chunk = bx >> 9;      // high-bit chunk: decorrelate mask across CUs
  const int b = seq >> 5;
  const int m = seq & 31;
  if (mask[b * M_ + m] == 0.0f) return;
  const int tid = threadIdx.x;
  const bool zh = (chunk == 0);
  const int lbase = chunk * CH2 - HALO;

  // weight stage helpers: 3 x 16B per thread per conv, row remap 64->72 stride
#define WLOAD(li)                                                              \
  { _Pragma("unroll") for (int q = 0; q < 3; ++q)                              \
      wreg[q] = *(const float4*)(wpack + (li) * 12288 +                        \
                                 (q * 64 + (tid >> 3)) * 64 + (tid & 7) * 8); }
#define WSTORE(buf)                                                            \
  { _Pragma("unroll") for (int q = 0; q < 3; ++q)                              \
      *(float4*)((buf) + (q * 64 + (tid >> 3)) * LDA_ + (tid & 7) * 8) = wreg[q]; }

  float4 wreg[3];
  WLOAD(0);

  // stage x values once (208->336 rows)
  for (int r = tid; r < ROWS2; r += 512) {
    int w = r - PADF, l = lbase + w;
    float xv = 0.f;
    if (w >= 0 && w < CH2 + HALO && l >= 0 && l < L_) xv = x[(b * L_ + l) * M_ + m];
    xr[r] = xv;
  }
  WSTORE(W0);
  __syncthreads();

  // build A = proj(x) + PE, bf16
  for (int idx = tid; idx < ROWS2 * 64; idx += 512) {
    int r = idx >> 6, c = idx & 63;
    int w = r - PADF, l = lbase + w;
    float v = 0.f;
    if (w >= 0 && w < CH2 + HALO && l >= 0 && l < L_)
      v = fmaf(xr[r], pw[c], pb[c]) + peT[l * 64 + c];
    A[r * LDA_ + c] = f2bf(v);
  }
  for (int idx = tid; idx < PADF * LDA_; idx += 512) Bq[idx] = 0;
  WLOAD(1);
  __syncthreads();

  // 8 convs, weights double-buffered W0/W1 (prefetch i+1 during conv i)
  conv_mfma<1, false>(A, Bq, W0, b1 + 0,   zh); WSTORE(W1); __syncthreads();
  WLOAD(2);
  conv_mfma<1, true >(Bq, A, W1, b2 + 0,   zh); WSTORE(W0); __syncthreads();
  WLOAD(3);
  conv_mfma<2, false>(A, Bq, W0, b1 + 64,  zh); WSTORE(W1); __syncthreads();
  WLOAD(4);
  conv_mfma<2, true >(Bq, A, W1, b2 + 64,  zh); WSTORE(W0); __syncthreads();
  WLOAD(5);
  conv_mfma<4, false>(A, Bq, W0, b1 + 128, zh); WSTORE(W1); __syncthreads();
  WLOAD(6);
  conv_mfma<4, true >(Bq, A, W1, b2 + 128, zh); WSTORE(W0); __syncthreads();
  WLOAD(7);
  conv_mfma<8, false>(A, Bq, W0, b1 + 192, zh); WSTORE(W1); __syncthreads();
  conv_mfma<8, true >(Bq, A, W1, b2 + 192, zh); __syncthreads();
#undef WLOAD
#undef WSTORE

  // LayerNorm over channels at each of 256 valid positions
  if (tid < CH2) {
    int r = PADF + HALO + tid;
    float s = 0.f, ss = 0.f;
    const bf16x8* ap = (const bf16x8*)(A + r * LDA_);
#pragma unroll
    for (int c8 = 0; c8 < 8; ++c8) {
      bf16x8 vv = ap[c8];
#pragma unroll
      for (int j = 0; j < 8; ++j) { float v = bf2f((unsigned short)vv[j]); s += v; ss += v * v; }
    }
    float mu = s * 0.015625f;
    float var = fmaxf(ss * 0.015625f - mu * mu, 0.0f);
    mst[tid] = mu;
    mst[CH2 + tid] = rsqrtf(var + 1e-5f);
  }
  __syncthreads();
  {
    int p = tid & 63, q = tid >> 6;          // 8 row-groups of 32
    float accp = 0.f;
    int r0 = PADF + HALO + q * 32;
    for (int r = r0; r < r0 + 32; ++r)
      accp += (bf2f(A[r * LDA_ + p]) - mst[r - PADF - HALO]) * mst[CH2 + r - PADF - HALO];
    atomicAdd(&psum[seq * 64 + p], lng[p] * accp + 32.0f * lnb[p]);
  }
}

// ---------------------------------------------------------------------------
// Kernel 2: transformer — MFMA GEMMs, B-frags streamed from global bf16
// ---------------------------------------------------------------------------
__device__ __forceinline__ void ln_sums(const float* __restrict__ In, float* mst, float* scr) {
  const int t = threadIdx.x;
  if (t < 256) {
    int mm = t >> 3, sg = t & 7;
    const float* ip = In + mm * 132 + sg * 16;
    float s = 0, ss = 0;
#pragma unroll
    for (int j = 0; j < 16; ++j) { float v = ip[j]; s += v; ss += v * v; }
    scr[t] = s; scr[256 + t] = ss;
  }
  __syncthreads();
  if (t < 32) {
    float s = 0, ss = 0;
#pragma unroll
    for (int k = 0; k < 8; ++k) { s += scr[t * 8 + k]; ss += scr[256 + t * 8 + k]; }
    float mu = s * 0.0078125f;
    float var = fmaxf(ss * 0.0078125f - mu * mu, 0.f);
    mst[t] = mu;
    mst[32 + t] = rsqrtf(var + 1e-5f);
  }
  __syncthreads();
}

__device__ __forceinline__ void ln_bf(const float* __restrict__ In, unsigned short* __restrict__ Out,
                                      const float* __restrict__ g, const float* __restrict__ b,
                                      float* mst, float* scr) {
  ln_sums(In, mst, scr);
  for (int idx = threadIdx.x; idx < 4096; idx += 512) {
    int mm = idx >> 7, j = idx & 127;
    Out[mm * 136 + j] = f2bf((In[mm * 132 + j] - mst[mm]) * mst[32 + mm] * g[j] + b[j]);
  }
  __syncthreads();
}

__device__ __forceinline__ void ln_f32(const float* __restrict__ In, float* __restrict__ Out,
                                       const float* __restrict__ g, const float* __restrict__ b,
                                       float* mst, float* scr) {
  ln_sums(In, mst, scr);
  for (int idx = threadIdx.x; idx < 4096; idx += 512) {
    int mm = idx >> 7, j = idx & 127;
    Out[mm * 132 + j] = (In[mm * 132 + j] - mst[mm]) * mst[32 + mm] * g[j] + b[j];
  }
  __syncthreads();
}

__global__ __launch_bounds__(512) void xf_kernel(
    const float* __restrict__ psum, const float* __restrict__ mask,
    const unsigned short* __restrict__ xfw,
    const float* __restrict__ ppb, const float* __restrict__ pos,
    const float* __restrict__ bq, const float* __restrict__ bk,
    const float* __restrict__ bv, const float* __restrict__ bo,
    const float* __restrict__ l1g, const float* __restrict__ l1b,
    const float* __restrict__ l2g, const float* __restrict__ l2b,
    const float* __restrict__ f1b, const float* __restrict__ f2b,
    const float* __restrict__ og_, const float* __restrict__ ob_,
    float* __restrict__ pooledws, float* __restrict__ ctxws, float* __restrict__ gws) {
  extern __shared__ float sm[];
  float* T    = sm;                 // 32*132
  float* QKV  = T + 4224;           // 32*396
  float* S    = QKV + 12672;        // 8448
  float* scr  = S + 8448;           // 512
  float* mst  = scr + 512;          // 64
  float* mkv  = mst + 64;           // 32
  unsigned short* Ybf = (unsigned short*)(mkv + 32);   // [32][136]
  unsigned short* Yb2 = Ybf + 32 * 136;                // [32][136]
  unsigned short* FFH = Yb2 + 32 * 136;                // [32][264]
  const int b = blockIdx.x;
  const int tid = threadIdx.x;
  const int wid = tid >> 6;
  const int lane = tid & 63;
  const int fr = lane & 15;
  const int g = lane >> 4;

  if (tid < 32) mkv[tid] = mask[b * 32 + tid];
  for (int idx = tid; idx < 2048; idx += 512) {
    int mm = idx >> 6, p = idx & 63;
    float v = mask[b * 32 + mm] * psum[(b * 32 + mm) * 64 + p] * (1.0f / 512.0f);
    pooledws[(b * 32 + mm) * 64 + p] = v;
    Ybf[mm * 136 + p] = f2bf(v);
  }
  __syncthreads();

  // pool-proj
  {
    int mt = wid >> 2;
    bf16x8 Af[2];
#pragma unroll
    for (int kf = 0; kf < 2; ++kf)
      Af[kf] = *(const bf16x8*)(Ybf + (mt * 16 + fr) * 136 + kf * 32 + g * 8);
#pragma unroll
    for (int i = 0; i < 2; ++i) {
      int nt = (wid & 3) * 2 + i;
      const unsigned short* bp = xfw + XFW_PPW + (nt * 16 + fr) * 64;
      f32x4 acc = {0.f, 0.f, 0.f, 0.f};
#pragma unroll
      for (int kf = 0; kf < 2; ++kf)
        acc = __builtin_amdgcn_mfma_f32_16x16x32_bf16(Af[kf], *(const bf16x8*)(bp + kf * 32 + g * 8), acc, 0, 0, 0);
      int n = nt * 16 + fr;
      float bb = ppb[n];
#pragma unroll
      for (int j = 0; j < 4; ++j) {
        int m = mt * 16 + g * 4 + j;
        T[m * 132 + n] = acc[j] + bb + pos[m * 128 + n];
      }
    }
  }
  __syncthreads();

  for (int l = 0; l < NL_; ++l) {
    ln_bf(T, Ybf, l1g + l * 128, l1b + l * 128, mst, scr);
#pragma unroll
    for (int i = 0; i < 6; ++i) {
      int tt = wid * 6 + i;
      int gem = tt >> 4, r = tt & 15, mt = r >> 3, nt = r & 7;
      const unsigned short* wT = xfw + XFW_QKVO + l * 65536 + gem * 16384;
      const float* bias = (gem == 0) ? bq : (gem == 1) ? bk : bv;
      bf16x8 Afr[4];
#pragma unroll
      for (int kf = 0; kf < 4; ++kf)
        Afr[kf] = *(const bf16x8*)(Ybf + (mt * 16 + fr) * 136 + kf * 32 + g * 8);
      const unsigned short* bp = wT + (nt * 16 + fr) * 128;
      f32x4 acc = {0.f, 0.f, 0.f, 0.f};
#pragma unroll
      for (int kf = 0; kf < 4; ++kf)
        acc = __builtin_amdgcn_mfma_f32_16x16x32_bf16(Afr[kf], *(const bf16x8*)(bp + kf * 32 + g * 8), acc, 0, 0, 0);
      int n = nt * 16 + fr;
      float bb = bias[l * 128 + n];
#pragma unroll
      for (int j = 0; j < 4; ++j)
        QKV[(mt * 16 + g * 4 + j) * 396 + gem * 132 + n] = acc[j] + bb;
    }
    __syncthreads();
    for (int idx = tid; idx < 8192; idx += 512) {
      int h = idx >> 10, rem = idx & 1023, mm = rem >> 5, n = rem & 31;
      const float* qp = QKV + mm * 396 + h * 16;
      const float* kp = QKV + n * 396 + 132 + h * 16;
      float a = 0;
#pragma unroll
      for (int d = 0; d < 16; ++d) a = fmaf(qp[d], kp[d], a);
      a *= 0.25f;
      if (mkv[n] == 0.0f) a -= 1e9f;
      S[h * 1056 + mm * 33 + n] = a;
    }
    __syncthreads();
    if (tid < 256) {
      float* sr = S + (tid >> 5) * 1056 + (tid & 31) * 33;
      float mx = sr[0];
      for (int n = 1; n < 32; ++n) mx = fmaxf(mx, sr[n]);
      float sum = 0;
      for (int n = 0; n < 32; ++n) { float e = __expf(sr[n] - mx); sr[n] = e; sum += e; }
      float inv = 1.0f / sum;
      for (int n = 0; n < 32; ++n) sr[n] *= inv;
    }
    __syncthreads();
    for (int idx = tid; idx < 4096; idx += 512) {
      int mm = idx >> 7, jd = idx & 127, h = jd >> 4, d = jd & 15;
      const float* sp = S + h * 1056 + mm * 33;
      const float* vp = QKV + 264 + h * 16 + d;
      float a = 0;
#pragma unroll 8
      for (int n = 0; n < 32; ++n) a = fmaf(sp[n], vp[n * 396], a);
      Yb2[mm * 136 + jd] = f2bf(a);
    }
    __syncthreads();
    {
      int mt = wid >> 2;
      bf16x8 Aw[4];
#pragma unroll
      for (int kf = 0; kf < 4; ++kf)
        Aw[kf] = *(const bf16x8*)(Yb2 + (mt * 16 + fr) * 136 + kf * 32 + g * 8);
#pragma unroll
      for (int i = 0; i < 2; ++i) {
        int nt = (wid & 3) * 2 + i;
        const unsigned short* bp = xfw + XFW_QKVO + l * 65536 + 3 * 16384 + (nt * 16 + fr) * 128;
        f32x4 acc = {0.f, 0.f, 0.f, 0.f};
#pragma unroll
        for (int kf = 0; kf < 4; ++kf)
          acc = __builtin_amdgcn_mfma_f32_16x16x32_bf16(Aw[kf], *(const bf16x8*)(bp + kf * 32 + g * 8), acc, 0, 0, 0);
        int n = nt * 16 + fr;
        float bb = bo[l * 128 + n];
#pragma unroll
        for (int j = 0; j < 4; ++j)
          T[(mt * 16 + g * 4 + j) * 132 + n] += acc[j] + bb;
      }
    }
    __syncthreads();
    ln_bf(T, Ybf, l2g + l * 128, l2b + l * 128, mst, scr);
    {
      int mt = wid >> 2;
      bf16x8 Aff[4];
#pragma unroll
      for (int kf = 0; kf < 4; ++kf)
        Aff[kf] = *(const bf16x8*)(Ybf + (mt * 16 + fr) * 136 + kf * 32 + g * 8);
#pragma unroll
      for (int i = 0; i < 4; ++i) {
        int tt = wid * 4 + i;
        int nt = tt & 15;
        const unsigned short* bp = xfw + XFW_F1 + l * 32768 + (nt * 16 + fr) * 128;
        f32x4 acc = {0.f, 0.f, 0.f, 0.f};
#pragma unroll
        for (int kf = 0; kf < 4; ++kf)
          acc = __builtin_amdgcn_mfma_f32_16x16x32_bf16(Aff[kf], *(const bf16x8*)(bp + kf * 32 + g * 8), acc, 0, 0, 0);
        int n = nt * 16 + fr;
        float bb = f1b[l * 256 + n];
#pragma unroll
        for (int j = 0; j < 4; ++j)
          FFH[(mt * 16 + g * 4 + j) * 264 + n] = f2bf(fmaxf(acc[j] + bb, 0.f));
      }
    }
    __syncthreads();
    {
      int mt = wid >> 2;
      bf16x8 Af2[8];
#pragma unroll
      for (int kf = 0; kf < 8; ++kf)
        Af2[kf] = *(const bf16x8*)(FFH + (mt * 16 + fr) * 264 + kf * 32 + g * 8);
#pragma unroll
      for (int i = 0; i < 2; ++i) {
        int nt = (wid & 3) * 2 + i;
        const unsigned short* bp = xfw + XFW_F2 + l * 32768 + (nt * 16 + fr) * 256;
        f32x4 acc = {0.f, 0.f, 0.f, 0.f};
#pragma unroll
        for (int kf = 0; kf < 8; ++kf)
          acc = __builtin_amdgcn_mfma_f32_16x16x32_bf16(Af2[kf], *(const bf16x8*)(bp + kf * 32 + g * 8), acc, 0, 0, 0);
        int n = nt * 16 + fr;
        float bb = f2b[l * 128 + n];
#pragma unroll
        for (int j = 0; j < 4; ++j)
          T[(mt * 16 + g * 4 + j) * 132 + n] += acc[j] + bb;
      }
    }
    __syncthreads();
  }

  ln_f32(T, S, og_, ob_, mst, scr);
  for (int idx = tid; idx < 4096; idx += 512) {
    int mm = idx >> 7, j = idx & 127;
    float c = S[mm * 132 + j] * mkv[mm];
    S[mm * 132 + j] = c;
    ctxws[(b * 32 + mm) * 128 + j] = c;
  }
  __syncthreads();
  if (tid < 128) {
    float cnt = 0;
    for (int mm = 0; mm < 32; ++mm) cnt += mkv[mm];
    cnt = fmaxf(cnt, 1.0f);
    float s = 0, mx = -1e9f;
    for (int mm = 0; mm < 32; ++mm) {
      float v = S[mm * 132 + tid];
      s += v;
      if (mkv[mm] > 0.0f) mx = fmaxf(mx, v);
    }
    gws[b * 256 + tid] = s / cnt;
    gws[b * 256 + 128 + tid] = mx;
  }
}

// ---------------------------------------------------------------------------
// Kernel 3: gates — top-2 + weights + expert lists + bf16 row pack
// ---------------------------------------------------------------------------
__global__ __launch_bounds__(64) void gates_kernel(
    const float* __restrict__ gws, const float* __restrict__ ctxws,
    const float* __restrict__ gfw, const float* __restrict__ gfb,
    const float* __restrict__ glw, const float* __restrict__ glb,
    const float* __restrict__ grw, const float* __restrict__ grb,
    float* __restrict__ gwt, int* __restrict__ ecnt, int* __restrict__ elist,
    unsigned short* __restrict__ xbf) {
  __shared__ float lg[16];
  int r = blockIdx.x;
  const float* in; const float* W; const float* Bb; int dl; int rr = 0;
  if (r < 16)      { rr = r;      in = gws + rr * 256;       W = gfw; Bb = gfb; dl = 256; }
  else if (r < 32) { rr = r - 16; in = gws + rr * 256;       W = glw; Bb = glb; dl = 256; }
  else             { in = ctxws + (r - 32) * 128;            W = grw; Bb = grb; dl = 128; }
  if (threadIdx.x < 16) {
    float a = Bb[threadIdx.x];
    for (int d = 0; d < dl; ++d) a = fmaf(in[d], W[d * 16 + threadIdx.x], a);
    lg[threadIdx.x] = a;
  }
#pragma unroll
  for (int q = 0; q < 4; ++q) {
    int d = threadIdx.x * 4 + q;
    float v;
    if (r < 32) v = gws[rr * 256 + d];
    else        v = (d < 128) ? ctxws[(r - 32) * 128 + d]
                              : gws[((r - 32) >> 5) * 256 + (d - 128)];
    xbf[r * 256 + d] = f2bf(v);
  }
  __syncthreads();
  if (threadIdx.x == 0) {
    int i0 = 0; float v0 = lg[0];
    for (int e = 1; e < 16; ++e) if (lg[e] > v0) { v0 = lg[e]; i0 = e; }
    int i1 = (i0 == 0) ? 1 : 0; float v1 = lg[i1];
    for (int e = 0; e < 16; ++e) if (e != i0 && lg[e] > v1) { v1 = lg[e]; i1 = e; }
    float e1 = __expf(v1 - v0);
    float w0 = 1.0f / (1.0f + e1);
    gwt[2 * r] = w0;  gwt[2 * r + 1] = 1.0f - w0;
    int p0 = atomicAdd(&ecnt[i0], 1); elist[i0 * 544 + p0] = 2 * r;
    int p1 = atomicAdd(&ecnt[i1], 1); elist[i1 * 544 + p1] = 2 * r + 1;
  }
}

// ---------------------------------------------------------------------------
// Kernel 4: MoE experts — batched MFMA GEMM per expert
// ---------------------------------------------------------------------------
__global__ __launch_bounds__(512) void moe_kernel(
    const unsigned short* __restrict__ xbf, const float* __restrict__ gwt,
    const int* __restrict__ elist, const int* __restrict__ ecnt,
    const unsigned short* __restrict__ w1t, const float* __restrict__ eb1,
    const unsigned short* __restrict__ w2t, const float* __restrict__ eb2,
    float* __restrict__ yall) {
  __shared__ unsigned short Xb[16 * 264];
  __shared__ unsigned short Hb[16 * 520];
  __shared__ float wl[16];
  __shared__ int rowl[16];
  const int e = blockIdx.x >> 3;
  const int slot = blockIdx.x & 7;
  const int n = ecnt[e];
  const int ntiles = (n + 15) >> 4;
  const int tid = threadIdx.x;
  const int wid = tid >> 6;
  const int lane = tid & 63;
  const int fr = lane & 15;
  const int g = lane >> 4;

  for (int t = slot; t < ntiles; t += 8) {
    if (tid < 16) {
      int idx = t * 16 + tid;
      int id = (idx < n) ? elist[e * 544 + idx] : -1;
      rowl[tid] = (id >= 0) ? (id >> 1) : -1;
      wl[tid] = (id >= 0) ? gwt[id] : 0.f;
    }
    __syncthreads();
    for (int i = tid; i < 512; i += 512) {
      int r = i >> 5, c8 = (i & 31) * 8;
      int row = rowl[r];
      bf16x8 v = {0, 0, 0, 0, 0, 0, 0, 0};
      if (row >= 0) v = *(const bf16x8*)(xbf + row * 256 + c8);
      *(bf16x8*)(Xb + r * 264 + c8) = v;
    }
    __syncthreads();
    bf16x8 Af[8];
#pragma unroll
    for (int kf = 0; kf < 8; ++kf)
      Af[kf] = *(const bf16x8*)(Xb + fr * 264 + kf * 32 + g * 8);
#pragma unroll
    for (int ntl = 0; ntl < 4; ++ntl) {
      int nt = wid * 4 + ntl;
      const unsigned short* bp = w1t + (e * 512 + nt * 16 + fr) * 256;
      f32x4 acc = {0.f, 0.f, 0.f, 0.f};
#pragma unroll
      for (int kf = 0; kf < 8; ++kf)
        acc = __builtin_amdgcn_mfma_f32_16x16x32_bf16(Af[kf], *(const bf16x8*)(bp + kf * 32 + g * 8), acc, 0, 0, 0);
      int h = nt * 16 + fr;
      float b1v = eb1[e * 512 + h];
#pragma unroll
      for (int j = 0; j < 4; ++j)
        Hb[(g * 4 + j) * 520 + h] = f2bf(fmaxf(acc[j] + b1v, 0.f));
    }
    __syncthreads();
    {
      const unsigned short* bp = w2t + (e * 128 + wid * 16 + fr) * 512;
      f32x4 acc = {0.f, 0.f, 0.f, 0.f};
#pragma unroll
      for (int kf = 0; kf < 16; ++kf) {
        bf16x8 Ah = *(const bf16x8*)(Hb + fr * 520 + kf * 32 + g * 8);
        acc = __builtin_amdgcn_mfma_f32_16x16x32_bf16(Ah, *(const bf16x8*)(bp + kf * 32 + g * 8), acc, 0, 0, 0);
      }
      int o = wid * 16 + fr;
      float b2v = eb2[e * 128 + o];
#pragma unroll
      for (int j = 0; j < 4; ++j) {
        int r = g * 4 + j;
        int row = rowl[r];
        if (row >= 0) atomicAdd(&yall[row * 128 + o], wl[r] * (acc[j] + b2v));
      }
    }
    __syncthreads();
  }
}

// ---------------------------------------------------------------------------
// Kernel 5: output heads -> fp32 output
// ---------------------------------------------------------------------------
__global__ __launch_bounds__(192) void heads_kernel(
    const float* __restrict__ x, const float* __restrict__ mask,
    const float* __restrict__ pooledws, const float* __restrict__ ctxws,
    const float* __restrict__ yf, const float* __restrict__ yfail, const float* __restrict__ yrca,
    const float* __restrict__ pw, const float* __restrict__ pb,
    const float* __restrict__ fw, const float* __restrict__ fb,
    const float* __restrict__ rw, const float* __restrict__ rb,
    float* __restrict__ out) {
  __shared__ float yfb[128];
  int b = blockIdx.x, t = threadIdx.x;
  if (t < 128) yfb[t] = yf[b * 128 + t];
  __syncthreads();
  if (t < 96) {
    int mm = t / 3, o = t - mm * 3;
    int s = b * 32 + mm;
    float a = pb[o];
    const float* pl = pooledws + s * 64;
    for (int i = 0; i < 64; ++i) a = fmaf(pl[i], pw[i * 3 + o], a);
    const float* cx = ctxws + s * 128;
    for (int i = 0; i < 128; ++i) a = fmaf(cx[i], pw[(64 + i) * 3 + o], a);
    for (int i = 0; i < 128; ++i) a = fmaf(yfb[i], pw[(192 + i) * 3 + o], a);
    a += x[(b * 512 + 511) * 32 + mm] * mask[b * 32 + mm];
    out[b * 131 + t] = a;
  } else if (t < 99) {
    int o = t - 96;
    float a = fb[o];
    const float* yl = yfail + b * 128;
    for (int i = 0; i < 128; ++i) a = fmaf(yl[i], fw[i * 3 + o], a);
    out[b * 131 + 96 + o] = a;
  } else if (t < 131) {
    int mm = t - 99;
    int s = b * 32 + mm;
    float a = rb[0];
    const float* pl = pooledws + s * 64;
    for (int i = 0; i < 64; ++i) a = fmaf(pl[i], rw[i], a);
    const float* cx = ctxws + s * 128;
    for (int i = 0; i < 128; ++i) a = fmaf(cx[i], rw[64 + i], a);
    const float* yr = yrca + s * 128;
    for (int i = 0; i < 128; ++i) a = fmaf(yr[i], rw[192 + i], a);
    out[b * 131 + 99 + mm] = a;
  }
}

// ---------------------------------------------------------------------------
extern "C" void kernel_launch(void* const* d_in, const int* in_sizes, int n_in,
                              void* d_out, int out_size, void* d_ws, size_t ws_size,
                              hipStream_t stream) {
  (void)in_sizes; (void)n_in; (void)out_size; (void)ws_size;
  const float* x    = (const float*)d_in[0];
  const float* msk  = (const float*)d_in[1];
  const float* epw  = (const float*)d_in[2];
  const float* epb  = (const float*)d_in[3];
  const float* tw1  = (const float*)d_in[4];
  const float* tb1  = (const float*)d_in[5];
  const float* tw2  = (const float*)d_in[6];
  const float* tb2  = (const float*)d_in[7];
  const float* eng  = (const float*)d_in[8];
  const float* enb  = (const float*)d_in[9];
  const float* ppw  = (const float*)d_in[10];
  const float* ppb  = (const float*)d_in[11];
  const float* pos  = (const float*)d_in[12];
  const float* twq  = (const float*)d_in[13];
  const float* tbq  = (const float*)d_in[14];
  const float* twk  = (const float*)d_in[15];
  const float* tbk  = (const float*)d_in[16];
  const float* twv  = (const float*)d_in[17];
  const float* tbv  = (const float*)d_in[18];
  const float* two  = (const float*)d_in[19];
  const float* tbo  = (const float*)d_in[20];
  const float* l1g  = (const float*)d_in[21];
  const float* l1b  = (const float*)d_in[22];
  const float* l2g  = (const float*)d_in[23];
  const float* l2b  = (const float*)d_in[24];
  const float* f1w  = (const float*)d_in[25];
  const float* f1b  = (const float*)d_in[26];
  const float* f2w  = (const float*)d_in[27];
  const float* f2b  = (const float*)d_in[28];
  const float* tog  = (const float*)d_in[29];
  const float* tob  = (const float*)d_in[30];
  const float* ew1  = (const float*)d_in[31];
  const float* eb1  = (const float*)d_in[32];
  const float* ew2  = (const float*)d_in[33];
  const float* eb2  = (const float*)d_in[34];
  const float* gfw  = (const float*)d_in[35];
  const float* gfb  = (const float*)d_in[36];
  const float* glw  = (const float*)d_in[37];
  const float* glb  = (const float*)d_in[38];
  const float* grw  = (const float*)d_in[39];
  const float* grb  = (const float*)d_in[40];
  const float* prw  = (const float*)d_in[41];
  const float* prb  = (const float*)d_in[42];
  const float* fw   = (const float*)d_in[43];
  const float* fb   = (const float*)d_in[44];
  const float* rw   = (const float*)d_in[45];
  const float* rb   = (const float*)d_in[46];

  float* ws      = (float*)d_ws;
  float* psum    = ws;                     // 32768
  float* pooledw = psum + 32768;           // 32768
  float* ctxw    = pooledw + 32768;        // 65536
  float* gwsb    = ctxw + 65536;           // 4096
  float* yall    = gwsb + 4096;            // 69632
  float* gwt     = yall + 69632;           // 1088
  int*   ecnt    = (int*)(gwt + 1088);     // 16
  int*   elist   = ecnt + 16;              // 8704
  float* peT     = (float*)(elist + 8704); // 32768
  unsigned short* wpack = (unsigned short*)(peT + 32768);  // 98304
  unsigned short* xfw   = wpack + 98304;                   // 270336
  unsigned short* w1t   = xfw + 270336;                    // 2097152
  unsigned short* w2t   = w1t + 2097152;                   // 1048576
  unsigned short* xbf   = w2t + 1048576;                   // 139264

  const int tcn_lds = (2 * ROWS2 * LDA_ + 2 * 192 * LDA_) * 2 + (ROWS2 + 512) * 4;  // 155456 B
  const int xf_lds  = (4224 + 12672 + 8448 + 512 + 64 + 32 + 2176 + 2176 + 4224) * 4;  // 138112 B
  hipFuncSetAttribute((const void*)tcn_kernel, hipFuncAttributeMaxDynamicSharedMemorySize, tcn_lds);
  hipFuncSetAttribute((const void*)xf_kernel,  hipFuncAttributeMaxDynamicSharedMemorySize, xf_lds);

  hipMemsetAsync(psum, 0, 32768 * sizeof(float), stream);
  hipMemsetAsync(yall, 0, 69632 * sizeof(float), stream);
  hipMemsetAsync(ecnt, 0, 16 * sizeof(int), stream);

  prep_kernel<<<842, 256, 0, stream>>>(ppw, twq, twk, twv, two, f1w, f2w, ew1, ew2,
                                       tw1, tw2, xfw, w1t, w2t, wpack, peT);
  tcn_kernel<<<1024, 512, tcn_lds, stream>>>(x, msk, epw, epb, wpack, tb1, tb2, peT,
                                             eng, enb, psum);
  xf_kernel<<<16, 512, xf_lds, stream>>>(psum, msk, xfw, ppb, pos,
                                         tbq, tbk, tbv, tbo,
                                         l1g, l1b, l2g, l2b, f1b, f2b,
                                         tog, tob, pooledw, ctxw, gwsb);
  gates_kernel<<<544, 64, 0, stream>>>(gwsb, ctxw, gfw, gfb, glw, glb, grw, grb,
                                       gwt, ecnt, elist, xbf);
  moe_kernel<<<128, 512, 0, stream>>>(xbf, gwt, elist, ecnt, w1t, eb1, w2t, eb2, yall);
  heads_kernel<<<16, 192, 0, stream>>>(x, msk, pooledw, ctxw,
                                       yall, yall + 2048, yall + 4096,
                                       prw, prb, fw, fb, rw, rb, (float*)d_out);
}

// Round 8
// 298.754 us; speedup vs baseline: 5.0251x; 1.0212x over previous
//
#include <hip/hip_runtime.h>
#include <hip/hip_bf16.h>

// Problem constants
#define B_   16
#define L_   512
#define M_   32
#define P_   64
#define D_   128
#define NH_  8
#define NL_  2
#define E_   16
#define EH_  512
#define O_   128

// TCN: whole sequence per block
#define PADF  16
#define ROWSF 528   // PADF + 512
#define LDW   64    // bf16 leading dim (128B rows) + XOR swizzle

typedef short  bf16x8 __attribute__((ext_vector_type(8)));
typedef float  f32x4  __attribute__((ext_vector_type(4)));
typedef unsigned short us4 __attribute__((ext_vector_type(4)));
typedef unsigned short us8 __attribute__((ext_vector_type(8)));

__device__ __forceinline__ float bf2f(unsigned short h) {
  unsigned u = ((unsigned)h) << 16; float f; __builtin_memcpy(&f, &u, 4); return f;
}
__device__ __forceinline__ unsigned short f2bf(float f) {
  unsigned u; __builtin_memcpy(&u, &f, 4);
  u += 0x7fffu + ((u >> 16) & 1);
  return (unsigned short)(u >> 16);
}
// swizzled ushort index into a [row][64] bf16 LDS tile (XOR row bits into 16B-slot bits)
__device__ __forceinline__ int swz(int row, int col_us) {
  return row * LDW + (col_us ^ ((row & 7) << 3));
}

// xfw packed-buffer offsets (bf16 elements)
#define XFW_PPW   0
#define XFW_QKVO  8192      // + l*65536 + gem*16384   [128n][128k]
#define XFW_F1    139264    // + l*32768               [256n][128k]
#define XFW_F2    204800    // + l*32768               [128n][256k]

// ---------------------------------------------------------------------------
// Kernel 0: prep — tiled transposes f32->bf16 + conv wpack + PE table
// ---------------------------------------------------------------------------
__global__ __launch_bounds__(256) void prep_kernel(
    const float* __restrict__ ppw,
    const float* __restrict__ twq, const float* __restrict__ twk,
    const float* __restrict__ twv, const float* __restrict__ two,
    const float* __restrict__ f1w, const float* __restrict__ f2w,
    const float* __restrict__ ew1, const float* __restrict__ ew2,
    const float* __restrict__ tw1, const float* __restrict__ tw2,
    unsigned short* __restrict__ xfw, unsigned short* __restrict__ w1t,
    unsigned short* __restrict__ w2t, unsigned short* __restrict__ wpack,
    float* __restrict__ peT) {
  const int b = blockIdx.x;
  const int tid = threadIdx.x;
  if (b < 834) {
    __shared__ float tl[64][65];
    const float* src; unsigned short* dst; int R, C, tr, tc;
    if (b < 2) {
      src = ppw; dst = xfw + XFW_PPW; R = 64; C = 128; tr = 0; tc = b;
    } else if (b < 34) {
      int t = b - 2; int lg = t >> 2; int l = lg >> 2, gem = lg & 3;
      int tt = t & 3; tr = tt >> 1; tc = tt & 1;
      const float* s4 = (gem == 0) ? twq : (gem == 1) ? twk : (gem == 2) ? twv : two;
      src = s4 + l * 16384; dst = xfw + XFW_QKVO + l * 65536 + gem * 16384; R = 128; C = 128;
    } else if (b < 50) {
      int t = b - 34; int l = t >> 3; int tt = t & 7; tr = tt >> 2; tc = tt & 3;
      src = f1w + l * 32768; dst = xfw + XFW_F1 + l * 32768; R = 128; C = 256;
    } else if (b < 66) {
      int t = b - 50; int l = t >> 3; int tt = t & 7; tr = tt >> 1; tc = tt & 1;
      src = f2w + l * 32768; dst = xfw + XFW_F2 + l * 32768; R = 256; C = 128;
    } else if (b < 578) {
      int t = b - 66; int e = t >> 5; int tt = t & 31; tr = tt >> 3; tc = tt & 7;
      src = ew1 + e * 131072; dst = w1t + e * 131072; R = 256; C = 512;
    } else {
      int t = b - 578; int e = t >> 4; int tt = t & 15; tr = tt >> 1; tc = tt & 1;
      src = ew2 + e * 65536; dst = w2t + e * 65536; R = 512; C = 128;
    }
    for (int i = tid; i < 4096; i += 256) {
      int r = i >> 6, c = i & 63;
      tl[r][c] = src[(tr * 64 + r) * C + tc * 64 + c];
    }
    __syncthreads();
    for (int i = tid; i < 4096; i += 256) {
      int c = i >> 6, r = i & 63;
      dst[(tc * 64 + c) * R + tr * 64 + r] = f2bf(tl[r][c]);
    }
  } else if (b < 840) {
    int base = (b - 834) * 16384;
    for (int q = tid; q < 16384; q += 256) {
      int i = base + q;
      int c = i & 63, o = (i >> 6) & 63, tlc = i >> 12;
      int t = tlc % 3, lc = tlc / 3, lvl = lc >> 1;
      const float* src = (lc & 1) ? tw2 : tw1;
      wpack[i] = f2bf(src[lvl * 12288 + o * 192 + c * 3 + t]);
    }
  } else {
    int base = (b - 840) * 16384;
    for (int q = tid; q < 16384; q += 256) {
      int j = base + q; int ll = j >> 6, c = j & 63;
      float dv = expf(-0.14391157f * (float)(c & ~1));
      float ang = (float)ll * dv;
      peT[j] = (c & 1) ? cosf(ang) : sinf(ang);
    }
  }
}

// ---------------------------------------------------------------------------
// Kernel 1: TCN — one block per sequence, full L in LDS, swizzled layout
// ---------------------------------------------------------------------------
template <int DIL, bool RES>
__device__ __forceinline__ void conv_mfma(const unsigned short* __restrict__ IN,
                                          unsigned short* __restrict__ OUT,
                                          const unsigned short* __restrict__ Wt,
                                          const float* __restrict__ bias) {
  const int tid  = threadIdx.x;
  const int wid  = tid >> 6;
  const int lane = tid & 63;
  const int fr   = lane & 15;
  const int g    = lane >> 4;
  const int ot0  = (wid & 1) * 2;   // 2 o-tiles per wave
  const int ng   = wid >> 1;        // 8 n-tiles per wave (stride 4)

  bf16x8 Af[2][6];
#pragma unroll
  for (int oo = 0; oo < 2; ++oo)
#pragma unroll
    for (int t = 0; t < 3; ++t)
#pragma unroll
      for (int kh = 0; kh < 2; ++kh) {
        int wr = t * 64 + (ot0 + oo) * 16 + fr;
        Af[oo][t * 2 + kh] = *(const bf16x8*)(Wt + swz(wr, kh * 32 + g * 8));
      }
  float bv[2][4];
#pragma unroll
  for (int oo = 0; oo < 2; ++oo)
#pragma unroll
    for (int j = 0; j < 4; ++j) bv[oo][j] = bias[(ot0 + oo) * 16 + g * 4 + j];

#pragma unroll
  for (int k = 0; k < 8; ++k) {
    const int rb = PADF + (ng + k * 4) * 16 + fr;
    bf16x8 Bf[6];
#pragma unroll
    for (int t = 0; t < 3; ++t) {
      int r = rb + (t - 2) * DIL;   // causal taps at l-2d, l-d, l
#pragma unroll
      for (int kh = 0; kh < 2; ++kh)
        Bf[t * 2 + kh] = *(const bf16x8*)(IN + swz(r, kh * 32 + g * 8));
    }
    f32x4 acc[2];
#pragma unroll
    for (int oo = 0; oo < 2; ++oo) {
      f32x4 a; a[0] = bv[oo][0]; a[1] = bv[oo][1]; a[2] = bv[oo][2]; a[3] = bv[oo][3];
      acc[oo] = a;
    }
#pragma unroll
    for (int f = 0; f < 6; ++f)
#pragma unroll
      for (int oo = 0; oo < 2; ++oo)
        acc[oo] = __builtin_amdgcn_mfma_f32_16x16x32_bf16(Af[oo][f], Bf[f], acc[oo], 0, 0, 0);

#pragma unroll
    for (int oo = 0; oo < 2; ++oo) {
      unsigned short* op = OUT + swz(rb, (ot0 + oo) * 16 + g * 4);
      us4 old;
      if (RES) old = *(const us4*)op;
      us4 st;
#pragma unroll
      for (int j = 0; j < 4; ++j) {
        float v = fmaxf(acc[oo][j], 0.f);
        if (RES) v = fmaxf(v + bf2f(old[j]), 0.f);
        st[j] = f2bf(v);
      }
      *(us4*)op = st;
    }
  }
}

__global__ __launch_bounds__(512) void tcn_kernel(
    const float* __restrict__ x, const float* __restrict__ mask,
    const float* __restrict__ pw, const float* __restrict__ pb,
    const unsigned short* __restrict__ wpack,
    const float* __restrict__ b1, const float* __restrict__ b2,
    const float* __restrict__ peT,
    const float* __restrict__ lng, const float* __restrict__ lnb,
    float* __restrict__ psum) {
  extern __shared__ unsigned short smu[];
  unsigned short* A  = smu;                  // [528][64] bf16 swizzled
  unsigned short* Bq = A + ROWSF * LDW;      // [528][64]
  unsigned short* Wb = Bq + ROWSF * LDW;     // [192][64] (overlaid: pwpb; later LN stats)

  const int seq = blockIdx.x;
  const int b = seq >> 5;
  const int m = seq & 31;
  if (mask[b * M_ + m] == 0.0f) return;      // masked sensor: output unused
  const int tid = threadIdx.x;

  float4 wreg[3];
#define WLOAD(li)                                                              \
  { _Pragma("unroll") for (int q = 0; q < 3; ++q)                              \
      wreg[q] = *(const float4*)(wpack + (li) * 12288 +                        \
                                 (q * 64 + (tid >> 3)) * 64 + (tid & 7) * 8); }
#define WSTORE()                                                               \
  { _Pragma("unroll") for (int q = 0; q < 3; ++q) {                            \
      int wr = q * 64 + (tid >> 3);                                            \
      *(float4*)(Wb + swz(wr, (tid & 7) * 8)) = wreg[q]; } }

  WLOAD(0);
  float* pwpb = (float*)Wb;                  // pw|pb staged briefly in W region
  if (tid < 64)       pwpb[tid] = pw[tid];
  else if (tid < 128) pwpb[tid] = pb[tid - 64];
  __syncthreads();

  // A-build: one row per thread; pads zeroed
  {
    int r = PADF + tid, l = tid;
    float xv = x[(b * L_ + l) * M_ + m];
    const float4* pe4 = (const float4*)(peT + l * 64);
#pragma unroll
    for (int c0 = 0; c0 < 64; c0 += 8) {
      float4 pa = pe4[c0 / 4], pc = pe4[c0 / 4 + 1];
      float pe[8] = {pa.x, pa.y, pa.z, pa.w, pc.x, pc.y, pc.z, pc.w};
      us8 st;
#pragma unroll
      for (int j = 0; j < 8; ++j) {
        int c = c0 + j;
        st[j] = f2bf(fmaf(xv, pwpb[c], pwpb[64 + c]) + pe[j]);
      }
      *(us8*)(A + swz(r, c0)) = st;
    }
  }
  for (int idx = tid; idx < PADF * LDW; idx += 512) { A[idx] = 0; Bq[idx] = 0; }
  __syncthreads();

#define STEP(li) WSTORE(); if (li < 7) WLOAD(li + 1); __syncthreads();
  STEP(0) conv_mfma<1, false>(A, Bq, Wb, b1 + 0);   __syncthreads();
  STEP(1) conv_mfma<1, true >(Bq, A, Wb, b2 + 0);   __syncthreads();
  STEP(2) conv_mfma<2, false>(A, Bq, Wb, b1 + 64);  __syncthreads();
  STEP(3) conv_mfma<2, true >(Bq, A, Wb, b2 + 64);  __syncthreads();
  STEP(4) conv_mfma<4, false>(A, Bq, Wb, b1 + 128); __syncthreads();
  STEP(5) conv_mfma<4, true >(Bq, A, Wb, b2 + 128); __syncthreads();
  STEP(6) conv_mfma<8, false>(A, Bq, Wb, b1 + 192); __syncthreads();
  STEP(7) conv_mfma<8, true >(Bq, A, Wb, b2 + 192); __syncthreads();
#undef STEP
#undef WLOAD
#undef WSTORE

  // LayerNorm stats per position (channel-permutation-invariant reads)
  float* mstp = (float*)Wb;        // [512] mu | [512] rstd
  float* pp   = mstp + 1024;       // [8][64] pool partials
  {
    int r = PADF + tid;
    float s = 0.f, ss = 0.f;
#pragma unroll
    for (int c0 = 0; c0 < 64; c0 += 8) {
      bf16x8 vv = *(const bf16x8*)(A + swz(r, c0));
#pragma unroll
      for (int j = 0; j < 8; ++j) { float v = bf2f((unsigned short)vv[j]); s += v; ss += v * v; }
    }
    float mu = s * 0.015625f;
    float var = fmaxf(ss * 0.015625f - mu * mu, 0.0f);
    mstp[tid] = mu;
    mstp[512 + tid] = rsqrtf(var + 1e-5f);
  }
  __syncthreads();
  {
    int p = tid & 63, q = tid >> 6;   // 8 groups x 64 rows
    float accp = 0.f;
    int r0 = PADF + q * 64;
    for (int r = r0; r < r0 + 64; ++r)
      accp += (bf2f(A[swz(r, p)]) - mstp[r - PADF]) * mstp[512 + r - PADF];
    pp[tid] = accp;
  }
  __syncthreads();
  if (tid < 64) {
    float acc = 0.f;
#pragma unroll
    for (int q = 0; q < 8; ++q) acc += pp[q * 64 + tid];
    psum[seq * 64 + tid] = lng[tid] * acc + 512.0f * lnb[tid];
  }
}

// ---------------------------------------------------------------------------
// Kernel 2: transformer — MFMA GEMMs, B-frags streamed from global bf16
// ---------------------------------------------------------------------------
__device__ __forceinline__ void ln_sums(const float* __restrict__ In, float* mst, float* scr) {
  const int t = threadIdx.x;
  if (t < 256) {
    int mm = t >> 3, sg = t & 7;
    const float* ip = In + mm * 132 + sg * 16;
    float s = 0, ss = 0;
#pragma unroll
    for (int j = 0; j < 16; ++j) { float v = ip[j]; s += v; ss += v * v; }
    scr[t] = s; scr[256 + t] = ss;
  }
  __syncthreads();
  if (t < 32) {
    float s = 0, ss = 0;
#pragma unroll
    for (int k = 0; k < 8; ++k) { s += scr[t * 8 + k]; ss += scr[256 + t * 8 + k]; }
    float mu = s * 0.0078125f;
    float var = fmaxf(ss * 0.0078125f - mu * mu, 0.f);
    mst[t] = mu;
    mst[32 + t] = rsqrtf(var + 1e-5f);
  }
  __syncthreads();
}

__device__ __forceinline__ void ln_bf(const float* __restrict__ In, unsigned short* __restrict__ Out,
                                      const float* __restrict__ g, const float* __restrict__ b,
                                      float* mst, float* scr) {
  ln_sums(In, mst, scr);
  for (int idx = threadIdx.x; idx < 4096; idx += 512) {
    int mm = idx >> 7, j = idx & 127;
    Out[mm * 136 + j] = f2bf((In[mm * 132 + j] - mst[mm]) * mst[32 + mm] * g[j] + b[j]);
  }
  __syncthreads();
}

__device__ __forceinline__ void ln_f32(const float* __restrict__ In, float* __restrict__ Out,
                                       const float* __restrict__ g, const float* __restrict__ b,
                                       float* mst, float* scr) {
  ln_sums(In, mst, scr);
  for (int idx = threadIdx.x; idx < 4096; idx += 512) {
    int mm = idx >> 7, j = idx & 127;
    Out[mm * 132 + j] = (In[mm * 132 + j] - mst[mm]) * mst[32 + mm] * g[j] + b[j];
  }
  __syncthreads();
}

__global__ __launch_bounds__(512) void xf_kernel(
    const float* __restrict__ psum, const float* __restrict__ mask,
    const unsigned short* __restrict__ xfw,
    const float* __restrict__ ppb, const float* __restrict__ pos,
    const float* __restrict__ bq, const float* __restrict__ bk,
    const float* __restrict__ bv, const float* __restrict__ bo,
    const float* __restrict__ l1g, const float* __restrict__ l1b,
    const float* __restrict__ l2g, const float* __restrict__ l2b,
    const float* __restrict__ f1b, const float* __restrict__ f2b,
    const float* __restrict__ og_, const float* __restrict__ ob_,
    float* __restrict__ pooledws, float* __restrict__ ctxws, float* __restrict__ gws) {
  extern __shared__ float sm[];
  float* T    = sm;                 // 32*132
  float* QKV  = T + 4224;           // 32*396
  float* S    = QKV + 12672;        // 8448
  float* scr  = S + 8448;           // 512
  float* mst  = scr + 512;          // 64
  float* mkv  = mst + 64;           // 32
  unsigned short* Ybf = (unsigned short*)(mkv + 32);   // [32][136]
  unsigned short* Yb2 = Ybf + 32 * 136;                // [32][136]
  unsigned short* FFH = Yb2 + 32 * 136;                // [32][264]
  const int b = blockIdx.x;
  const int tid = threadIdx.x;
  const int wid = tid >> 6;
  const int lane = tid & 63;
  const int fr = lane & 15;
  const int g = lane >> 4;

  if (tid < 32) mkv[tid] = mask[b * 32 + tid];
  for (int idx = tid; idx < 2048; idx += 512) {
    int mm = idx >> 6, p = idx & 63;
    float v = mask[b * 32 + mm] * psum[(b * 32 + mm) * 64 + p] * (1.0f / 512.0f);
    pooledws[(b * 32 + mm) * 64 + p] = v;
    Ybf[mm * 136 + p] = f2bf(v);
  }
  __syncthreads();

  // pool-proj
  {
    int mt = wid >> 2;
    bf16x8 Af[2];
#pragma unroll
    for (int kf = 0; kf < 2; ++kf)
      Af[kf] = *(const bf16x8*)(Ybf + (mt * 16 + fr) * 136 + kf * 32 + g * 8);
#pragma unroll
    for (int i = 0; i < 2; ++i) {
      int nt = (wid & 3) * 2 + i;
      const unsigned short* bp = xfw + XFW_PPW + (nt * 16 + fr) * 64;
      f32x4 acc = {0.f, 0.f, 0.f, 0.f};
#pragma unroll
      for (int kf = 0; kf < 2; ++kf)
        acc = __builtin_amdgcn_mfma_f32_16x16x32_bf16(Af[kf], *(const bf16x8*)(bp + kf * 32 + g * 8), acc, 0, 0, 0);
      int n = nt * 16 + fr;
      float bb = ppb[n];
#pragma unroll
      for (int j = 0; j < 4; ++j) {
        int m = mt * 16 + g * 4 + j;
        T[m * 132 + n] = acc[j] + bb + pos[m * 128 + n];
      }
    }
  }
  __syncthreads();

  for (int l = 0; l < NL_; ++l) {
    ln_bf(T, Ybf, l1g + l * 128, l1b + l * 128, mst, scr);
#pragma unroll
    for (int i = 0; i < 6; ++i) {
      int tt = wid * 6 + i;
      int gem = tt >> 4, r = tt & 15, mt = r >> 3, nt = r & 7;
      const unsigned short* wT = xfw + XFW_QKVO + l * 65536 + gem * 16384;
      const float* bias = (gem == 0) ? bq : (gem == 1) ? bk : bv;
      bf16x8 Afr[4];
#pragma unroll
      for (int kf = 0; kf < 4; ++kf)
        Afr[kf] = *(const bf16x8*)(Ybf + (mt * 16 + fr) * 136 + kf * 32 + g * 8);
      const unsigned short* bp = wT + (nt * 16 + fr) * 128;
      f32x4 acc = {0.f, 0.f, 0.f, 0.f};
#pragma unroll
      for (int kf = 0; kf < 4; ++kf)
        acc = __builtin_amdgcn_mfma_f32_16x16x32_bf16(Afr[kf], *(const bf16x8*)(bp + kf * 32 + g * 8), acc, 0, 0, 0);
      int n = nt * 16 + fr;
      float bb = bias[l * 128 + n];
#pragma unroll
      for (int j = 0; j < 4; ++j)
        QKV[(mt * 16 + g * 4 + j) * 396 + gem * 132 + n] = acc[j] + bb;
    }
    __syncthreads();
    for (int idx = tid; idx < 8192; idx += 512) {
      int h = idx >> 10, rem = idx & 1023, mm = rem >> 5, n = rem & 31;
      const float* qp = QKV + mm * 396 + h * 16;
      const float* kp = QKV + n * 396 + 132 + h * 16;
      float a = 0;
#pragma unroll
      for (int d = 0; d < 16; ++d) a = fmaf(qp[d], kp[d], a);
      a *= 0.25f;
      if (mkv[n] == 0.0f) a -= 1e9f;
      S[h * 1056 + mm * 33 + n] = a;
    }
    __syncthreads();
    if (tid < 256) {
      float* sr = S + (tid >> 5) * 1056 + (tid & 31) * 33;
      float mx = sr[0];
      for (int n = 1; n < 32; ++n) mx = fmaxf(mx, sr[n]);
      float sum = 0;
      for (int n = 0; n < 32; ++n) { float e = __expf(sr[n] - mx); sr[n] = e; sum += e; }
      float inv = 1.0f / sum;
      for (int n = 0; n < 32; ++n) sr[n] *= inv;
    }
    __syncthreads();
    for (int idx = tid; idx < 4096; idx += 512) {
      int mm = idx >> 7, jd = idx & 127, h = jd >> 4, d = jd & 15;
      const float* sp = S + h * 1056 + mm * 33;
      const float* vp = QKV + 264 + h * 16 + d;
      float a = 0;
#pragma unroll 8
      for (int n = 0; n < 32; ++n) a = fmaf(sp[n], vp[n * 396], a);
      Yb2[mm * 136 + jd] = f2bf(a);
    }
    __syncthreads();
    {
      int mt = wid >> 2;
      bf16x8 Aw[4];
#pragma unroll
      for (int kf = 0; kf < 4; ++kf)
        Aw[kf] = *(const bf16x8*)(Yb2 + (mt * 16 + fr) * 136 + kf * 32 + g * 8);
#pragma unroll
      for (int i = 0; i < 2; ++i) {
        int nt = (wid & 3) * 2 + i;
        const unsigned short* bp = xfw + XFW_QKVO + l * 65536 + 3 * 16384 + (nt * 16 + fr) * 128;
        f32x4 acc = {0.f, 0.f, 0.f, 0.f};
#pragma unroll
        for (int kf = 0; kf < 4; ++kf)
          acc = __builtin_amdgcn_mfma_f32_16x16x32_bf16(Aw[kf], *(const bf16x8*)(bp + kf * 32 + g * 8), acc, 0, 0, 0);
        int n = nt * 16 + fr;
        float bb = bo[l * 128 + n];
#pragma unroll
        for (int j = 0; j < 4; ++j)
          T[(mt * 16 + g * 4 + j) * 132 + n] += acc[j] + bb;
      }
    }
    __syncthreads();
    ln_bf(T, Ybf, l2g + l * 128, l2b + l * 128, mst, scr);
    {
      int mt = wid >> 2;
      bf16x8 Aff[4];
#pragma unroll
      for (int kf = 0; kf < 4; ++kf)
        Aff[kf] = *(const bf16x8*)(Ybf + (mt * 16 + fr) * 136 + kf * 32 + g * 8);
#pragma unroll
      for (int i = 0; i < 4; ++i) {
        int tt = wid * 4 + i;
        int nt = tt & 15;
        const unsigned short* bp = xfw + XFW_F1 + l * 32768 + (nt * 16 + fr) * 128;
        f32x4 acc = {0.f, 0.f, 0.f, 0.f};
#pragma unroll
        for (int kf = 0; kf < 4; ++kf)
          acc = __builtin_amdgcn_mfma_f32_16x16x32_bf16(Aff[kf], *(const bf16x8*)(bp + kf * 32 + g * 8), acc, 0, 0, 0);
        int n = nt * 16 + fr;
        float bb = f1b[l * 256 + n];
#pragma unroll
        for (int j = 0; j < 4; ++j)
          FFH[(mt * 16 + g * 4 + j) * 264 + n] = f2bf(fmaxf(acc[j] + bb, 0.f));
      }
    }
    __syncthreads();
    {
      int mt = wid >> 2;
      bf16x8 Af2[8];
#pragma unroll
      for (int kf = 0; kf < 8; ++kf)
        Af2[kf] = *(const bf16x8*)(FFH + (mt * 16 + fr) * 264 + kf * 32 + g * 8);
#pragma unroll
      for (int i = 0; i < 2; ++i) {
        int nt = (wid & 3) * 2 + i;
        const unsigned short* bp = xfw + XFW_F2 + l * 32768 + (nt * 16 + fr) * 256;
        f32x4 acc = {0.f, 0.f, 0.f, 0.f};
#pragma unroll
        for (int kf = 0; kf < 8; ++kf)
          acc = __builtin_amdgcn_mfma_f32_16x16x32_bf16(Af2[kf], *(const bf16x8*)(bp + kf * 32 + g * 8), acc, 0, 0, 0);
        int n = nt * 16 + fr;
        float bb = f2b[l * 128 + n];
#pragma unroll
        for (int j = 0; j < 4; ++j)
          T[(mt * 16 + g * 4 + j) * 132 + n] += acc[j] + bb;
      }
    }
    __syncthreads();
  }

  ln_f32(T, S, og_, ob_, mst, scr);
  for (int idx = tid; idx < 4096; idx += 512) {
    int mm = idx >> 7, j = idx & 127;
    float c = S[mm * 132 + j] * mkv[mm];
    S[mm * 132 + j] = c;
    ctxws[(b * 32 + mm) * 128 + j] = c;
  }
  __syncthreads();
  if (tid < 128) {
    float cnt = 0;
    for (int mm = 0; mm < 32; ++mm) cnt += mkv[mm];
    cnt = fmaxf(cnt, 1.0f);
    float s = 0, mx = -1e9f;
    for (int mm = 0; mm < 32; ++mm) {
      float v = S[mm * 132 + tid];
      s += v;
      if (mkv[mm] > 0.0f) mx = fmaxf(mx, v);
    }
    gws[b * 256 + tid] = s / cnt;
    gws[b * 256 + 128 + tid] = mx;
  }
}

// ---------------------------------------------------------------------------
// Kernel 3: gates — top-2 + weights + expert lists + bf16 row pack
// ---------------------------------------------------------------------------
__global__ __launch_bounds__(64) void gates_kernel(
    const float* __restrict__ gws, const float* __restrict__ ctxws,
    const float* __restrict__ gfw, const float* __restrict__ gfb,
    const float* __restrict__ glw, const float* __restrict__ glb,
    const float* __restrict__ grw, const float* __restrict__ grb,
    float* __restrict__ gwt, int* __restrict__ ecnt, int* __restrict__ elist,
    unsigned short* __restrict__ xbf) {
  __shared__ float lg[16];
  int r = blockIdx.x;
  const float* in; const float* W; const float* Bb; int dl; int rr = 0;
  if (r < 16)      { rr = r;      in = gws + rr * 256;       W = gfw; Bb = gfb; dl = 256; }
  else if (r < 32) { rr = r - 16; in = gws + rr * 256;       W = glw; Bb = glb; dl = 256; }
  else             { in = ctxws + (r - 32) * 128;            W = grw; Bb = grb; dl = 128; }
  if (threadIdx.x < 16) {
    float a = Bb[threadIdx.x];
    for (int d = 0; d < dl; ++d) a = fmaf(in[d], W[d * 16 + threadIdx.x], a);
    lg[threadIdx.x] = a;
  }
#pragma unroll
  for (int q = 0; q < 4; ++q) {
    int d = threadIdx.x * 4 + q;
    float v;
    if (r < 32) v = gws[rr * 256 + d];
    else        v = (d < 128) ? ctxws[(r - 32) * 128 + d]
                              : gws[((r - 32) >> 5) * 256 + (d - 128)];
    xbf[r * 256 + d] = f2bf(v);
  }
  __syncthreads();
  if (threadIdx.x == 0) {
    int i0 = 0; float v0 = lg[0];
    for (int e = 1; e < 16; ++e) if (lg[e] > v0) { v0 = lg[e]; i0 = e; }
    int i1 = (i0 == 0) ? 1 : 0; float v1 = lg[i1];
    for (int e = 0; e < 16; ++e) if (e != i0 && lg[e] > v1) { v1 = lg[e]; i1 = e; }
    float e1 = __expf(v1 - v0);
    float w0 = 1.0f / (1.0f + e1);
    gwt[2 * r] = w0;  gwt[2 * r + 1] = 1.0f - w0;
    int p0 = atomicAdd(&ecnt[i0], 1); elist[i0 * 544 + p0] = 2 * r;
    int p1 = atomicAdd(&ecnt[i1], 1); elist[i1 * 544 + p1] = 2 * r + 1;
  }
}

// ---------------------------------------------------------------------------
// Kernel 4: MoE experts — batched MFMA GEMM per expert
// ---------------------------------------------------------------------------
__global__ __launch_bounds__(512) void moe_kernel(
    const unsigned short* __restrict__ xbf, const float* __restrict__ gwt,
    const int* __restrict__ elist, const int* __restrict__ ecnt,
    const unsigned short* __restrict__ w1t, const float* __restrict__ eb1,
    const unsigned short* __restrict__ w2t, const float* __restrict__ eb2,
    float* __restrict__ yall) {
  __shared__ unsigned short Xb[16 * 264];
  __shared__ unsigned short Hb[16 * 520];
  __shared__ float wl[16];
  __shared__ int rowl[16];
  const int e = blockIdx.x >> 3;
  const int slot = blockIdx.x & 7;
  const int n = ecnt[e];
  const int ntiles = (n + 15) >> 4;
  const int tid = threadIdx.x;
  const int wid = tid >> 6;
  const int lane = tid & 63;
  const int fr = lane & 15;
  const int g = lane >> 4;

  for (int t = slot; t < ntiles; t += 8) {
    if (tid < 16) {
      int idx = t * 16 + tid;
      int id = (idx < n) ? elist[e * 544 + idx] : -1;
      rowl[tid] = (id >= 0) ? (id >> 1) : -1;
      wl[tid] = (id >= 0) ? gwt[id] : 0.f;
    }
    __syncthreads();
    for (int i = tid; i < 512; i += 512) {
      int r = i >> 5, c8 = (i & 31) * 8;
      int row = rowl[r];
      bf16x8 v = {0, 0, 0, 0, 0, 0, 0, 0};
      if (row >= 0) v = *(const bf16x8*)(xbf + row * 256 + c8);
      *(bf16x8*)(Xb + r * 264 + c8) = v;
    }
    __syncthreads();
    bf16x8 Af[8];
#pragma unroll
    for (int kf = 0; kf < 8; ++kf)
      Af[kf] = *(const bf16x8*)(Xb + fr * 264 + kf * 32 + g * 8);
#pragma unroll
    for (int ntl = 0; ntl < 4; ++ntl) {
      int nt = wid * 4 + ntl;
      const unsigned short* bp = w1t + (e * 512 + nt * 16 + fr) * 256;
      f32x4 acc = {0.f, 0.f, 0.f, 0.f};
#pragma unroll
      for (int kf = 0; kf < 8; ++kf)
        acc = __builtin_amdgcn_mfma_f32_16x16x32_bf16(Af[kf], *(const bf16x8*)(bp + kf * 32 + g * 8), acc, 0, 0, 0);
      int h = nt * 16 + fr;
      float b1v = eb1[e * 512 + h];
#pragma unroll
      for (int j = 0; j < 4; ++j)
        Hb[(g * 4 + j) * 520 + h] = f2bf(fmaxf(acc[j] + b1v, 0.f));
    }
    __syncthreads();
    {
      const unsigned short* bp = w2t + (e * 128 + wid * 16 + fr) * 512;
      f32x4 acc = {0.f, 0.f, 0.f, 0.f};
#pragma unroll
      for (int kf = 0; kf < 16; ++kf) {
        bf16x8 Ah = *(const bf16x8*)(Hb + fr * 520 + kf * 32 + g * 8);
        acc = __builtin_amdgcn_mfma_f32_16x16x32_bf16(Ah, *(const bf16x8*)(bp + kf * 32 + g * 8), acc, 0, 0, 0);
      }
      int o = wid * 16 + fr;
      float b2v = eb2[e * 128 + o];
#pragma unroll
      for (int j = 0; j < 4; ++j) {
        int r = g * 4 + j;
        int row = rowl[r];
        if (row >= 0) atomicAdd(&yall[row * 128 + o], wl[r] * (acc[j] + b2v));
      }
    }
    __syncthreads();
  }
}

// ---------------------------------------------------------------------------
// Kernel 5: output heads -> fp32 output
// ---------------------------------------------------------------------------
__global__ __launch_bounds__(192) void heads_kernel(
    const float* __restrict__ x, const float* __restrict__ mask,
    const float* __restrict__ pooledws, const float* __restrict__ ctxws,
    const float* __restrict__ yf, const float* __restrict__ yfail, const float* __restrict__ yrca,
    const float* __restrict__ pw, const float* __restrict__ pb,
    const float* __restrict__ fw, const float* __restrict__ fb,
    const float* __restrict__ rw, const float* __restrict__ rb,
    float* __restrict__ out) {
  __shared__ float yfb[128];
  int b = blockIdx.x, t = threadIdx.x;
  if (t < 128) yfb[t] = yf[b * 128 + t];
  __syncthreads();
  if (t < 96) {
    int mm = t / 3, o = t - mm * 3;
    int s = b * 32 + mm;
    float a = pb[o];
    const float* pl = pooledws + s * 64;
    for (int i = 0; i < 64; ++i) a = fmaf(pl[i], pw[i * 3 + o], a);
    const float* cx = ctxws + s * 128;
    for (int i = 0; i < 128; ++i) a = fmaf(cx[i], pw[(64 + i) * 3 + o], a);
    for (int i = 0; i < 128; ++i) a = fmaf(yfb[i], pw[(192 + i) * 3 + o], a);
    a += x[(b * 512 + 511) * 32 + mm] * mask[b * 32 + mm];
    out[b * 131 + t] = a;
  } else if (t < 99) {
    int o = t - 96;
    float a = fb[o];
    const float* yl = yfail + b * 128;
    for (int i = 0; i < 128; ++i) a = fmaf(yl[i], fw[i * 3 + o], a);
    out[b * 131 + 96 + o] = a;
  } else if (t < 131) {
    int mm = t - 99;
    int s = b * 32 + mm;
    float a = rb[0];
    const float* pl = pooledws + s * 64;
    for (int i = 0; i < 64; ++i) a = fmaf(pl[i], rw[i], a);
    const float* cx = ctxws + s * 128;
    for (int i = 0; i < 128; ++i) a = fmaf(cx[i], rw[64 + i], a);
    const float* yr = yrca + s * 128;
    for (int i = 0; i < 128; ++i) a = fmaf(yr[i], rw[192 + i], a);
    out[b * 131 + 99 + mm] = a;
  }
}

// ---------------------------------------------------------------------------
extern "C" void kernel_launch(void* const* d_in, const int* in_sizes, int n_in,
                              void* d_out, int out_size, void* d_ws, size_t ws_size,
                              hipStream_t stream) {
  (void)in_sizes; (void)n_in; (void)out_size; (void)ws_size;
  const float* x    = (const float*)d_in[0];
  const float* msk  = (const float*)d_in[1];
  const float* epw  = (const float*)d_in[2];
  const float* epb  = (const float*)d_in[3];
  const float* tw1  = (const float*)d_in[4];
  const float* tb1  = (const float*)d_in[5];
  const float* tw2  = (const float*)d_in[6];
  const float* tb2  = (const float*)d_in[7];
  const float* eng  = (const float*)d_in[8];
  const float* enb  = (const float*)d_in[9];
  const float* ppw  = (const float*)d_in[10];
  const float* ppb  = (const float*)d_in[11];
  const float* pos  = (const float*)d_in[12];
  const float* twq  = (const float*)d_in[13];
  const float* tbq  = (const float*)d_in[14];
  const float* twk  = (const float*)d_in[15];
  const float* tbk  = (const float*)d_in[16];
  const float* twv  = (const float*)d_in[17];
  const float* tbv  = (const float*)d_in[18];
  const float* two  = (const float*)d_in[19];
  const float* tbo  = (const float*)d_in[20];
  const float* l1g  = (const float*)d_in[21];
  const float* l1b  = (const float*)d_in[22];
  const float* l2g  = (const float*)d_in[23];
  const float* l2b  = (const float*)d_in[24];
  const float* f1w  = (const float*)d_in[25];
  const float* f1b  = (const float*)d_in[26];
  const float* f2w  = (const float*)d_in[27];
  const float* f2b  = (const float*)d_in[28];
  const float* tog  = (const float*)d_in[29];
  const float* tob  = (const float*)d_in[30];
  const float* ew1  = (const float*)d_in[31];
  const float* eb1  = (const float*)d_in[32];
  const float* ew2  = (const float*)d_in[33];
  const float* eb2  = (const float*)d_in[34];
  const float* gfw  = (const float*)d_in[35];
  const float* gfb  = (const float*)d_in[36];
  const float* glw  = (const float*)d_in[37];
  const float* glb  = (const float*)d_in[38];
  const float* grw  = (const float*)d_in[39];
  const float* grb  = (const float*)d_in[40];
  const float* prw  = (const float*)d_in[41];
  const float* prb  = (const float*)d_in[42];
  const float* fw   = (const float*)d_in[43];
  const float* fb   = (const float*)d_in[44];
  const float* rw   = (const float*)d_in[45];
  const float* rb   = (const float*)d_in[46];

  float* ws      = (float*)d_ws;
  float* psum    = ws;                     // 32768
  float* pooledw = psum + 32768;           // 32768
  float* ctxw    = pooledw + 32768;        // 65536
  float* gwsb    = ctxw + 65536;           // 4096
  float* yall    = gwsb + 4096;            // 69632
  float* gwt     = yall + 69632;           // 1088
  int*   ecnt    = (int*)(gwt + 1088);     // 16
  int*   elist   = ecnt + 16;              // 8704
  float* peT     = (float*)(elist + 8704); // 32768
  unsigned short* wpack = (unsigned short*)(peT + 32768);  // 98304
  unsigned short* xfw   = wpack + 98304;                   // 270336
  unsigned short* w1t   = xfw + 270336;                    // 2097152
  unsigned short* w2t   = w1t + 2097152;                   // 1048576
  unsigned short* xbf   = w2t + 1048576;                   // 139264

  const int tcn_lds = (2 * ROWSF * LDW + 192 * LDW) * 2;  // 159744 B
  const int xf_lds  = (4224 + 12672 + 8448 + 512 + 64 + 32 + 2176 + 2176 + 4224) * 4;  // 138112 B
  hipFuncSetAttribute((const void*)tcn_kernel, hipFuncAttributeMaxDynamicSharedMemorySize, tcn_lds);
  hipFuncSetAttribute((const void*)xf_kernel,  hipFuncAttributeMaxDynamicSharedMemorySize, xf_lds);

  hipMemsetAsync(yall, 0, 69632 * sizeof(float), stream);
  hipMemsetAsync(ecnt, 0, 16 * sizeof(int), stream);

  prep_kernel<<<842, 256, 0, stream>>>(ppw, twq, twk, twv, two, f1w, f2w, ew1, ew2,
                                       tw1, tw2, xfw, w1t, w2t, wpack, peT);
  tcn_kernel<<<512, 512, tcn_lds, stream>>>(x, msk, epw, epb, wpack, tb1, tb2, peT,
                                            eng, enb, psum);
  xf_kernel<<<16, 512, xf_lds, stream>>>(psum, msk, xfw, ppb, pos,
                                         tbq, tbk, tbv, tbo,
                                         l1g, l1b, l2g, l2b, f1b, f2b,
                                         tog, tob, pooledw, ctxw, gwsb);
  gates_kernel<<<544, 64, 0, stream>>>(gwsb, ctxw, gfw, gfb, glw, glb, grw, grb,
                                       gwt, ecnt, elist, xbf);
  moe_kernel<<<128, 512, 0, stream>>>(xbf, gwt, elist, ecnt, w1t, eb1, w2t, eb2, yall);
  heads_kernel<<<16, 192, 0, stream>>>(x, msk, pooledw, ctxw,
                                       yall, yall + 2048, yall + 4096,
                                       prw, prb, fw, fb, rw, rb, (float*)d_out);
}